// Round 1
// baseline (2345.900 us; speedup 1.0000x reference)
//
#include <hip/hip_runtime.h>
#include <hip/hip_bf16.h>
#include <math.h>

#define BB   4
#define LL   2048
#define INF_ 64
#define DD   256
#define NN   16
#define KK   32
#define BLn  (BB*LL)      // 8192
#define FCNT 1025         // L/2+1

__device__ __forceinline__ float softplusf(float x) {
    return x > 20.f ? x : log1pf(__expf(x));
}
__device__ __forceinline__ float sigmoidf_(float x) {
    return 1.f / (1.f + __expf(-x));
}

// ---------------- twiddle table: tab[k]=cos(2*pi*k/2048), tab[2048+k]=sin ----
__global__ void twiddle_kernel(float* tab) {
    int i = blockIdx.x * 256 + threadIdx.x;
    if (i < 2048) {
        double ang = 2.0 * 3.14159265358979323846 * (double)i / 2048.0;
        tab[i]        = (float)cos(ang);
        tab[2048 + i] = (float)sin(ang);
    }
}

// ---------------- generic fp32 GEMM, 64x64 tile, 256 thr, 4x4 micro ---------
// C[M,N] = act(A@W + bias) + addend ; act: 0 none, 1 softplus, 2 sigmoid
template<typename AT>
__global__ void gemm64(const AT* __restrict__ A, const float* __restrict__ W,
                       const float* __restrict__ bias, const float* __restrict__ addend,
                       float* __restrict__ C, int M, int N, int K, int act) {
    __shared__ float As[16][68];   // [kk][m], padded: b128 reads conflict-free
    __shared__ float Ws[16][64];   // [kk][j]
    const int tid = threadIdx.x;
    const int tx = tid & 15, ty = tid >> 4;
    const int row0 = blockIdx.y * 64, col0 = blockIdx.x * 64;
    float acc[4][4] = {};
    for (int k0 = 0; k0 < K; k0 += 16) {
#pragma unroll
        for (int e = 0; e < 4; ++e) {
            int p = e * 256 + tid;
            int kk = p & 15, m = p >> 4;
            float v;
            if constexpr (sizeof(AT) == 2)
                v = __bfloat162float(A[(size_t)(row0 + m) * K + k0 + kk]);
            else
                v = A[(size_t)(row0 + m) * K + k0 + kk];
            As[kk][m] = v;
        }
#pragma unroll
        for (int e = 0; e < 4; ++e) {
            int p = e * 256 + tid;
            int kk = p >> 6, j = p & 63;
            Ws[kk][j] = W[(size_t)(k0 + kk) * N + col0 + j];
        }
        __syncthreads();
#pragma unroll
        for (int kk = 0; kk < 16; ++kk) {
            float4 a4 = *(const float4*)&As[kk][ty * 4];
            float4 w4 = *(const float4*)&Ws[kk][tx * 4];
            float av[4] = {a4.x, a4.y, a4.z, a4.w};
            float wv[4] = {w4.x, w4.y, w4.z, w4.w};
#pragma unroll
            for (int i = 0; i < 4; ++i)
#pragma unroll
                for (int j = 0; j < 4; ++j)
                    acc[i][j] = fmaf(av[i], wv[j], acc[i][j]);
        }
        __syncthreads();
    }
#pragma unroll
    for (int i = 0; i < 4; ++i) {
        int r = row0 + ty * 4 + i;
#pragma unroll
        for (int j = 0; j < 4; ++j) {
            int c = col0 + tx * 4 + j;
            float v = acc[i][j];
            if (bias) v += bias[c];
            if (act == 1) v = softplusf(v);
            else if (act == 2) v = sigmoidf_(v);
            if (addend) v += addend[(size_t)r * N + c];
            C[(size_t)r * N + c] = v;
        }
    }
}

// ---------------- small GEMM: C[M,16] = A[M,256] @ W[256,16] (no bias) ------
__global__ void gemm_n16(const float* __restrict__ A, const float* __restrict__ W,
                         float* __restrict__ C) {
    __shared__ float As[16][260];
    __shared__ float Ws[256][16];
    const int tid = threadIdx.x;
    const int row0 = blockIdx.x * 16;
#pragma unroll
    for (int e = 0; e < 16; ++e)
        As[e][tid] = A[(size_t)(row0 + e) * 256 + tid];
#pragma unroll
    for (int e = 0; e < 16; ++e) {
        int p = e * 256 + tid;
        Ws[p >> 4][p & 15] = W[p];
    }
    __syncthreads();
    const int r = tid >> 4, n = tid & 15;
    float acc = 0.f;
#pragma unroll 8
    for (int k = 0; k < 256; ++k)
        acc = fmaf(As[r][k], Ws[k][n], acc);
    C[(size_t)(row0 + r) * 16 + n] = acc;
}

// ---------------- LayerNorm over D=256, one row per block -------------------
__global__ void ln_kernel(const float* __restrict__ X, const float* __restrict__ g,
                          const float* __restrict__ b, float* __restrict__ Y) {
    __shared__ float red[256];
    const int row = blockIdx.x, tid = threadIdx.x;
    const size_t base = (size_t)row * DD;
    float v = X[base + tid];
    red[tid] = v; __syncthreads();
    for (int s = 128; s > 0; s >>= 1) { if (tid < s) red[tid] += red[tid + s]; __syncthreads(); }
    float m = red[0] * (1.f / DD);
    __syncthreads();
    float c = v - m;
    red[tid] = c * c; __syncthreads();
    for (int s = 128; s > 0; s >>= 1) { if (tid < s) red[tid] += red[tid + s]; __syncthreads(); }
    float var = red[0] * (1.f / DD);
    Y[base + tid] = c * rsqrtf(var + 1e-5f) * g[tid] + b[tid];
}

// ---------------- depthwise conv k=3, zero pad -------------------------------
__global__ void conv_kernel(const float* __restrict__ Xn, const float* __restrict__ cw,
                            const float* __restrict__ cb, float* __restrict__ Xc) {
    const size_t i = (size_t)blockIdx.x * 256 + threadIdx.x;  // < BLn*DD
    const int d = (int)(i & 255);
    const int l = (int)((i >> 8) & (LL - 1));
    float w0 = cw[d * 3 + 0], w1 = cw[d * 3 + 1], w2 = cw[d * 3 + 2];
    float xm = (l > 0)      ? Xn[i - DD] : 0.f;
    float x0 = Xn[i];
    float xp = (l < LL - 1) ? Xn[i + DD] : 0.f;
    Xc[i] = fmaf(w0, xm, fmaf(w1, x0, fmaf(w2, xp, cb[d])));
}

__global__ void mul_kernel(const float* __restrict__ a, const float* __restrict__ b,
                           float* __restrict__ c) {
    size_t i = (size_t)blockIdx.x * 256 + threadIdx.x;
    c[i] = a[i] * b[i];
}

// ---------------- SSM scan: thread = one (b,d,n) chain ----------------------
__global__ void scan_kernel(const float* __restrict__ delta, const float* __restrict__ Bt,
                            const float* __restrict__ Ct, const float* __restrict__ loglam,
                            __hip_bfloat16* __restrict__ ys, float* __restrict__ hfin) {
    const int blk = blockIdx.x;
    const int b = blk >> 4, dblk = blk & 15;
    const int tid = threadIdx.x;
    const int d = dblk * 16 + (tid >> 4);
    const int n = tid & 15;
    const float lam = softplusf(loglam[d * NN + n]);
    float hv = 0.f;
    const size_t baseD = (size_t)b * LL * DD;
    const size_t baseN = (size_t)b * LL * NN;
    for (int l = 0; l < LL; ++l) {
        float dv = delta[baseD + (size_t)l * DD + d];
        float bt = Bt[baseN + (size_t)l * NN + n];
        float a = __expf(-dv * lam);
        hv = fmaf(a, hv, dv * bt);
        if (ys) {
            float ct = Ct[baseN + (size_t)l * NN + n];
            ys[(size_t)(b * LL + l) * (DD * NN) + dblk * 256 + tid] = __float2bfloat16(hv * ct);
        }
    }
    if (hfin) hfin[(size_t)b * (DD * NN) + dblk * 256 + tid] = hv;
}

// ---------------- layer-2 last-position SSM output ---------------------------
__global__ void last_ssm_kernel(const float* __restrict__ hfin, const float* __restrict__ Ct,
                                const float* __restrict__ wo, const float* __restrict__ bo,
                                float* __restrict__ outlast) {
    __shared__ float hC[4096];
    const int b = blockIdx.x, tid = threadIdx.x;
    const size_t ctbase = ((size_t)b * LL + (LL - 1)) * NN;
    for (int p = tid; p < 4096; p += 256)
        hC[p] = hfin[(size_t)b * 4096 + p] * Ct[ctbase + (p & 15)];
    __syncthreads();
    float acc = bo[tid];
    for (int p = 0; p < 4096; ++p)
        acc = fmaf(hC[p], wo[(size_t)p * DD + tid], acc);
    outlast[b * DD + tid] = acc;
}

// ---------------- layer-2 last-position gate + proj + residual --------------
__global__ void last_proj_kernel(const float* __restrict__ xn, const float* __restrict__ outlast,
                                 const float* __restrict__ gw, const float* __restrict__ gb,
                                 const float* __restrict__ pw, const float* __restrict__ pb,
                                 const float* __restrict__ resid, float* __restrict__ xtlast) {
    __shared__ float xrow[256];
    __shared__ float xsg[256];
    const int b = blockIdx.x, d = threadIdx.x;
    const size_t rbase = ((size_t)b * LL + (LL - 1)) * DD;
    xrow[d] = xn[rbase + d];
    __syncthreads();
    float acc = gb[d];
    for (int k = 0; k < 256; ++k) acc = fmaf(xrow[k], gw[(size_t)k * DD + d], acc);
    float g = sigmoidf_(acc);
    xsg[d] = outlast[b * DD + d] * g;
    __syncthreads();
    float acc2 = pb[d];
    for (int k = 0; k < 256; ++k) acc2 = fmaf(xsg[k], pw[(size_t)k * DD + d], acc2);
    xtlast[b * DD + d] = acc2 + resid[rbase + d];
}

// ---------------- fp32 DFT: 5 freqs/thread, incremental twiddle -------------
__global__ void dft_kernel(const float* __restrict__ h, const float* __restrict__ tab,
                           float* __restrict__ Xre, float* __restrict__ Xim) {
    __shared__ float ct[2048];
    __shared__ float st[2048];
    const int tid = threadIdx.x;
    for (int i = tid; i < 2048; i += 256) { ct[i] = tab[i]; st[i] = tab[2048 + i]; }
    __syncthreads();
    const int b = blockIdx.y;
    const int f0 = blockIdx.x * 5;
    float ar[5] = {}, ai[5] = {};
    float twr[5], twi[5], sr[5], si[5];
#pragma unroll
    for (int j = 0; j < 5; ++j) { int f = f0 + j; sr[j] = ct[f]; si[j] = -st[f]; }
    const float* hp = h + (size_t)b * LL * DD + tid;
    for (int t = 0; t < LL; ++t) {
        if ((t & 63) == 0) {   // exact refresh: kills rotation drift
#pragma unroll
            for (int j = 0; j < 5; ++j) {
                int k = ((f0 + j) * t) & 2047;
                twr[j] = ct[k]; twi[j] = -st[k];
            }
        }
        float v = hp[(size_t)t * DD];
#pragma unroll
        for (int j = 0; j < 5; ++j) {
            ar[j] = fmaf(v, twr[j], ar[j]);
            ai[j] = fmaf(v, twi[j], ai[j]);
            float nr = fmaf(twr[j], sr[j], -twi[j] * si[j]);
            twi[j] = fmaf(twr[j], si[j], twi[j] * sr[j]);
            twr[j] = nr;
        }
    }
#pragma unroll
    for (int j = 0; j < 5; ++j) {
        int f = f0 + j;
        Xre[(size_t)f * 1024 + b * 256 + tid] = ar[j];
        Xim[(size_t)f * 1024 + b * 256 + tid] = ai[j];
    }
}

// ---------------- mag[f] = mean |X[b,f,d]| over 1024 channels ---------------
__global__ void mag_kernel(const float* __restrict__ Xre, const float* __restrict__ Xim,
                           float* __restrict__ mag) {
    __shared__ float red[256];
    const int f = blockIdx.x, tid = threadIdx.x;
    float s = 0.f;
#pragma unroll
    for (int q = 0; q < 4; ++q) {
        int i = q * 256 + tid;
        float re = Xre[(size_t)f * 1024 + i], im = Xim[(size_t)f * 1024 + i];
        s += sqrtf(re * re + im * im);
    }
    red[tid] = s; __syncthreads();
    for (int sft = 128; sft > 0; sft >>= 1) { if (tid < sft) red[tid] += red[tid + sft]; __syncthreads(); }
    if (tid == 0) mag[f] = red[0] * (1.f / 1024.f);
}

// ---------------- top-32, jax.lax.top_k order (desc, ties->lower idx) -------
__global__ void topk_kernel(const float* __restrict__ mag, int* __restrict__ sel) {
    __shared__ float vals[1056];
    __shared__ float rv[256];
    __shared__ int ri[256];
    const int tid = threadIdx.x;
    for (int i = tid; i < 1056; i += 256) vals[i] = (i < FCNT) ? mag[i] : -1e30f;
    __syncthreads();
    for (int k = 0; k < 32; ++k) {
        float bv = -1e30f; int bi = 0x7fffffff;
        for (int i = tid; i < FCNT; i += 256) {
            float v = vals[i];
            if (v > bv) { bv = v; bi = i; }     // ascending i keeps lowest index on tie
        }
        rv[tid] = bv; ri[tid] = bi; __syncthreads();
        for (int s = 128; s > 0; s >>= 1) {
            if (tid < s) {
                if (rv[tid + s] > rv[tid] ||
                    (rv[tid + s] == rv[tid] && ri[tid + s] < ri[tid])) {
                    rv[tid] = rv[tid + s]; ri[tid] = ri[tid + s];
                }
            }
            __syncthreads();
        }
        if (tid == 0) { sel[k] = ri[0]; vals[ri[0]] = -1e30f; }
        __syncthreads();
    }
}

// ---------------- xs_spectral at t = L-1 only --------------------------------
__global__ void xslast_kernel(const float* __restrict__ Xre, const float* __restrict__ Xim,
                              const int* __restrict__ sel, const float* __restrict__ fr,
                              const float* __restrict__ fi, const float* __restrict__ tab,
                              float* __restrict__ xsl) {
    const int b = blockIdx.x, d = threadIdx.x;
    float acc = 0.f;
    for (int j = 0; j < 32; ++j) {
        int f = sel[j];
        float xr = Xre[(size_t)f * 1024 + b * 256 + d];
        float xi = Xim[(size_t)f * 1024 + b * 256 + d];
        float frv = fr[d * KK + j], fiv = fi[d * KK + j];
        float xor_ = xr * frv - xi * fiv;   // Re(X*filt)
        float xoi  = xr * fiv + xi * frv;   // Im(X*filt)
        int kk2 = (f * (LL - 1)) & (LL - 1);
        float c = tab[kk2], s = tab[2048 + kk2];   // e^{+2pi i f (L-1)/L}
        float w = (f == 0 || f == 1024) ? 1.f : 2.f;
        acc = fmaf(w, xor_ * c - xoi * s, acc);
    }
    xsl[b * DD + d] = acc * (1.f / LL);
}

// ---------------- final head: mix, LN, MLP -> out (B,2) ----------------------
__global__ void head_kernel(const float* __restrict__ xtlast, const float* __restrict__ xslast,
                            const float* __restrict__ alpha, const float* __restrict__ beta,
                            const float* __restrict__ gout, const float* __restrict__ bout,
                            const float* __restrict__ hw1, const float* __restrict__ hb1,
                            const float* __restrict__ hw2, const float* __restrict__ hb2,
                            float* __restrict__ out) {
    __shared__ float red[256];
    __shared__ float z[256];
    __shared__ float hid[128];
    const int b = blockIdx.x, tid = threadIdx.x;
    float zv = alpha[tid] * xtlast[b * 256 + tid] + beta[tid] * xslast[b * 256 + tid];
    red[tid] = zv; __syncthreads();
    for (int s = 128; s > 0; s >>= 1) { if (tid < s) red[tid] += red[tid + s]; __syncthreads(); }
    float m = red[0] * (1.f / DD);
    __syncthreads();
    float c = zv - m;
    red[tid] = c * c; __syncthreads();
    for (int s = 128; s > 0; s >>= 1) { if (tid < s) red[tid] += red[tid + s]; __syncthreads(); }
    float var = red[0] * (1.f / DD);
    z[tid] = c * rsqrtf(var + 1e-5f) * gout[tid] + bout[tid];
    __syncthreads();
    if (tid < 128) {
        float a = hb1[tid];
        for (int k = 0; k < 256; ++k) a = fmaf(z[k], hw1[(size_t)k * 128 + tid], a);
        hid[tid] = a * sigmoidf_(a);   // silu
    }
    __syncthreads();
    if (tid < 2) {
        float a = hb2[tid];
        for (int k = 0; k < 128; ++k) a = fmaf(hid[k], hw2[(size_t)k * 2 + tid], a);
        out[b * 2 + tid] = a;
    }
}

extern "C" void kernel_launch(void* const* d_in, const int* in_sizes, int n_in,
                              void* d_out, int out_size, void* d_ws, size_t ws_size,
                              hipStream_t stream) {
    const float* x      = (const float*)d_in[0];
    const float* w_in   = (const float*)d_in[1];
    const float* b_in   = (const float*)d_in[2];
    const float* ln_g   = (const float*)d_in[3];
    const float* ln_b   = (const float*)d_in[4];
    const float* conv_w = (const float*)d_in[5];
    const float* conv_b = (const float*)d_in[6];
    const float* loglam = (const float*)d_in[7];
    const float* wd     = (const float*)d_in[8];
    const float* bd     = (const float*)d_in[9];
    const float* wb     = (const float*)d_in[10];
    const float* wc     = (const float*)d_in[11];
    const float* wo     = (const float*)d_in[12];
    const float* bo     = (const float*)d_in[13];
    const float* gw     = (const float*)d_in[14];
    const float* gb     = (const float*)d_in[15];
    const float* pw     = (const float*)d_in[16];
    const float* pb     = (const float*)d_in[17];
    const float* fr     = (const float*)d_in[18];
    const float* fi     = (const float*)d_in[19];
    const float* alpha  = (const float*)d_in[20];
    const float* beta   = (const float*)d_in[21];
    const float* gout   = (const float*)d_in[22];
    const float* bout   = (const float*)d_in[23];
    const float* hw1    = (const float*)d_in[24];
    const float* hb1    = (const float*)d_in[25];
    const float* hw2    = (const float*)d_in[26];
    const float* hb2    = (const float*)d_in[27];

    float* ws = (float*)d_ws;
    size_t o = 0;
    float* h       = ws + o; o += (size_t)BLn * DD;
    float* xt1     = ws + o; o += (size_t)BLn * DD;
    float* xn      = ws + o; o += (size_t)BLn * DD;
    float* xc      = ws + o; o += (size_t)BLn * DD;
    float* delta   = ws + o; o += (size_t)BLn * DD;
    float* gatebuf = ws + o; o += (size_t)BLn * DD;
    float* ssmout  = ws + o; o += (size_t)BLn * DD;
    float* xsg     = ws + o; o += (size_t)BLn * DD;
    float* Btm     = ws + o; o += (size_t)BLn * NN;
    float* Ctm     = ws + o; o += (size_t)BLn * NN;
    float* tab     = ws + o; o += 4096;
    float* Xre     = ws + o; o += (size_t)FCNT * 1024;
    float* Xim     = ws + o; o += (size_t)FCNT * 1024;
    float* magb    = ws + o; o += 1056;
    int*   sel     = (int*)(ws + o); o += 32;
    float* hfin    = ws + o; o += (size_t)BB * DD * NN;
    float* outlast = ws + o; o += BB * DD;
    float* xtlast  = ws + o; o += BB * DD;
    float* xslast  = ws + o; o += BB * DD;
    __hip_bfloat16* ys = (__hip_bfloat16*)(ws + o); o += (size_t)BLn * DD * NN / 2;

    const dim3 blk(256);

    twiddle_kernel<<<8, blk, 0, stream>>>(tab);

    // h = x @ w_in + b_in
    gemm64<float><<<dim3(DD / 64, BLn / 64), blk, 0, stream>>>(
        x, w_in, b_in, nullptr, h, BLn, DD, INF_, 0);

    const float* cur = h;
    for (int layer = 0; layer < 2; ++layer) {
        ln_kernel<<<BLn, blk, 0, stream>>>(cur, ln_g + layer * DD, ln_b + layer * DD, xn);
        conv_kernel<<<(BLn * DD) / 256, blk, 0, stream>>>(xn, conv_w + layer * DD * 3,
                                                          conv_b + layer * DD, xc);
        gemm64<float><<<dim3(DD / 64, BLn / 64), blk, 0, stream>>>(
            xc, wd + (size_t)layer * DD * DD, bd + layer * DD, nullptr, delta, BLn, DD, DD, 1);
        gemm_n16<<<BLn / 16, blk, 0, stream>>>(xc, wb + layer * DD * NN, Btm);
        gemm_n16<<<BLn / 16, blk, 0, stream>>>(xc, wc + layer * DD * NN, Ctm);

        if (layer == 0) {
            scan_kernel<<<BB * 16, blk, 0, stream>>>(delta, Btm, Ctm,
                                                     loglam + layer * DD * NN, ys, nullptr);
            gemm64<__hip_bfloat16><<<dim3(DD / 64, BLn / 64), blk, 0, stream>>>(
                ys, wo + (size_t)layer * DD * NN * DD, bo + layer * DD, nullptr,
                ssmout, BLn, DD, DD * NN, 0);
            gemm64<float><<<dim3(DD / 64, BLn / 64), blk, 0, stream>>>(
                xn, gw + (size_t)layer * DD * DD, gb + layer * DD, nullptr,
                gatebuf, BLn, DD, DD, 2);
            mul_kernel<<<(BLn * DD) / 256, blk, 0, stream>>>(ssmout, gatebuf, xsg);
            gemm64<float><<<dim3(DD / 64, BLn / 64), blk, 0, stream>>>(
                xsg, pw + (size_t)layer * DD * DD, pb + layer * DD, cur, xt1, BLn, DD, DD, 0);
            cur = xt1;
        } else {
            scan_kernel<<<BB * 16, blk, 0, stream>>>(delta, Btm, Ctm,
                                                     loglam + layer * DD * NN, nullptr, hfin);
            last_ssm_kernel<<<BB, blk, 0, stream>>>(hfin, Ctm,
                                                    wo + (size_t)layer * DD * NN * DD,
                                                    bo + layer * DD, outlast);
            last_proj_kernel<<<BB, blk, 0, stream>>>(xn, outlast,
                                                     gw + (size_t)layer * DD * DD, gb + layer * DD,
                                                     pw + (size_t)layer * DD * DD, pb + layer * DD,
                                                     cur, xtlast);
        }
    }

    // spectral path on h (only t=L-1 needed downstream)
    dft_kernel<<<dim3(FCNT / 5, BB), blk, 0, stream>>>(h, tab, Xre, Xim);
    mag_kernel<<<FCNT, blk, 0, stream>>>(Xre, Xim, magb);
    topk_kernel<<<1, blk, 0, stream>>>(magb, sel);
    xslast_kernel<<<BB, blk, 0, stream>>>(Xre, Xim, sel, fr, fi, tab, xslast);

    head_kernel<<<BB, blk, 0, stream>>>(xtlast, xslast, alpha, beta, gout, bout,
                                        hw1, hb1, hw2, hb2, (float*)d_out);
}

// Round 3
// 822.529 us; speedup vs baseline: 2.8521x; 2.8521x over previous
//
#include <hip/hip_runtime.h>
#include <hip/hip_bf16.h>
#include <math.h>

#define BB   4
#define LL   2048
#define INF_ 64
#define DD   256
#define NN   16
#define KK   32
#define BLn  (BB*LL)      // 8192
#define FCNT 1025         // L/2+1

typedef short short8 __attribute__((ext_vector_type(8)));
typedef float f32x4  __attribute__((ext_vector_type(4)));

__device__ __forceinline__ float softplusf(float x) {
    return x > 20.f ? x : log1pf(__expf(x));
}
__device__ __forceinline__ float sigmoidf_(float x) {
    return 1.f / (1.f + __expf(-x));
}

// ---------------- twiddle table: tab[k]=cos(2*pi*k/2048), tab[2048+k]=sin ----
__global__ void twiddle_kernel(float* tab) {
    int i = blockIdx.x * 256 + threadIdx.x;
    if (i < 2048) {
        double ang = 2.0 * 3.14159265358979323846 * (double)i / 2048.0;
        tab[i]        = (float)cos(ang);
        tab[2048 + i] = (float)sin(ang);
    }
}

// ---------------- transpose+cast weights: W[K][N] fp32 -> Wt[N][K] bf16 -----
__global__ void tcast_kernel(const float* __restrict__ W, __hip_bfloat16* __restrict__ Wt,
                             int K, int N) {
    __shared__ float t[32][33];
    const int k0 = blockIdx.y * 32, n0 = blockIdx.x * 32;
    const int tx = threadIdx.x & 31, ty = threadIdx.x >> 5;   // 256 thr: ty 0..7
    for (int r = ty; r < 32; r += 8) t[r][tx] = W[(size_t)(k0 + r) * N + n0 + tx];
    __syncthreads();
    for (int r = ty; r < 32; r += 8)
        Wt[(size_t)(n0 + r) * K + k0 + tx] = __float2bfloat16(t[tx][r]);
}

// ---------------- fp32 GEMM (input projection only, K=64) -------------------
__global__ void gemm64(const float* __restrict__ A, const float* __restrict__ W,
                       const float* __restrict__ bias, float* __restrict__ C,
                       int M, int N, int K) {
    __shared__ float As[16][68];
    __shared__ float Ws[16][64];
    const int tid = threadIdx.x;
    const int tx = tid & 15, ty = tid >> 4;
    const int row0 = blockIdx.y * 64, col0 = blockIdx.x * 64;
    float acc[4][4] = {};
    for (int k0 = 0; k0 < K; k0 += 16) {
#pragma unroll
        for (int e = 0; e < 4; ++e) {
            int p = e * 256 + tid;
            int kk = p & 15, m = p >> 4;
            As[kk][m] = A[(size_t)(row0 + m) * K + k0 + kk];
        }
#pragma unroll
        for (int e = 0; e < 4; ++e) {
            int p = e * 256 + tid;
            int kk = p >> 6, j = p & 63;
            Ws[kk][j] = W[(size_t)(k0 + kk) * N + col0 + j];
        }
        __syncthreads();
#pragma unroll
        for (int kk = 0; kk < 16; ++kk) {
            float4 a4 = *(const float4*)&As[kk][ty * 4];
            float4 w4 = *(const float4*)&Ws[kk][tx * 4];
            float av[4] = {a4.x, a4.y, a4.z, a4.w};
            float wv[4] = {w4.x, w4.y, w4.z, w4.w};
#pragma unroll
            for (int i = 0; i < 4; ++i)
#pragma unroll
                for (int j = 0; j < 4; ++j)
                    acc[i][j] = fmaf(av[i], wv[j], acc[i][j]);
        }
        __syncthreads();
    }
#pragma unroll
    for (int i = 0; i < 4; ++i) {
        int r = row0 + ty * 4 + i;
#pragma unroll
        for (int j = 0; j < 4; ++j) {
            int c = col0 + tx * 4 + j;
            C[(size_t)r * N + c] = acc[i][j] + bias[c];
        }
    }
}

// ---------------- bf16 MFMA GEMM: C = act(A @ Wt^T + bias) [+ addend] -------
// A: [M,K] bf16 row-major; Wt: [N,K] bf16 (pre-transposed). Tile 128x64.
__global__ __launch_bounds__(256)
void gemm_mfma(const __hip_bfloat16* __restrict__ Abf, const __hip_bfloat16* __restrict__ Wt,
               const float* __restrict__ bias, const float* __restrict__ addend,
               float* __restrict__ C, int M, int N, int K, int act) {
    __shared__ alignas(16) short As[128][40];   // pad 32->40: conflict-free b128
    __shared__ alignas(16) short Bs[64][40];
    const int tid = threadIdx.x;
    const int w = tid >> 6, lane = tid & 63;
    const int hi = lane >> 4, lo = lane & 15;
    const int row0 = blockIdx.y * 128, col0 = blockIdx.x * 64;
    const short* A = (const short*)Abf;
    const short* B = (const short*)Wt;
    f32x4 acc[2][4];
    f32x4 zz = {0.f, 0.f, 0.f, 0.f};
#pragma unroll
    for (int m = 0; m < 2; ++m)
#pragma unroll
        for (int n = 0; n < 4; ++n) acc[m][n] = zz;
    // staging geometry: A tile = 128x32 shorts = 512 short8-chunks (2/thread)
    //                   B tile =  64x32 shorts = 256 short8-chunks (1/thread)
    const int ra0 = tid >> 1;                    // unused-free; chunk math below
    (void)ra0;
    for (int k0 = 0; k0 < K; k0 += 32) {
#pragma unroll
        for (int e = 0; e < 2; ++e) {
            int c = e * 256 + tid;
            int r = c >> 2, col = (c & 3) * 8;
            *(short8*)&As[r][col] = *(const short8*)&A[(size_t)(row0 + r) * K + k0 + col];
        }
        {
            int r = tid >> 2, col = (tid & 3) * 8;
            *(short8*)&Bs[r][col] = *(const short8*)&B[(size_t)(col0 + r) * K + k0 + col];
        }
        __syncthreads();
        short8 af[2], bfr[4];
#pragma unroll
        for (int m = 0; m < 2; ++m)
            af[m] = *(const short8*)&As[w * 32 + m * 16 + lo][hi * 8];
#pragma unroll
        for (int n = 0; n < 4; ++n)
            bfr[n] = *(const short8*)&Bs[n * 16 + lo][hi * 8];
#pragma unroll
        for (int m = 0; m < 2; ++m)
#pragma unroll
            for (int n = 0; n < 4; ++n)
                acc[m][n] = __builtin_amdgcn_mfma_f32_16x16x32_bf16(af[m], bfr[n], acc[m][n], 0, 0, 0);
        __syncthreads();
    }
#pragma unroll
    for (int m = 0; m < 2; ++m) {
#pragma unroll
        for (int n = 0; n < 4; ++n) {
#pragma unroll
            for (int r = 0; r < 4; ++r) {
                int row = row0 + w * 32 + m * 16 + hi * 4 + r;
                int col = col0 + n * 16 + lo;
                float v = acc[m][n][r];
                if (bias) v += bias[col];
                if (act == 1) v = softplusf(v);
                else if (act == 2) v = sigmoidf_(v);
                if (addend) v += addend[(size_t)row * N + col];
                C[(size_t)row * N + col] = v;
            }
        }
    }
}

// ---------------- small GEMM: C[M,16] = A[M,256] @ W[256,16] (no bias) ------
__global__ void gemm_n16(const float* __restrict__ A, const float* __restrict__ W,
                         float* __restrict__ C) {
    __shared__ float As[16][260];
    __shared__ float Ws[256][16];
    const int tid = threadIdx.x;
    const int row0 = blockIdx.x * 16;
#pragma unroll
    for (int e = 0; e < 16; ++e)
        As[e][tid] = A[(size_t)(row0 + e) * 256 + tid];
#pragma unroll
    for (int e = 0; e < 16; ++e) {
        int p = e * 256 + tid;
        Ws[p >> 4][p & 15] = W[p];
    }
    __syncthreads();
    const int r = tid >> 4, n = tid & 15;
    float acc = 0.f;
#pragma unroll 8
    for (int k = 0; k < 256; ++k)
        acc = fmaf(As[r][k], Ws[k][n], acc);
    C[(size_t)(row0 + r) * 16 + n] = acc;
}

// ---------------- LayerNorm over D=256 (fp32 out + bf16 out) ----------------
__global__ void ln_kernel(const float* __restrict__ X, const float* __restrict__ g,
                          const float* __restrict__ b, float* __restrict__ Y,
                          __hip_bfloat16* __restrict__ Ybf) {
    __shared__ float red[256];
    const int row = blockIdx.x, tid = threadIdx.x;
    const size_t base = (size_t)row * DD;
    float v = X[base + tid];
    red[tid] = v; __syncthreads();
    for (int s = 128; s > 0; s >>= 1) { if (tid < s) red[tid] += red[tid + s]; __syncthreads(); }
    float m = red[0] * (1.f / DD);
    __syncthreads();
    float c = v - m;
    red[tid] = c * c; __syncthreads();
    for (int s = 128; s > 0; s >>= 1) { if (tid < s) red[tid] += red[tid + s]; __syncthreads(); }
    float var = red[0] * (1.f / DD);
    float y = c * rsqrtf(var + 1e-5f) * g[tid] + b[tid];
    Y[base + tid] = y;
    Ybf[base + tid] = __float2bfloat16(y);
}

// ---------------- depthwise conv k=3 (fp32 out + bf16 out) ------------------
__global__ void conv_kernel(const float* __restrict__ Xn, const float* __restrict__ cw,
                            const float* __restrict__ cb, float* __restrict__ Xc,
                            __hip_bfloat16* __restrict__ Xcbf) {
    const size_t i = (size_t)blockIdx.x * 256 + threadIdx.x;
    const int d = (int)(i & 255);
    const int l = (int)((i >> 8) & (LL - 1));
    float w0 = cw[d * 3 + 0], w1 = cw[d * 3 + 1], w2 = cw[d * 3 + 2];
    float xm = (l > 0)      ? Xn[i - DD] : 0.f;
    float x0 = Xn[i];
    float xp = (l < LL - 1) ? Xn[i + DD] : 0.f;
    float y = fmaf(w0, xm, fmaf(w1, x0, fmaf(w2, xp, cb[d])));
    Xc[i] = y;
    Xcbf[i] = __float2bfloat16(y);
}

__global__ void mulbf_kernel(const float* __restrict__ a, const float* __restrict__ b,
                             __hip_bfloat16* __restrict__ c) {
    size_t i = (size_t)blockIdx.x * 256 + threadIdx.x;
    c[i] = __float2bfloat16(a[i] * b[i]);
}

// ---------------- chunked SSM scan ------------------------------------------
// PHASE 0: per-chunk (A-product, local h from 0) -> sA, sB
// PHASE 1: recompute interior with true h0 (hstart), write ys = bf16(h*Ct)
template<int PHASE>
__global__ void ssm_chunk_kernel(const float* __restrict__ delta, const float* __restrict__ Bt,
                                 const float* __restrict__ Ct, const float* __restrict__ loglam,
                                 const float* __restrict__ hstart,
                                 float* __restrict__ sA, float* __restrict__ sB,
                                 __hip_bfloat16* __restrict__ ys) {
    __shared__ float dl[128][16];
    __shared__ float btl[128][16];
    __shared__ float ctl[128][16];
    const int dblk = blockIdx.x, c = blockIdx.y, b = blockIdx.z;
    const int tid = threadIdx.x;
    const size_t lbase = (size_t)b * LL + c * 128;
    for (int i = tid; i < 2048; i += 256) {
        int l = i >> 4, q = i & 15;
        dl[l][q]  = delta[(lbase + l) * DD + dblk * 16 + q];
        btl[l][q] = Bt[(lbase + l) * NN + q];
        if (PHASE == 1) ctl[l][q] = Ct[(lbase + l) * NN + q];
    }
    __syncthreads();
    const int dloc = tid >> 4, n = tid & 15;
    const float lam = softplusf(loglam[(dblk * 16 + dloc) * NN + n]);
    float hv = 0.f, ap = 1.f;
    if (PHASE == 1) hv = hstart[((size_t)(b * 16 + c)) * 4096 + dblk * 256 + tid];
    for (int l = 0; l < 128; ++l) {
        float dv = dl[l][dloc];
        float a = __expf(-dv * lam);
        hv = fmaf(a, hv, dv * btl[l][n]);
        if (PHASE == 0) ap *= a;
        else ys[(lbase + l) * (DD * NN) + dblk * 256 + tid] = __float2bfloat16(hv * ctl[l][n]);
    }
    if (PHASE == 0) {
        size_t oi = ((size_t)(b * 16 + c)) * 4096 + dblk * 256 + tid;
        sA[oi] = ap; sB[oi] = hv;
    }
}

// chunk-summary combine: h at chunk starts (+ optional final state)
__global__ void ssm_comb_kernel(const float* __restrict__ sA, const float* __restrict__ sB,
                                float* __restrict__ hstart, float* __restrict__ hfin) {
    const int id = blockIdx.x * 256 + threadIdx.x;   // < BB*4096
    const int b = id >> 12, col = id & 4095;
    float h = 0.f;
#pragma unroll
    for (int c = 0; c < 16; ++c) {
        size_t oi = ((size_t)(b * 16 + c)) * 4096 + col;
        hstart[oi] = h;
        h = fmaf(sA[oi], h, sB[oi]);
    }
    if (hfin) hfin[(size_t)b * 4096 + col] = h;
}

// ---------------- layer-2 last-position SSM output ---------------------------
__global__ void last_ssm_kernel(const float* __restrict__ hfin, const float* __restrict__ Ct,
                                const float* __restrict__ wo, const float* __restrict__ bo,
                                float* __restrict__ outlast) {
    __shared__ float hC[4096];
    const int b = blockIdx.x, tid = threadIdx.x;
    const size_t ctbase = ((size_t)b * LL + (LL - 1)) * NN;
    for (int p = tid; p < 4096; p += 256)
        hC[p] = hfin[(size_t)b * 4096 + p] * Ct[ctbase + (p & 15)];
    __syncthreads();
    float acc = bo[tid];
    for (int p = 0; p < 4096; ++p)
        acc = fmaf(hC[p], wo[(size_t)p * DD + tid], acc);
    outlast[b * DD + tid] = acc;
}

// ---------------- layer-2 last-position gate + proj + residual --------------
__global__ void last_proj_kernel(const float* __restrict__ xn, const float* __restrict__ outlast,
                                 const float* __restrict__ gw, const float* __restrict__ gb,
                                 const float* __restrict__ pw, const float* __restrict__ pb,
                                 const float* __restrict__ resid, float* __restrict__ xtlast) {
    __shared__ float xrow[256];
    __shared__ float xsg[256];
    const int b = blockIdx.x, d = threadIdx.x;
    const size_t rbase = ((size_t)b * LL + (LL - 1)) * DD;
    xrow[d] = xn[rbase + d];
    __syncthreads();
    float acc = gb[d];
    for (int k = 0; k < 256; ++k) acc = fmaf(xrow[k], gw[(size_t)k * DD + d], acc);
    float g = sigmoidf_(acc);
    xsg[d] = outlast[b * DD + d] * g;
    __syncthreads();
    float acc2 = pb[d];
    for (int k = 0; k < 256; ++k) acc2 = fmaf(xsg[k], pw[(size_t)k * DD + d], acc2);
    xtlast[b * DD + d] = acc2 + resid[rbase + d];
}

// ---------------- fp32 DFT: 5 freqs/thread, incremental twiddle -------------
__global__ void dft_kernel(const float* __restrict__ h, const float* __restrict__ tab,
                           float* __restrict__ Xre, float* __restrict__ Xim) {
    __shared__ float ct[2048];
    __shared__ float st[2048];
    const int tid = threadIdx.x;
    for (int i = tid; i < 2048; i += 256) { ct[i] = tab[i]; st[i] = tab[2048 + i]; }
    __syncthreads();
    const int b = blockIdx.y;
    const int f0 = blockIdx.x * 5;
    float ar[5] = {}, ai[5] = {};
    float twr[5], twi[5], sr[5], si[5];
#pragma unroll
    for (int j = 0; j < 5; ++j) { int f = f0 + j; sr[j] = ct[f]; si[j] = -st[f]; }
    const float* hp = h + (size_t)b * LL * DD + tid;
    for (int t = 0; t < LL; ++t) {
        if ((t & 63) == 0) {
#pragma unroll
            for (int j = 0; j < 5; ++j) {
                int k = ((f0 + j) * t) & 2047;
                twr[j] = ct[k]; twi[j] = -st[k];
            }
        }
        float v = hp[(size_t)t * DD];
#pragma unroll
        for (int j = 0; j < 5; ++j) {
            ar[j] = fmaf(v, twr[j], ar[j]);
            ai[j] = fmaf(v, twi[j], ai[j]);
            float nr = fmaf(twr[j], sr[j], -twi[j] * si[j]);
            twi[j] = fmaf(twr[j], si[j], twi[j] * sr[j]);
            twr[j] = nr;
        }
    }
#pragma unroll
    for (int j = 0; j < 5; ++j) {
        int f = f0 + j;
        Xre[(size_t)f * 1024 + b * 256 + tid] = ar[j];
        Xim[(size_t)f * 1024 + b * 256 + tid] = ai[j];
    }
}

// ---------------- mag[f] = mean |X[b,f,d]| over 1024 channels ---------------
__global__ void mag_kernel(const float* __restrict__ Xre, const float* __restrict__ Xim,
                           float* __restrict__ mag) {
    __shared__ float red[256];
    const int f = blockIdx.x, tid = threadIdx.x;
    float s = 0.f;
#pragma unroll
    for (int q = 0; q < 4; ++q) {
        int i = q * 256 + tid;
        float re = Xre[(size_t)f * 1024 + i], im = Xim[(size_t)f * 1024 + i];
        s += sqrtf(re * re + im * im);
    }
    red[tid] = s; __syncthreads();
    for (int sft = 128; sft > 0; sft >>= 1) { if (tid < sft) red[tid] += red[tid + sft]; __syncthreads(); }
    if (tid == 0) mag[f] = red[0] * (1.f / 1024.f);
}

// ---------------- top-32, jax.lax.top_k order (desc, ties->lower idx) -------
__global__ void topk_kernel(const float* __restrict__ mag, int* __restrict__ sel) {
    __shared__ float vals[1056];
    __shared__ float rv[256];
    __shared__ int ri[256];
    const int tid = threadIdx.x;
    for (int i = tid; i < 1056; i += 256) vals[i] = (i < FCNT) ? mag[i] : -1e30f;
    __syncthreads();
    for (int k = 0; k < 32; ++k) {
        float bv = -1e30f; int bi = 0x7fffffff;
        for (int i = tid; i < FCNT; i += 256) {
            float v = vals[i];
            if (v > bv) { bv = v; bi = i; }
        }
        rv[tid] = bv; ri[tid] = bi; __syncthreads();
        for (int s = 128; s > 0; s >>= 1) {
            if (tid < s) {
                if (rv[tid + s] > rv[tid] ||
                    (rv[tid + s] == rv[tid] && ri[tid + s] < ri[tid])) {
                    rv[tid] = rv[tid + s]; ri[tid] = ri[tid + s];
                }
            }
            __syncthreads();
        }
        if (tid == 0) { sel[k] = ri[0]; vals[ri[0]] = -1e30f; }
        __syncthreads();
    }
}

// ---------------- xs_spectral at t = L-1 only --------------------------------
__global__ void xslast_kernel(const float* __restrict__ Xre, const float* __restrict__ Xim,
                              const int* __restrict__ sel, const float* __restrict__ fr,
                              const float* __restrict__ fi, const float* __restrict__ tab,
                              float* __restrict__ xsl) {
    const int b = blockIdx.x, d = threadIdx.x;
    float acc = 0.f;
    for (int j = 0; j < 32; ++j) {
        int f = sel[j];
        float xr = Xre[(size_t)f * 1024 + b * 256 + d];
        float xi = Xim[(size_t)f * 1024 + b * 256 + d];
        float frv = fr[d * KK + j], fiv = fi[d * KK + j];
        float xor_ = xr * frv - xi * fiv;
        float xoi  = xr * fiv + xi * frv;
        int kk2 = (f * (LL - 1)) & (LL - 1);
        float c = tab[kk2], s = tab[2048 + kk2];
        float w = (f == 0 || f == 1024) ? 1.f : 2.f;
        acc = fmaf(w, xor_ * c - xoi * s, acc);
    }
    xsl[b * DD + d] = acc * (1.f / LL);
}

// ---------------- final head: mix, LN, MLP -> out (B,2) ----------------------
__global__ void head_kernel(const float* __restrict__ xtlast, const float* __restrict__ xslast,
                            const float* __restrict__ alpha, const float* __restrict__ beta,
                            const float* __restrict__ gout, const float* __restrict__ bout,
                            const float* __restrict__ hw1, const float* __restrict__ hb1,
                            const float* __restrict__ hw2, const float* __restrict__ hb2,
                            float* __restrict__ out) {
    __shared__ float red[256];
    __shared__ float z[256];
    __shared__ float hid[128];
    const int b = blockIdx.x, tid = threadIdx.x;
    float zv = alpha[tid] * xtlast[b * 256 + tid] + beta[tid] * xslast[b * 256 + tid];
    red[tid] = zv; __syncthreads();
    for (int s = 128; s > 0; s >>= 1) { if (tid < s) red[tid] += red[tid + s]; __syncthreads(); }
    float m = red[0] * (1.f / DD);
    __syncthreads();
    float c = zv - m;
    red[tid] = c * c; __syncthreads();
    for (int s = 128; s > 0; s >>= 1) { if (tid < s) red[tid] += red[tid + s]; __syncthreads(); }
    float var = red[0] * (1.f / DD);
    z[tid] = c * rsqrtf(var + 1e-5f) * gout[tid] + bout[tid];
    __syncthreads();
    if (tid < 128) {
        float a = hb1[tid];
        for (int k = 0; k < 256; ++k) a = fmaf(z[k], hw1[(size_t)k * 128 + tid], a);
        hid[tid] = a * sigmoidf_(a);
    }
    __syncthreads();
    if (tid < 2) {
        float a = hb2[tid];
        for (int k = 0; k < 128; ++k) a = fmaf(hid[k], hw2[(size_t)k * 2 + tid], a);
        out[b * 2 + tid] = a;
    }
}

extern "C" void kernel_launch(void* const* d_in, const int* in_sizes, int n_in,
                              void* d_out, int out_size, void* d_ws, size_t ws_size,
                              hipStream_t stream) {
    const float* x      = (const float*)d_in[0];
    const float* w_in   = (const float*)d_in[1];
    const float* b_in   = (const float*)d_in[2];
    const float* ln_g   = (const float*)d_in[3];
    const float* ln_b   = (const float*)d_in[4];
    const float* conv_w = (const float*)d_in[5];
    const float* conv_b = (const float*)d_in[6];
    const float* loglam = (const float*)d_in[7];
    const float* wd     = (const float*)d_in[8];
    const float* bd     = (const float*)d_in[9];
    const float* wb     = (const float*)d_in[10];
    const float* wc     = (const float*)d_in[11];
    const float* wo     = (const float*)d_in[12];
    const float* bo     = (const float*)d_in[13];
    const float* gw     = (const float*)d_in[14];
    const float* gb     = (const float*)d_in[15];
    const float* pw     = (const float*)d_in[16];
    const float* pb     = (const float*)d_in[17];
    const float* fr     = (const float*)d_in[18];
    const float* fi     = (const float*)d_in[19];
    const float* alpha  = (const float*)d_in[20];
    const float* beta   = (const float*)d_in[21];
    const float* gout   = (const float*)d_in[22];
    const float* bout   = (const float*)d_in[23];
    const float* hw1    = (const float*)d_in[24];
    const float* hb1    = (const float*)d_in[25];
    const float* hw2    = (const float*)d_in[26];
    const float* hb2    = (const float*)d_in[27];

    float* ws = (float*)d_ws;
    size_t o = 0;
    auto alloc = [&](size_t n) { float* p = ws + o; o += (n + 15) & ~(size_t)15; return p; };

    const size_t BLnDD = (size_t)BLn * DD;
    float* h      = alloc(BLnDD);
    float* xt1    = alloc(BLnDD);
    float* xn     = alloc(BLnDD);   // also reused as gate fp32 output
    float* xc     = alloc(BLnDD);
    float* delta  = alloc(BLnDD);   // also reused as ssmout
    float* Btm    = alloc((size_t)BLn * NN);
    float* Ctm    = alloc((size_t)BLn * NN);
    float* tab    = alloc(4096);
    float* ysf    = alloc(BLnDD * NN / 2);          // ys bf16 region; later Xre/Xim
    float* sA     = alloc((size_t)BB * 16 * 4096);
    float* sB     = alloc((size_t)BB * 16 * 4096);
    float* hst    = alloc((size_t)BB * 16 * 4096);
    float* xnbf_f = alloc(BLnDD / 2);
    float* xcbf_f = alloc(BLnDD / 2);
    float* xsgf   = alloc(BLnDD / 2);
    float* wdt_f  = alloc((size_t)2 * DD * DD / 2);
    float* gwt_f  = alloc((size_t)DD * DD / 2);
    float* pwt_f  = alloc((size_t)DD * DD / 2);
    float* wot_f  = alloc((size_t)DD * NN * DD / 2);
    float* magb   = alloc(1056);
    int*   sel    = (int*)alloc(32);
    float* hfin   = alloc((size_t)BB * DD * NN);
    float* outlast= alloc(BB * DD);
    float* xtlast = alloc(BB * DD);
    float* xslast = alloc(BB * DD);

    __hip_bfloat16* ys    = (__hip_bfloat16*)ysf;
    float*          Xre   = ysf;                       // alias: ys dead before DFT
    float*          Xim   = ysf + (size_t)FCNT * 1024;
    __hip_bfloat16* xn_bf = (__hip_bfloat16*)xnbf_f;
    __hip_bfloat16* xc_bf = (__hip_bfloat16*)xcbf_f;
    __hip_bfloat16* xsg_bf= (__hip_bfloat16*)xsgf;
    __hip_bfloat16* wdt0  = (__hip_bfloat16*)wdt_f;
    __hip_bfloat16* wdt1  = wdt0 + (size_t)DD * DD;
    __hip_bfloat16* gwt   = (__hip_bfloat16*)gwt_f;
    __hip_bfloat16* pwt   = (__hip_bfloat16*)pwt_f;
    __hip_bfloat16* wot   = (__hip_bfloat16*)wot_f;

    const dim3 blk(256);

    twiddle_kernel<<<8, blk, 0, stream>>>(tab);
    tcast_kernel<<<dim3(8, 8),   blk, 0, stream>>>(wd,                    wdt0, DD, DD);
    tcast_kernel<<<dim3(8, 8),   blk, 0, stream>>>(wd + (size_t)DD * DD,  wdt1, DD, DD);
    tcast_kernel<<<dim3(8, 8),   blk, 0, stream>>>(gw,                    gwt,  DD, DD);
    tcast_kernel<<<dim3(8, 8),   blk, 0, stream>>>(pw,                    pwt,  DD, DD);
    tcast_kernel<<<dim3(8, 128), blk, 0, stream>>>(wo,                    wot,  DD * NN, DD);

    // h = x @ w_in + b_in  (fp32, K=64)
    gemm64<<<dim3(DD / 64, BLn / 64), blk, 0, stream>>>(x, w_in, b_in, h, BLn, DD, INF_);

    const dim3 mgrid(DD / 64, BLn / 128);
    const dim3 sgrid(16, 16, BB);

    // ---- layer 0 (full sequence) ----
    ln_kernel<<<BLn, blk, 0, stream>>>(h, ln_g, ln_b, xn, xn_bf);
    conv_kernel<<<(BLn * DD) / 256, blk, 0, stream>>>(xn, conv_w, conv_b, xc, xc_bf);
    gemm_mfma<<<mgrid, blk, 0, stream>>>(xc_bf, wdt0, bd, nullptr, delta, BLn, DD, DD, 1);
    gemm_n16<<<BLn / 16, blk, 0, stream>>>(xc, wb, Btm);
    gemm_n16<<<BLn / 16, blk, 0, stream>>>(xc, wc, Ctm);
    ssm_chunk_kernel<0><<<sgrid, blk, 0, stream>>>(delta, Btm, nullptr, loglam,
                                                   nullptr, sA, sB, nullptr);
    ssm_comb_kernel<<<BB * 4096 / 256, blk, 0, stream>>>(sA, sB, hst, nullptr);
    ssm_chunk_kernel<1><<<sgrid, blk, 0, stream>>>(delta, Btm, Ctm, loglam,
                                                   hst, nullptr, nullptr, ys);
    float* ssmout = delta;   // delta dead after phase C
    gemm_mfma<<<mgrid, blk, 0, stream>>>(ys, wot, bo, nullptr, ssmout, BLn, DD, DD * NN, 0);
    float* gatebuf = xn;     // xn fp32 dead after conv
    gemm_mfma<<<mgrid, blk, 0, stream>>>(xn_bf, gwt, gb, nullptr, gatebuf, BLn, DD, DD, 2);
    mulbf_kernel<<<(BLn * DD) / 256, blk, 0, stream>>>(ssmout, gatebuf, xsg_bf);
    gemm_mfma<<<mgrid, blk, 0, stream>>>(xsg_bf, pwt, pb, h, xt1, BLn, DD, DD, 0);

    // ---- layer 1 (only final state needed downstream) ----
    ln_kernel<<<BLn, blk, 0, stream>>>(xt1, ln_g + DD, ln_b + DD, xn, xn_bf);
    conv_kernel<<<(BLn * DD) / 256, blk, 0, stream>>>(xn, conv_w + DD * 3, conv_b + DD, xc, xc_bf);
    gemm_mfma<<<mgrid, blk, 0, stream>>>(xc_bf, wdt1, bd + DD, nullptr, delta, BLn, DD, DD, 1);
    gemm_n16<<<BLn / 16, blk, 0, stream>>>(xc, wb + DD * NN, Btm);
    gemm_n16<<<BLn / 16, blk, 0, stream>>>(xc, wc + DD * NN, Ctm);
    ssm_chunk_kernel<0><<<sgrid, blk, 0, stream>>>(delta, Btm, nullptr, loglam + DD * NN,
                                                   nullptr, sA, sB, nullptr);
    ssm_comb_kernel<<<BB * 4096 / 256, blk, 0, stream>>>(sA, sB, hst, hfin);
    last_ssm_kernel<<<BB, blk, 0, stream>>>(hfin, Ctm, wo + (size_t)DD * NN * DD, bo + DD, outlast);
    last_proj_kernel<<<BB, blk, 0, stream>>>(xn, outlast, gw + (size_t)DD * DD, gb + DD,
                                             pw + (size_t)DD * DD, pb + DD, xt1, xtlast);

    // ---- spectral path on h (only t = L-1 needed downstream) ----
    dft_kernel<<<dim3(FCNT / 5, BB), blk, 0, stream>>>(h, tab, Xre, Xim);
    mag_kernel<<<FCNT, blk, 0, stream>>>(Xre, Xim, magb);
    topk_kernel<<<1, blk, 0, stream>>>(magb, sel);
    xslast_kernel<<<BB, blk, 0, stream>>>(Xre, Xim, sel, fr, fi, tab, xslast);

    head_kernel<<<BB, blk, 0, stream>>>(xtlast, xslast, alpha, beta, gout, bout,
                                        hw1, hb1, hw2, hb2, (float*)d_out);
}

// Round 4
// 539.809 us; speedup vs baseline: 4.3458x; 1.5237x over previous
//
#include <hip/hip_runtime.h>
#include <hip/hip_bf16.h>
#include <math.h>

#define BB   4
#define LL   2048
#define INF_ 64
#define DD   256
#define NN   16
#define KK   32
#define BLn  (BB*LL)      // 8192
#define FCNT 1025         // L/2+1
#define FSTR 1056         // padded per-sequence stride for X

typedef short short8 __attribute__((ext_vector_type(8)));
typedef float f32x4  __attribute__((ext_vector_type(4)));

__device__ __forceinline__ float softplusf(float x) {
    return x > 20.f ? x : log1pf(__expf(x));
}
__device__ __forceinline__ float sigmoidf_(float x) {
    return 1.f / (1.f + __expf(-x));
}

// ---------------- twiddle table: tab[k]=cos(2*pi*k/2048), tab[2048+k]=sin ----
__global__ void twiddle_kernel(float* tab) {
    int i = blockIdx.x * 256 + threadIdx.x;
    if (i < 2048) {
        double ang = 2.0 * 3.14159265358979323846 * (double)i / 2048.0;
        tab[i]        = (float)cos(ang);
        tab[2048 + i] = (float)sin(ang);
    }
}

// ---------------- transpose+cast weights: W[K][N] fp32 -> Wt[N][K] bf16 -----
__global__ void tcast_kernel(const float* __restrict__ W, __hip_bfloat16* __restrict__ Wt,
                             int K, int N) {
    __shared__ float t[32][33];
    const int k0 = blockIdx.y * 32, n0 = blockIdx.x * 32;
    const int tx = threadIdx.x & 31, ty = threadIdx.x >> 5;   // 256 thr: ty 0..7
    for (int r = ty; r < 32; r += 8) t[r][tx] = W[(size_t)(k0 + r) * N + n0 + tx];
    __syncthreads();
    for (int r = ty; r < 32; r += 8)
        Wt[(size_t)(n0 + r) * K + k0 + tx] = __float2bfloat16(t[tx][r]);
}

// ---------------- fp32 GEMM (input projection only, K=64) -------------------
__global__ void gemm64(const float* __restrict__ A, const float* __restrict__ W,
                       const float* __restrict__ bias, float* __restrict__ C,
                       int M, int N, int K) {
    __shared__ float As[16][68];
    __shared__ float Ws[16][64];
    const int tid = threadIdx.x;
    const int tx = tid & 15, ty = tid >> 4;
    const int row0 = blockIdx.y * 64, col0 = blockIdx.x * 64;
    float acc[4][4] = {};
    for (int k0 = 0; k0 < K; k0 += 16) {
#pragma unroll
        for (int e = 0; e < 4; ++e) {
            int p = e * 256 + tid;
            int kk = p & 15, m = p >> 4;
            As[kk][m] = A[(size_t)(row0 + m) * K + k0 + kk];
        }
#pragma unroll
        for (int e = 0; e < 4; ++e) {
            int p = e * 256 + tid;
            int kk = p >> 6, j = p & 63;
            Ws[kk][j] = W[(size_t)(k0 + kk) * N + col0 + j];
        }
        __syncthreads();
#pragma unroll
        for (int kk = 0; kk < 16; ++kk) {
            float4 a4 = *(const float4*)&As[kk][ty * 4];
            float4 w4 = *(const float4*)&Ws[kk][tx * 4];
            float av[4] = {a4.x, a4.y, a4.z, a4.w};
            float wv[4] = {w4.x, w4.y, w4.z, w4.w};
#pragma unroll
            for (int i = 0; i < 4; ++i)
#pragma unroll
                for (int j = 0; j < 4; ++j)
                    acc[i][j] = fmaf(av[i], wv[j], acc[i][j]);
        }
        __syncthreads();
    }
#pragma unroll
    for (int i = 0; i < 4; ++i) {
        int r = row0 + ty * 4 + i;
#pragma unroll
        for (int j = 0; j < 4; ++j) {
            int c = col0 + tx * 4 + j;
            C[(size_t)r * N + c] = acc[i][j] + bias[c];
        }
    }
}

// ---------------- bf16 MFMA GEMM: C = act(A @ Wt^T + bias) [+ addend] -------
// A: [M,K] bf16 row-major; Wt: [N,K] bf16 (pre-transposed). Tile 128x64.
__global__ __launch_bounds__(256)
void gemm_mfma(const __hip_bfloat16* __restrict__ Abf, const __hip_bfloat16* __restrict__ Wt,
               const float* __restrict__ bias, const float* __restrict__ addend,
               float* __restrict__ C, int M, int N, int K, int act) {
    __shared__ alignas(16) short As[128][40];   // pad 32->40: conflict-free b128
    __shared__ alignas(16) short Bs[64][40];
    const int tid = threadIdx.x;
    const int w = tid >> 6, lane = tid & 63;
    const int hi = lane >> 4, lo = lane & 15;
    const int row0 = blockIdx.y * 128, col0 = blockIdx.x * 64;
    const short* A = (const short*)Abf;
    const short* B = (const short*)Wt;
    f32x4 acc[2][4];
    f32x4 zz = {0.f, 0.f, 0.f, 0.f};
#pragma unroll
    for (int m = 0; m < 2; ++m)
#pragma unroll
        for (int n = 0; n < 4; ++n) acc[m][n] = zz;
    // staging: A tile = 128x32 shorts = 512 short8-chunks (2/thread)
    //          B tile =  64x32 shorts = 256 short8-chunks (1/thread)
    for (int k0 = 0; k0 < K; k0 += 32) {
#pragma unroll
        for (int e = 0; e < 2; ++e) {
            int c = e * 256 + tid;
            int r = c >> 2, col = (c & 3) * 8;
            *(short8*)&As[r][col] = *(const short8*)&A[(size_t)(row0 + r) * K + k0 + col];
        }
        {
            int r = tid >> 2, col = (tid & 3) * 8;
            *(short8*)&Bs[r][col] = *(const short8*)&B[(size_t)(col0 + r) * K + k0 + col];
        }
        __syncthreads();
        short8 af[2], bfr[4];
#pragma unroll
        for (int m = 0; m < 2; ++m)
            af[m] = *(const short8*)&As[w * 32 + m * 16 + lo][hi * 8];
#pragma unroll
        for (int n = 0; n < 4; ++n)
            bfr[n] = *(const short8*)&Bs[n * 16 + lo][hi * 8];
#pragma unroll
        for (int m = 0; m < 2; ++m)
#pragma unroll
            for (int n = 0; n < 4; ++n)
                acc[m][n] = __builtin_amdgcn_mfma_f32_16x16x32_bf16(af[m], bfr[n], acc[m][n], 0, 0, 0);
        __syncthreads();
    }
#pragma unroll
    for (int m = 0; m < 2; ++m) {
#pragma unroll
        for (int n = 0; n < 4; ++n) {
#pragma unroll
            for (int r = 0; r < 4; ++r) {
                int row = row0 + w * 32 + m * 16 + hi * 4 + r;
                int col = col0 + n * 16 + lo;
                float v = acc[m][n][r];
                if (bias) v += bias[col];
                if (act == 1) v = softplusf(v);
                else if (act == 2) v = sigmoidf_(v);
                if (addend) v += addend[(size_t)row * N + col];
                C[(size_t)row * N + col] = v;
            }
        }
    }
}

// ---------------- small GEMM: C[M,16] = A[M,256] @ W[256,16] (no bias) ------
__global__ void gemm_n16(const float* __restrict__ A, const float* __restrict__ W,
                         float* __restrict__ C) {
    __shared__ float As[16][260];
    __shared__ float Ws[256][16];
    const int tid = threadIdx.x;
    const int row0 = blockIdx.x * 16;
#pragma unroll
    for (int e = 0; e < 16; ++e)
        As[e][tid] = A[(size_t)(row0 + e) * 256 + tid];
#pragma unroll
    for (int e = 0; e < 16; ++e) {
        int p = e * 256 + tid;
        Ws[p >> 4][p & 15] = W[p];
    }
    __syncthreads();
    const int r = tid >> 4, n = tid & 15;
    float acc = 0.f;
#pragma unroll 8
    for (int k = 0; k < 256; ++k)
        acc = fmaf(As[r][k], Ws[k][n], acc);
    C[(size_t)(row0 + r) * 16 + n] = acc;
}

// ---------------- LayerNorm over D=256 (fp32 out + bf16 out) ----------------
__global__ void ln_kernel(const float* __restrict__ X, const float* __restrict__ g,
                          const float* __restrict__ b, float* __restrict__ Y,
                          __hip_bfloat16* __restrict__ Ybf) {
    __shared__ float red[256];
    const int row = blockIdx.x, tid = threadIdx.x;
    const size_t base = (size_t)row * DD;
    float v = X[base + tid];
    red[tid] = v; __syncthreads();
    for (int s = 128; s > 0; s >>= 1) { if (tid < s) red[tid] += red[tid + s]; __syncthreads(); }
    float m = red[0] * (1.f / DD);
    __syncthreads();
    float c = v - m;
    red[tid] = c * c; __syncthreads();
    for (int s = 128; s > 0; s >>= 1) { if (tid < s) red[tid] += red[tid + s]; __syncthreads(); }
    float var = red[0] * (1.f / DD);
    float y = c * rsqrtf(var + 1e-5f) * g[tid] + b[tid];
    Y[base + tid] = y;
    Ybf[base + tid] = __float2bfloat16(y);
}

// ---------------- depthwise conv k=3 (fp32 out + bf16 out) ------------------
__global__ void conv_kernel(const float* __restrict__ Xn, const float* __restrict__ cw,
                            const float* __restrict__ cb, float* __restrict__ Xc,
                            __hip_bfloat16* __restrict__ Xcbf) {
    const size_t i = (size_t)blockIdx.x * 256 + threadIdx.x;
    const int d = (int)(i & 255);
    const int l = (int)((i >> 8) & (LL - 1));
    float w0 = cw[d * 3 + 0], w1 = cw[d * 3 + 1], w2 = cw[d * 3 + 2];
    float xm = (l > 0)      ? Xn[i - DD] : 0.f;
    float x0 = Xn[i];
    float xp = (l < LL - 1) ? Xn[i + DD] : 0.f;
    float y = fmaf(w0, xm, fmaf(w1, x0, fmaf(w2, xp, cb[d])));
    Xc[i] = y;
    Xcbf[i] = __float2bfloat16(y);
}

__global__ void mulbf_kernel(const float* __restrict__ a, const float* __restrict__ b,
                             __hip_bfloat16* __restrict__ c) {
    size_t i = (size_t)blockIdx.x * 256 + threadIdx.x;
    c[i] = __float2bfloat16(a[i] * b[i]);
}

// ---------------- chunked SSM scan ------------------------------------------
template<int PHASE>
__global__ void ssm_chunk_kernel(const float* __restrict__ delta, const float* __restrict__ Bt,
                                 const float* __restrict__ Ct, const float* __restrict__ loglam,
                                 const float* __restrict__ hstart,
                                 float* __restrict__ sA, float* __restrict__ sB,
                                 __hip_bfloat16* __restrict__ ys) {
    __shared__ float dl[128][16];
    __shared__ float btl[128][16];
    __shared__ float ctl[128][16];
    const int dblk = blockIdx.x, c = blockIdx.y, b = blockIdx.z;
    const int tid = threadIdx.x;
    const size_t lbase = (size_t)b * LL + c * 128;
    for (int i = tid; i < 2048; i += 256) {
        int l = i >> 4, q = i & 15;
        dl[l][q]  = delta[(lbase + l) * DD + dblk * 16 + q];
        btl[l][q] = Bt[(lbase + l) * NN + q];
        if (PHASE == 1) ctl[l][q] = Ct[(lbase + l) * NN + q];
    }
    __syncthreads();
    const int dloc = tid >> 4, n = tid & 15;
    const float lam = softplusf(loglam[(dblk * 16 + dloc) * NN + n]);
    float hv = 0.f, ap = 1.f;
    if (PHASE == 1) hv = hstart[((size_t)(b * 16 + c)) * 4096 + dblk * 256 + tid];
    for (int l = 0; l < 128; ++l) {
        float dv = dl[l][dloc];
        float a = __expf(-dv * lam);
        hv = fmaf(a, hv, dv * btl[l][n]);
        if (PHASE == 0) ap *= a;
        else ys[(lbase + l) * (DD * NN) + dblk * 256 + tid] = __float2bfloat16(hv * ctl[l][n]);
    }
    if (PHASE == 0) {
        size_t oi = ((size_t)(b * 16 + c)) * 4096 + dblk * 256 + tid;
        sA[oi] = ap; sB[oi] = hv;
    }
}

// chunk-summary combine: h at chunk starts (+ optional final state)
__global__ void ssm_comb_kernel(const float* __restrict__ sA, const float* __restrict__ sB,
                                float* __restrict__ hstart, float* __restrict__ hfin) {
    const int id = blockIdx.x * 256 + threadIdx.x;   // < BB*4096
    const int b = id >> 12, col = id & 4095;
    float h = 0.f;
#pragma unroll
    for (int c = 0; c < 16; ++c) {
        size_t oi = ((size_t)(b * 16 + c)) * 4096 + col;
        hstart[oi] = h;
        h = fmaf(sA[oi], h, sB[oi]);
    }
    if (hfin) hfin[(size_t)b * 4096 + col] = h;
}

// ---------------- layer-2 last-position SSM output ---------------------------
__global__ void last_ssm_kernel(const float* __restrict__ hfin, const float* __restrict__ Ct,
                                const float* __restrict__ wo, const float* __restrict__ bo,
                                float* __restrict__ outlast) {
    __shared__ float hC[4096];
    const int b = blockIdx.x, tid = threadIdx.x;
    const size_t ctbase = ((size_t)b * LL + (LL - 1)) * NN;
    for (int p = tid; p < 4096; p += 256)
        hC[p] = hfin[(size_t)b * 4096 + p] * Ct[ctbase + (p & 15)];
    __syncthreads();
    float acc = bo[tid];
    for (int p = 0; p < 4096; ++p)
        acc = fmaf(hC[p], wo[(size_t)p * DD + tid], acc);
    outlast[b * DD + tid] = acc;
}

// ---------------- layer-2 last-position gate + proj + residual --------------
__global__ void last_proj_kernel(const float* __restrict__ xn, const float* __restrict__ outlast,
                                 const float* __restrict__ gw, const float* __restrict__ gb,
                                 const float* __restrict__ pw, const float* __restrict__ pb,
                                 const float* __restrict__ resid, float* __restrict__ xtlast) {
    __shared__ float xrow[256];
    __shared__ float xsg[256];
    const int b = blockIdx.x, d = threadIdx.x;
    const size_t rbase = ((size_t)b * LL + (LL - 1)) * DD;
    xrow[d] = xn[rbase + d];
    __syncthreads();
    float acc = gb[d];
    for (int k = 0; k < 256; ++k) acc = fmaf(xrow[k], gw[(size_t)k * DD + d], acc);
    float g = sigmoidf_(acc);
    xsg[d] = outlast[b * DD + d] * g;
    __syncthreads();
    float acc2 = pb[d];
    for (int k = 0; k < 256; ++k) acc2 = fmaf(xsg[k], pw[(size_t)k * DD + d], acc2);
    xtlast[b * DD + d] = acc2 + resid[rbase + d];
}

// ---------------- radix-2 FFT, 2048-pt, one sequence (b,d) per block --------
// X[seq][f] layout (seq-major, stride FSTR), rfft sign convention.
__global__ __launch_bounds__(256)
void fft_kernel(const float* __restrict__ h, const float* __restrict__ tab,
                float* __restrict__ Xre, float* __restrict__ Xim) {
    __shared__ float re[2048];
    __shared__ float im[2048];
    __shared__ float ct[1024];
    __shared__ float st[1024];
    const int tid = threadIdx.x;
    const int seq = blockIdx.x;            // b*256 + d
    const int b = seq >> 8, d = seq & 255;
    for (int i = tid; i < 1024; i += 256) { ct[i] = tab[i]; st[i] = tab[2048 + i]; }
    const float* hp = h + (size_t)b * LL * DD + d;
    for (int i = tid; i < 2048; i += 256) {
        int r = (int)(__brev((unsigned)i) >> 21);   // 11-bit reversal
        re[r] = hp[(size_t)i * DD];
        im[r] = 0.f;
    }
    __syncthreads();
#pragma unroll
    for (int s = 1; s <= 11; ++s) {
        const int half = 1 << (s - 1);
        const int tsh = 11 - s;
#pragma unroll
        for (int e = 0; e < 4; ++e) {
            int q = e * 256 + tid;
            int j = q & (half - 1);
            int i0 = ((q >> (s - 1)) << s) + j;
            int i1 = i0 + half;
            int tw = j << tsh;
            float wr = ct[tw], wi = -st[tw];
            float xr = re[i1], xi = im[i1];
            float tr = xr * wr - xi * wi;
            float ti = xr * wi + xi * wr;
            float ur = re[i0], ui = im[i0];
            re[i0] = ur + tr; im[i0] = ui + ti;
            re[i1] = ur - tr; im[i1] = ui - ti;
        }
        __syncthreads();
    }
    float* xr = Xre + (size_t)seq * FSTR;
    float* xi = Xim + (size_t)seq * FSTR;
    for (int f = tid; f < FCNT; f += 256) { xr[f] = re[f]; xi[f] = im[f]; }
}

// ---------------- mag[f] = mean |X[seq][f]| over 1024 sequences -------------
__global__ void mag_kernel(const float* __restrict__ Xre, const float* __restrict__ Xim,
                           float* __restrict__ mag) {
    __shared__ float red[256];
    const int f = blockIdx.x, tid = threadIdx.x;
    float s = 0.f;
#pragma unroll
    for (int q = 0; q < 4; ++q) {
        int i = q * 256 + tid;
        float re = Xre[(size_t)i * FSTR + f], im = Xim[(size_t)i * FSTR + f];
        s += sqrtf(re * re + im * im);
    }
    red[tid] = s; __syncthreads();
    for (int sft = 128; sft > 0; sft >>= 1) { if (tid < sft) red[tid] += red[tid + sft]; __syncthreads(); }
    if (tid == 0) mag[f] = red[0] * (1.f / 1024.f);
}

// ---------------- top-32, jax.lax.top_k order (desc, ties->lower idx) -------
__global__ void topk_kernel(const float* __restrict__ mag, int* __restrict__ sel) {
    __shared__ float vals[1056];
    __shared__ float rv[256];
    __shared__ int ri[256];
    const int tid = threadIdx.x;
    for (int i = tid; i < 1056; i += 256) vals[i] = (i < FCNT) ? mag[i] : -1e30f;
    __syncthreads();
    for (int k = 0; k < 32; ++k) {
        float bv = -1e30f; int bi = 0x7fffffff;
        for (int i = tid; i < FCNT; i += 256) {
            float v = vals[i];
            if (v > bv) { bv = v; bi = i; }
        }
        rv[tid] = bv; ri[tid] = bi; __syncthreads();
        for (int s = 128; s > 0; s >>= 1) {
            if (tid < s) {
                if (rv[tid + s] > rv[tid] ||
                    (rv[tid + s] == rv[tid] && ri[tid + s] < ri[tid])) {
                    rv[tid] = rv[tid + s]; ri[tid] = ri[tid + s];
                }
            }
            __syncthreads();
        }
        if (tid == 0) { sel[k] = ri[0]; vals[ri[0]] = -1e30f; }
        __syncthreads();
    }
}

// ---------------- xs_spectral at t = L-1 only --------------------------------
__global__ void xslast_kernel(const float* __restrict__ Xre, const float* __restrict__ Xim,
                              const int* __restrict__ sel, const float* __restrict__ fr,
                              const float* __restrict__ fi, const float* __restrict__ tab,
                              float* __restrict__ xsl) {
    const int b = blockIdx.x, d = threadIdx.x;
    const size_t sbase = (size_t)(b * 256 + d) * FSTR;
    float acc = 0.f;
    for (int j = 0; j < 32; ++j) {
        int f = sel[j];
        float xr = Xre[sbase + f];
        float xi = Xim[sbase + f];
        float frv = fr[d * KK + j], fiv = fi[d * KK + j];
        float xor_ = xr * frv - xi * fiv;
        float xoi  = xr * fiv + xi * frv;
        int kk2 = (f * (LL - 1)) & (LL - 1);
        float c = tab[kk2], s = tab[2048 + kk2];
        float w = (f == 0 || f == 1024) ? 1.f : 2.f;
        acc = fmaf(w, xor_ * c - xoi * s, acc);
    }
    xsl[b * DD + d] = acc * (1.f / LL);
}

// ---------------- final head: mix, LN, MLP -> out (B,2) ----------------------
__global__ void head_kernel(const float* __restrict__ xtlast, const float* __restrict__ xslast,
                            const float* __restrict__ alpha, const float* __restrict__ beta,
                            const float* __restrict__ gout, const float* __restrict__ bout,
                            const float* __restrict__ hw1, const float* __restrict__ hb1,
                            const float* __restrict__ hw2, const float* __restrict__ hb2,
                            float* __restrict__ out) {
    __shared__ float red[256];
    __shared__ float z[256];
    __shared__ float hid[128];
    const int b = blockIdx.x, tid = threadIdx.x;
    float zv = alpha[tid] * xtlast[b * 256 + tid] + beta[tid] * xslast[b * 256 + tid];
    red[tid] = zv; __syncthreads();
    for (int s = 128; s > 0; s >>= 1) { if (tid < s) red[tid] += red[tid + s]; __syncthreads(); }
    float m = red[0] * (1.f / DD);
    __syncthreads();
    float c = zv - m;
    red[tid] = c * c; __syncthreads();
    for (int s = 128; s > 0; s >>= 1) { if (tid < s) red[tid] += red[tid + s]; __syncthreads(); }
    float var = red[0] * (1.f / DD);
    z[tid] = c * rsqrtf(var + 1e-5f) * gout[tid] + bout[tid];
    __syncthreads();
    if (tid < 128) {
        float a = hb1[tid];
        for (int k = 0; k < 256; ++k) a = fmaf(z[k], hw1[(size_t)k * 128 + tid], a);
        hid[tid] = a * sigmoidf_(a);
    }
    __syncthreads();
    if (tid < 2) {
        float a = hb2[tid];
        for (int k = 0; k < 128; ++k) a = fmaf(hid[k], hw2[(size_t)k * 2 + tid], a);
        out[b * 2 + tid] = a;
    }
}

extern "C" void kernel_launch(void* const* d_in, const int* in_sizes, int n_in,
                              void* d_out, int out_size, void* d_ws, size_t ws_size,
                              hipStream_t stream) {
    const float* x      = (const float*)d_in[0];
    const float* w_in   = (const float*)d_in[1];
    const float* b_in   = (const float*)d_in[2];
    const float* ln_g   = (const float*)d_in[3];
    const float* ln_b   = (const float*)d_in[4];
    const float* conv_w = (const float*)d_in[5];
    const float* conv_b = (const float*)d_in[6];
    const float* loglam = (const float*)d_in[7];
    const float* wd     = (const float*)d_in[8];
    const float* bd     = (const float*)d_in[9];
    const float* wb     = (const float*)d_in[10];
    const float* wc     = (const float*)d_in[11];
    const float* wo     = (const float*)d_in[12];
    const float* bo     = (const float*)d_in[13];
    const float* gw     = (const float*)d_in[14];
    const float* gb     = (const float*)d_in[15];
    const float* pw     = (const float*)d_in[16];
    const float* pb     = (const float*)d_in[17];
    const float* fr     = (const float*)d_in[18];
    const float* fi     = (const float*)d_in[19];
    const float* alpha  = (const float*)d_in[20];
    const float* beta   = (const float*)d_in[21];
    const float* gout   = (const float*)d_in[22];
    const float* bout   = (const float*)d_in[23];
    const float* hw1    = (const float*)d_in[24];
    const float* hb1    = (const float*)d_in[25];
    const float* hw2    = (const float*)d_in[26];
    const float* hb2    = (const float*)d_in[27];

    float* ws = (float*)d_ws;
    size_t o = 0;
    auto alloc = [&](size_t n) { float* p = ws + o; o += (n + 15) & ~(size_t)15; return p; };

    const size_t BLnDD = (size_t)BLn * DD;
    float* h      = alloc(BLnDD);
    float* xt1    = alloc(BLnDD);
    float* xn     = alloc(BLnDD);   // also reused as gate fp32 output
    float* xc     = alloc(BLnDD);
    float* delta  = alloc(BLnDD);   // also reused as ssmout
    float* Btm    = alloc((size_t)BLn * NN);
    float* Ctm    = alloc((size_t)BLn * NN);
    float* tab    = alloc(4096);
    float* ysf    = alloc(BLnDD * NN / 2);          // ys bf16 region; later Xre/Xim
    float* sA     = alloc((size_t)BB * 16 * 4096);
    float* sB     = alloc((size_t)BB * 16 * 4096);
    float* hst    = alloc((size_t)BB * 16 * 4096);
    float* xnbf_f = alloc(BLnDD / 2);
    float* xcbf_f = alloc(BLnDD / 2);
    float* xsgf   = alloc(BLnDD / 2);
    float* wdt_f  = alloc((size_t)2 * DD * DD / 2);
    float* gwt_f  = alloc((size_t)DD * DD / 2);
    float* pwt_f  = alloc((size_t)DD * DD / 2);
    float* wot_f  = alloc((size_t)DD * NN * DD / 2);
    float* magb   = alloc(1056);
    int*   sel    = (int*)alloc(32);
    float* hfin   = alloc((size_t)BB * DD * NN);
    float* outlast= alloc(BB * DD);
    float* xtlast = alloc(BB * DD);
    float* xslast = alloc(BB * DD);

    __hip_bfloat16* ys    = (__hip_bfloat16*)ysf;
    float*          Xre   = ysf;                        // alias: ys dead before FFT
    float*          Xim   = ysf + (size_t)1024 * FSTR;
    __hip_bfloat16* xn_bf = (__hip_bfloat16*)xnbf_f;
    __hip_bfloat16* xc_bf = (__hip_bfloat16*)xcbf_f;
    __hip_bfloat16* xsg_bf= (__hip_bfloat16*)xsgf;
    __hip_bfloat16* wdt0  = (__hip_bfloat16*)wdt_f;
    __hip_bfloat16* wdt1  = wdt0 + (size_t)DD * DD;
    __hip_bfloat16* gwt   = (__hip_bfloat16*)gwt_f;
    __hip_bfloat16* pwt   = (__hip_bfloat16*)pwt_f;
    __hip_bfloat16* wot   = (__hip_bfloat16*)wot_f;

    const dim3 blk(256);

    twiddle_kernel<<<8, blk, 0, stream>>>(tab);
    tcast_kernel<<<dim3(8, 8),   blk, 0, stream>>>(wd,                    wdt0, DD, DD);
    tcast_kernel<<<dim3(8, 8),   blk, 0, stream>>>(wd + (size_t)DD * DD,  wdt1, DD, DD);
    tcast_kernel<<<dim3(8, 8),   blk, 0, stream>>>(gw,                    gwt,  DD, DD);
    tcast_kernel<<<dim3(8, 8),   blk, 0, stream>>>(pw,                    pwt,  DD, DD);
    tcast_kernel<<<dim3(8, 128), blk, 0, stream>>>(wo,                    wot,  DD * NN, DD);

    // h = x @ w_in + b_in  (fp32, K=64)
    gemm64<<<dim3(DD / 64, BLn / 64), blk, 0, stream>>>(x, w_in, b_in, h, BLn, DD, INF_);

    const dim3 mgrid(DD / 64, BLn / 128);
    const dim3 sgrid(16, 16, BB);

    // ---- layer 0 (full sequence) ----
    ln_kernel<<<BLn, blk, 0, stream>>>(h, ln_g, ln_b, xn, xn_bf);
    conv_kernel<<<(BLn * DD) / 256, blk, 0, stream>>>(xn, conv_w, conv_b, xc, xc_bf);
    gemm_mfma<<<mgrid, blk, 0, stream>>>(xc_bf, wdt0, bd, nullptr, delta, BLn, DD, DD, 1);
    gemm_n16<<<BLn / 16, blk, 0, stream>>>(xc, wb, Btm);
    gemm_n16<<<BLn / 16, blk, 0, stream>>>(xc, wc, Ctm);
    ssm_chunk_kernel<0><<<sgrid, blk, 0, stream>>>(delta, Btm, nullptr, loglam,
                                                   nullptr, sA, sB, nullptr);
    ssm_comb_kernel<<<BB * 4096 / 256, blk, 0, stream>>>(sA, sB, hst, nullptr);
    ssm_chunk_kernel<1><<<sgrid, blk, 0, stream>>>(delta, Btm, Ctm, loglam,
                                                   hst, nullptr, nullptr, ys);
    float* ssmout = delta;   // delta dead after phase 1
    gemm_mfma<<<mgrid, blk, 0, stream>>>(ys, wot, bo, nullptr, ssmout, BLn, DD, DD * NN, 0);
    float* gatebuf = xn;     // xn fp32 dead after conv
    gemm_mfma<<<mgrid, blk, 0, stream>>>(xn_bf, gwt, gb, nullptr, gatebuf, BLn, DD, DD, 2);
    mulbf_kernel<<<(BLn * DD) / 256, blk, 0, stream>>>(ssmout, gatebuf, xsg_bf);
    gemm_mfma<<<mgrid, blk, 0, stream>>>(xsg_bf, pwt, pb, h, xt1, BLn, DD, DD, 0);

    // ---- layer 1 (only final state needed downstream) ----
    ln_kernel<<<BLn, blk, 0, stream>>>(xt1, ln_g + DD, ln_b + DD, xn, xn_bf);
    conv_kernel<<<(BLn * DD) / 256, blk, 0, stream>>>(xn, conv_w + DD * 3, conv_b + DD, xc, xc_bf);
    gemm_mfma<<<mgrid, blk, 0, stream>>>(xc_bf, wdt1, bd + DD, nullptr, delta, BLn, DD, DD, 1);
    gemm_n16<<<BLn / 16, blk, 0, stream>>>(xc, wb + DD * NN, Btm);
    gemm_n16<<<BLn / 16, blk, 0, stream>>>(xc, wc + DD * NN, Ctm);
    ssm_chunk_kernel<0><<<sgrid, blk, 0, stream>>>(delta, Btm, nullptr, loglam + DD * NN,
                                                   nullptr, sA, sB, nullptr);
    ssm_comb_kernel<<<BB * 4096 / 256, blk, 0, stream>>>(sA, sB, hst, hfin);
    last_ssm_kernel<<<BB, blk, 0, stream>>>(hfin, Ctm, wo + (size_t)DD * NN * DD, bo + DD, outlast);
    last_proj_kernel<<<BB, blk, 0, stream>>>(xn, outlast, gw + (size_t)DD * DD, gb + DD,
                                             pw + (size_t)DD * DD, pb + DD, xt1, xtlast);

    // ---- spectral path on h (only t = L-1 needed downstream) ----
    fft_kernel<<<1024, blk, 0, stream>>>(h, tab, Xre, Xim);
    mag_kernel<<<FCNT, blk, 0, stream>>>(Xre, Xim, magb);
    topk_kernel<<<1, blk, 0, stream>>>(magb, sel);
    xslast_kernel<<<BB, blk, 0, stream>>>(Xre, Xim, sel, fr, fi, tab, xslast);

    head_kernel<<<BB, blk, 0, stream>>>(xtlast, xslast, alpha, beta, gout, bout,
                                        hw1, hb1, hw2, hb2, (float*)d_out);
}

// Round 5
// 450.456 us; speedup vs baseline: 5.2078x; 1.1984x over previous
//
#include <hip/hip_runtime.h>
#include <hip/hip_bf16.h>
#include <math.h>

#define BB   4
#define LL   2048
#define INF_ 64
#define DD   256
#define NN   16
#define KK   32
#define BLn  (BB*LL)      // 8192
#define FCNT 1025         // L/2+1
#define FSTR 1056         // padded per-sequence stride for X

typedef short short8 __attribute__((ext_vector_type(8)));
typedef float f32x4  __attribute__((ext_vector_type(4)));

__device__ __forceinline__ float softplusf(float x) {
    return x > 20.f ? x : log1pf(__expf(x));
}
__device__ __forceinline__ float sigmoidf_(float x) {
    return 1.f / (1.f + __expf(-x));
}

// ---------------- twiddle table: tab[k]=cos(2*pi*k/2048), tab[2048+k]=sin ----
__global__ void twiddle_kernel(float* tab) {
    int i = blockIdx.x * 256 + threadIdx.x;
    if (i < 2048) {
        double ang = 2.0 * 3.14159265358979323846 * (double)i / 2048.0;
        tab[i]        = (float)cos(ang);
        tab[2048 + i] = (float)sin(ang);
    }
}

// ---------------- transpose+cast weights: W[K][N] fp32 -> Wt[N][K] bf16 -----
__global__ void tcast_kernel(const float* __restrict__ W, __hip_bfloat16* __restrict__ Wt,
                             int K, int N) {
    __shared__ float t[32][33];
    const int k0 = blockIdx.y * 32, n0 = blockIdx.x * 32;
    const int tx = threadIdx.x & 31, ty = threadIdx.x >> 5;   // 256 thr: ty 0..7
    for (int r = ty; r < 32; r += 8) t[r][tx] = W[(size_t)(k0 + r) * N + n0 + tx];
    __syncthreads();
    for (int r = ty; r < 32; r += 8)
        Wt[(size_t)(n0 + r) * K + k0 + tx] = __float2bfloat16(t[tx][r]);
}

// ---------------- fp32 GEMM (input projection only, K=64) -------------------
__global__ void gemm64(const float* __restrict__ A, const float* __restrict__ W,
                       const float* __restrict__ bias, float* __restrict__ C,
                       int M, int N, int K) {
    __shared__ float As[16][68];
    __shared__ float Ws[16][64];
    const int tid = threadIdx.x;
    const int tx = tid & 15, ty = tid >> 4;
    const int row0 = blockIdx.y * 64, col0 = blockIdx.x * 64;
    float acc[4][4] = {};
    for (int k0 = 0; k0 < K; k0 += 16) {
#pragma unroll
        for (int e = 0; e < 4; ++e) {
            int p = e * 256 + tid;
            int kk = p & 15, m = p >> 4;
            As[kk][m] = A[(size_t)(row0 + m) * K + k0 + kk];
        }
#pragma unroll
        for (int e = 0; e < 4; ++e) {
            int p = e * 256 + tid;
            int kk = p >> 6, j = p & 63;
            Ws[kk][j] = W[(size_t)(k0 + kk) * N + col0 + j];
        }
        __syncthreads();
#pragma unroll
        for (int kk = 0; kk < 16; ++kk) {
            float4 a4 = *(const float4*)&As[kk][ty * 4];
            float4 w4 = *(const float4*)&Ws[kk][tx * 4];
            float av[4] = {a4.x, a4.y, a4.z, a4.w};
            float wv[4] = {w4.x, w4.y, w4.z, w4.w};
#pragma unroll
            for (int i = 0; i < 4; ++i)
#pragma unroll
                for (int j = 0; j < 4; ++j)
                    acc[i][j] = fmaf(av[i], wv[j], acc[i][j]);
        }
        __syncthreads();
    }
#pragma unroll
    for (int i = 0; i < 4; ++i) {
        int r = row0 + ty * 4 + i;
#pragma unroll
        for (int j = 0; j < 4; ++j) {
            int c = col0 + tx * 4 + j;
            C[(size_t)r * N + c] = acc[i][j] + bias[c];
        }
    }
}

// ---------------- bf16 MFMA GEMM: C = act(A @ Wt^T + bias) [+ addend] -------
// A: [M,K] bf16 row-major; Wt: [N,K] bf16 (pre-transposed). Tile 128x64.
__global__ __launch_bounds__(256)
void gemm_mfma(const __hip_bfloat16* __restrict__ Abf, const __hip_bfloat16* __restrict__ Wt,
               const float* __restrict__ bias, const float* __restrict__ addend,
               float* __restrict__ C, int M, int N, int K, int act) {
    __shared__ alignas(16) short As[128][40];   // pad 32->40: conflict-free b128
    __shared__ alignas(16) short Bs[64][40];
    const int tid = threadIdx.x;
    const int w = tid >> 6, lane = tid & 63;
    const int hi = lane >> 4, lo = lane & 15;
    const int row0 = blockIdx.y * 128, col0 = blockIdx.x * 64;
    const short* A = (const short*)Abf;
    const short* B = (const short*)Wt;
    f32x4 acc[2][4];
    f32x4 zz = {0.f, 0.f, 0.f, 0.f};
#pragma unroll
    for (int m = 0; m < 2; ++m)
#pragma unroll
        for (int n = 0; n < 4; ++n) acc[m][n] = zz;
    // staging: A tile = 128x32 shorts = 512 short8-chunks (2/thread)
    //          B tile =  64x32 shorts = 256 short8-chunks (1/thread)
    for (int k0 = 0; k0 < K; k0 += 32) {
#pragma unroll
        for (int e = 0; e < 2; ++e) {
            int c = e * 256 + tid;
            int r = c >> 2, col = (c & 3) * 8;
            *(short8*)&As[r][col] = *(const short8*)&A[(size_t)(row0 + r) * K + k0 + col];
        }
        {
            int r = tid >> 2, col = (tid & 3) * 8;
            *(short8*)&Bs[r][col] = *(const short8*)&B[(size_t)(col0 + r) * K + k0 + col];
        }
        __syncthreads();
        short8 af[2], bfr[4];
#pragma unroll
        for (int m = 0; m < 2; ++m)
            af[m] = *(const short8*)&As[w * 32 + m * 16 + lo][hi * 8];
#pragma unroll
        for (int n = 0; n < 4; ++n)
            bfr[n] = *(const short8*)&Bs[n * 16 + lo][hi * 8];
#pragma unroll
        for (int m = 0; m < 2; ++m)
#pragma unroll
            for (int n = 0; n < 4; ++n)
                acc[m][n] = __builtin_amdgcn_mfma_f32_16x16x32_bf16(af[m], bfr[n], acc[m][n], 0, 0, 0);
        __syncthreads();
    }
#pragma unroll
    for (int m = 0; m < 2; ++m) {
#pragma unroll
        for (int n = 0; n < 4; ++n) {
#pragma unroll
            for (int r = 0; r < 4; ++r) {
                int row = row0 + w * 32 + m * 16 + hi * 4 + r;
                int col = col0 + n * 16 + lo;
                float v = acc[m][n][r];
                if (bias) v += bias[col];
                if (act == 1) v = softplusf(v);
                else if (act == 2) v = sigmoidf_(v);
                if (addend) v += addend[(size_t)row * N + col];
                C[(size_t)row * N + col] = v;
            }
        }
    }
}

// ---------------- small GEMM: C[M,16] = A[M,256] @ W[256,16] (no bias) ------
__global__ void gemm_n16(const float* __restrict__ A, const float* __restrict__ W,
                         float* __restrict__ C) {
    __shared__ float As[16][260];
    __shared__ float Ws[256][16];
    const int tid = threadIdx.x;
    const int row0 = blockIdx.x * 16;
#pragma unroll
    for (int e = 0; e < 16; ++e)
        As[e][tid] = A[(size_t)(row0 + e) * 256 + tid];
#pragma unroll
    for (int e = 0; e < 16; ++e) {
        int p = e * 256 + tid;
        Ws[p >> 4][p & 15] = W[p];
    }
    __syncthreads();
    const int r = tid >> 4, n = tid & 15;
    float acc = 0.f;
#pragma unroll 8
    for (int k = 0; k < 256; ++k)
        acc = fmaf(As[r][k], Ws[k][n], acc);
    C[(size_t)(row0 + r) * 16 + n] = acc;
}

// ---------------- LayerNorm over D=256 (fp32 out + bf16 out) ----------------
__global__ void ln_kernel(const float* __restrict__ X, const float* __restrict__ g,
                          const float* __restrict__ b, float* __restrict__ Y,
                          __hip_bfloat16* __restrict__ Ybf) {
    __shared__ float red[256];
    const int row = blockIdx.x, tid = threadIdx.x;
    const size_t base = (size_t)row * DD;
    float v = X[base + tid];
    red[tid] = v; __syncthreads();
    for (int s = 128; s > 0; s >>= 1) { if (tid < s) red[tid] += red[tid + s]; __syncthreads(); }
    float m = red[0] * (1.f / DD);
    __syncthreads();
    float c = v - m;
    red[tid] = c * c; __syncthreads();
    for (int s = 128; s > 0; s >>= 1) { if (tid < s) red[tid] += red[tid + s]; __syncthreads(); }
    float var = red[0] * (1.f / DD);
    float y = c * rsqrtf(var + 1e-5f) * g[tid] + b[tid];
    Y[base + tid] = y;
    Ybf[base + tid] = __float2bfloat16(y);
}

// ---------------- depthwise conv k=3 (fp32 out + bf16 out) ------------------
__global__ void conv_kernel(const float* __restrict__ Xn, const float* __restrict__ cw,
                            const float* __restrict__ cb, float* __restrict__ Xc,
                            __hip_bfloat16* __restrict__ Xcbf) {
    const size_t i = (size_t)blockIdx.x * 256 + threadIdx.x;
    const int d = (int)(i & 255);
    const int l = (int)((i >> 8) & (LL - 1));
    float w0 = cw[d * 3 + 0], w1 = cw[d * 3 + 1], w2 = cw[d * 3 + 2];
    float xm = (l > 0)      ? Xn[i - DD] : 0.f;
    float x0 = Xn[i];
    float xp = (l < LL - 1) ? Xn[i + DD] : 0.f;
    float y = fmaf(w0, xm, fmaf(w1, x0, fmaf(w2, xp, cb[d])));
    Xc[i] = y;
    Xcbf[i] = __float2bfloat16(y);
}

__global__ void mulbf_kernel(const float* __restrict__ a, const float* __restrict__ b,
                             __hip_bfloat16* __restrict__ c) {
    size_t i = (size_t)blockIdx.x * 256 + threadIdx.x;
    c[i] = __float2bfloat16(a[i] * b[i]);
}

// ---------------- chunked SSM scan ------------------------------------------
template<int PHASE>
__global__ void ssm_chunk_kernel(const float* __restrict__ delta, const float* __restrict__ Bt,
                                 const float* __restrict__ Ct, const float* __restrict__ loglam,
                                 const float* __restrict__ hstart,
                                 float* __restrict__ sA, float* __restrict__ sB,
                                 __hip_bfloat16* __restrict__ ys) {
    __shared__ float dl[128][16];
    __shared__ float btl[128][16];
    __shared__ float ctl[128][16];
    const int dblk = blockIdx.x, c = blockIdx.y, b = blockIdx.z;
    const int tid = threadIdx.x;
    const size_t lbase = (size_t)b * LL + c * 128;
    for (int i = tid; i < 2048; i += 256) {
        int l = i >> 4, q = i & 15;
        dl[l][q]  = delta[(lbase + l) * DD + dblk * 16 + q];
        btl[l][q] = Bt[(lbase + l) * NN + q];
        if (PHASE == 1) ctl[l][q] = Ct[(lbase + l) * NN + q];
    }
    __syncthreads();
    const int dloc = tid >> 4, n = tid & 15;
    const float lam = softplusf(loglam[(dblk * 16 + dloc) * NN + n]);
    float hv = 0.f, ap = 1.f;
    if (PHASE == 1) hv = hstart[((size_t)(b * 16 + c)) * 4096 + dblk * 256 + tid];
    for (int l = 0; l < 128; ++l) {
        float dv = dl[l][dloc];
        float a = __expf(-dv * lam);
        hv = fmaf(a, hv, dv * btl[l][n]);
        if (PHASE == 0) ap *= a;
        else ys[(lbase + l) * (DD * NN) + dblk * 256 + tid] = __float2bfloat16(hv * ctl[l][n]);
    }
    if (PHASE == 0) {
        size_t oi = ((size_t)(b * 16 + c)) * 4096 + dblk * 256 + tid;
        sA[oi] = ap; sB[oi] = hv;
    }
}

// chunk-summary combine: h at chunk starts (+ optional final state)
__global__ void ssm_comb_kernel(const float* __restrict__ sA, const float* __restrict__ sB,
                                float* __restrict__ hstart, float* __restrict__ hfin) {
    const int id = blockIdx.x * 256 + threadIdx.x;   // < BB*4096
    const int b = id >> 12, col = id & 4095;
    float h = 0.f;
#pragma unroll
    for (int c = 0; c < 16; ++c) {
        size_t oi = ((size_t)(b * 16 + c)) * 4096 + col;
        hstart[oi] = h;
        h = fmaf(sA[oi], h, sB[oi]);
    }
    if (hfin) hfin[(size_t)b * 4096 + col] = h;
}

// ---------------- layer-2 last-position SSM output, split-K -----------------
// part[b][c][d] = sum_{p in chunk c} hfin[b][p]*Ct_last[b][p&15] * wo[p][d]
__global__ void last_ssm_part_kernel(const float* __restrict__ hfin, const float* __restrict__ Ct,
                                     const float* __restrict__ wo, float* __restrict__ part) {
    __shared__ float hC[4][128];
    const int c = blockIdx.x, tid = threadIdx.x;
    const int p0 = c * 128;
#pragma unroll
    for (int e = 0; e < 2; ++e) {
        int i = e * 256 + tid;                 // < 512
        int b = i >> 7, p = i & 127;
        hC[b][p] = hfin[b * 4096 + p0 + p] *
                   Ct[((size_t)b * LL + (LL - 1)) * NN + (p & 15)];
    }
    __syncthreads();
    float a0 = 0.f, a1 = 0.f, a2 = 0.f, a3 = 0.f;
    for (int p = 0; p < 128; ++p) {
        float wv = wo[(size_t)(p0 + p) * DD + tid];
        a0 = fmaf(hC[0][p], wv, a0);
        a1 = fmaf(hC[1][p], wv, a1);
        a2 = fmaf(hC[2][p], wv, a2);
        a3 = fmaf(hC[3][p], wv, a3);
    }
    part[(0 * 32 + c) * DD + tid] = a0;
    part[(1 * 32 + c) * DD + tid] = a1;
    part[(2 * 32 + c) * DD + tid] = a2;
    part[(3 * 32 + c) * DD + tid] = a3;
}

__global__ void last_ssm_red_kernel(const float* __restrict__ part, const float* __restrict__ bo,
                                    float* __restrict__ outlast) {
    const int b = blockIdx.x, d = threadIdx.x;
    float acc = bo[d];
#pragma unroll
    for (int c = 0; c < 32; ++c) acc += part[(b * 32 + c) * DD + d];
    outlast[b * DD + d] = acc;
}

// ---------------- layer-2 last-position gate + proj + residual --------------
__global__ void last_proj_kernel(const float* __restrict__ xn, const float* __restrict__ outlast,
                                 const float* __restrict__ gw, const float* __restrict__ gb,
                                 const float* __restrict__ pw, const float* __restrict__ pb,
                                 const float* __restrict__ resid, float* __restrict__ xtlast) {
    __shared__ float xrow[256];
    __shared__ float xsg[256];
    const int b = blockIdx.x, d = threadIdx.x;
    const size_t rbase = ((size_t)b * LL + (LL - 1)) * DD;
    xrow[d] = xn[rbase + d];
    __syncthreads();
    float acc = gb[d];
    for (int k = 0; k < 256; ++k) acc = fmaf(xrow[k], gw[(size_t)k * DD + d], acc);
    float g = sigmoidf_(acc);
    xsg[d] = outlast[b * DD + d] * g;
    __syncthreads();
    float acc2 = pb[d];
    for (int k = 0; k < 256; ++k) acc2 = fmaf(xsg[k], pw[(size_t)k * DD + d], acc2);
    xtlast[b * DD + d] = acc2 + resid[rbase + d];
}

// ---------------- radix-2 FFT, 2048-pt, one sequence (b,d) per block --------
__global__ __launch_bounds__(256)
void fft_kernel(const float* __restrict__ h, const float* __restrict__ tab,
                float* __restrict__ Xre, float* __restrict__ Xim) {
    __shared__ float re[2048];
    __shared__ float im[2048];
    __shared__ float ct[1024];
    __shared__ float st[1024];
    const int tid = threadIdx.x;
    const int seq = blockIdx.x;            // b*256 + d
    const int b = seq >> 8, d = seq & 255;
    for (int i = tid; i < 1024; i += 256) { ct[i] = tab[i]; st[i] = tab[2048 + i]; }
    const float* hp = h + (size_t)b * LL * DD + d;
    for (int i = tid; i < 2048; i += 256) {
        int r = (int)(__brev((unsigned)i) >> 21);   // 11-bit reversal
        re[r] = hp[(size_t)i * DD];
        im[r] = 0.f;
    }
    __syncthreads();
#pragma unroll
    for (int s = 1; s <= 11; ++s) {
        const int half = 1 << (s - 1);
        const int tsh = 11 - s;
#pragma unroll
        for (int e = 0; e < 4; ++e) {
            int q = e * 256 + tid;
            int j = q & (half - 1);
            int i0 = ((q >> (s - 1)) << s) + j;
            int i1 = i0 + half;
            int tw = j << tsh;
            float wr = ct[tw], wi = -st[tw];
            float xr = re[i1], xi = im[i1];
            float tr = xr * wr - xi * wi;
            float ti = xr * wi + xi * wr;
            float ur = re[i0], ui = im[i0];
            re[i0] = ur + tr; im[i0] = ui + ti;
            re[i1] = ur - tr; im[i1] = ui - ti;
        }
        __syncthreads();
    }
    float* xr = Xre + (size_t)seq * FSTR;
    float* xi = Xim + (size_t)seq * FSTR;
    for (int f = tid; f < FCNT; f += 256) { xr[f] = re[f]; xi[f] = im[f]; }
}

// ---------------- mag partials: part[sb][f] = sum over 64 seqs of |X| -------
__global__ void mag_part_kernel(const float* __restrict__ Xre, const float* __restrict__ Xim,
                                float* __restrict__ part) {
    const int fb = blockIdx.x;      // 0..4 (f0 = fb*256)
    const int sb = blockIdx.y;      // 0..15 (seq0 = sb*64)
    const int tid = threadIdx.x;
    const int f = fb * 256 + tid;
    float s = 0.f;
    if (f < FCNT) {
        for (int q = 0; q < 64; ++q) {
            size_t base = (size_t)(sb * 64 + q) * FSTR + f;
            float re = Xre[base], im = Xim[base];
            s += sqrtf(re * re + im * im);
        }
    }
    part[sb * 1280 + fb * 256 + tid] = s;
}

// ---------------- top-32 (reduces mag partials first) ------------------------
__global__ void topk_kernel(const float* __restrict__ part, int* __restrict__ sel) {
    __shared__ float vals[1280];
    __shared__ float rv[256];
    __shared__ int ri[256];
    const int tid = threadIdx.x;
    for (int i = tid; i < 1280; i += 256) {
        float v = -1e30f;
        if (i < FCNT) {
            v = 0.f;
#pragma unroll
            for (int sb = 0; sb < 16; ++sb) v += part[sb * 1280 + i];
        }
        vals[i] = v;
    }
    __syncthreads();
    for (int k = 0; k < 32; ++k) {
        float bv = -1e30f; int bi = 0x7fffffff;
        for (int i = tid; i < FCNT; i += 256) {
            float v = vals[i];
            if (v > bv) { bv = v; bi = i; }
        }
        rv[tid] = bv; ri[tid] = bi; __syncthreads();
        for (int s = 128; s > 0; s >>= 1) {
            if (tid < s) {
                if (rv[tid + s] > rv[tid] ||
                    (rv[tid + s] == rv[tid] && ri[tid + s] < ri[tid])) {
                    rv[tid] = rv[tid + s]; ri[tid] = ri[tid + s];
                }
            }
            __syncthreads();
        }
        if (tid == 0) { sel[k] = ri[0]; vals[ri[0]] = -1e30f; }
        __syncthreads();
    }
}

// ---------------- xs_spectral at t = L-1 only --------------------------------
__global__ void xslast_kernel(const float* __restrict__ Xre, const float* __restrict__ Xim,
                              const int* __restrict__ sel, const float* __restrict__ fr,
                              const float* __restrict__ fi, const float* __restrict__ tab,
                              float* __restrict__ xsl) {
    const int b = blockIdx.x, d = threadIdx.x;
    const size_t sbase = (size_t)(b * 256 + d) * FSTR;
    float acc = 0.f;
    for (int j = 0; j < 32; ++j) {
        int f = sel[j];
        float xr = Xre[sbase + f];
        float xi = Xim[sbase + f];
        float frv = fr[d * KK + j], fiv = fi[d * KK + j];
        float xor_ = xr * frv - xi * fiv;
        float xoi  = xr * fiv + xi * frv;
        int kk2 = (f * (LL - 1)) & (LL - 1);
        float c = tab[kk2], s = tab[2048 + kk2];
        float w = (f == 0 || f == 1024) ? 1.f : 2.f;
        acc = fmaf(w, xor_ * c - xoi * s, acc);
    }
    xsl[b * DD + d] = acc * (1.f / LL);
}

// ---------------- final head: mix, LN, MLP -> out (B,2) ----------------------
__global__ void head_kernel(const float* __restrict__ xtlast, const float* __restrict__ xslast,
                            const float* __restrict__ alpha, const float* __restrict__ beta,
                            const float* __restrict__ gout, const float* __restrict__ bout,
                            const float* __restrict__ hw1, const float* __restrict__ hb1,
                            const float* __restrict__ hw2, const float* __restrict__ hb2,
                            float* __restrict__ out) {
    __shared__ float red[256];
    __shared__ float z[256];
    __shared__ float hid[128];
    const int b = blockIdx.x, tid = threadIdx.x;
    float zv = alpha[tid] * xtlast[b * 256 + tid] + beta[tid] * xslast[b * 256 + tid];
    red[tid] = zv; __syncthreads();
    for (int s = 128; s > 0; s >>= 1) { if (tid < s) red[tid] += red[tid + s]; __syncthreads(); }
    float m = red[0] * (1.f / DD);
    __syncthreads();
    float c = zv - m;
    red[tid] = c * c; __syncthreads();
    for (int s = 128; s > 0; s >>= 1) { if (tid < s) red[tid] += red[tid + s]; __syncthreads(); }
    float var = red[0] * (1.f / DD);
    z[tid] = c * rsqrtf(var + 1e-5f) * gout[tid] + bout[tid];
    __syncthreads();
    if (tid < 128) {
        float a = hb1[tid];
        for (int k = 0; k < 256; ++k) a = fmaf(z[k], hw1[(size_t)k * 128 + tid], a);
        hid[tid] = a * sigmoidf_(a);
    }
    __syncthreads();
    if (tid < 2) {
        float a = hb2[tid];
        for (int k = 0; k < 128; ++k) a = fmaf(hid[k], hw2[(size_t)k * 2 + tid], a);
        out[b * 2 + tid] = a;
    }
}

extern "C" void kernel_launch(void* const* d_in, const int* in_sizes, int n_in,
                              void* d_out, int out_size, void* d_ws, size_t ws_size,
                              hipStream_t stream) {
    const float* x      = (const float*)d_in[0];
    const float* w_in   = (const float*)d_in[1];
    const float* b_in   = (const float*)d_in[2];
    const float* ln_g   = (const float*)d_in[3];
    const float* ln_b   = (const float*)d_in[4];
    const float* conv_w = (const float*)d_in[5];
    const float* conv_b = (const float*)d_in[6];
    const float* loglam = (const float*)d_in[7];
    const float* wd     = (const float*)d_in[8];
    const float* bd     = (const float*)d_in[9];
    const float* wb     = (const float*)d_in[10];
    const float* wc     = (const float*)d_in[11];
    const float* wo     = (const float*)d_in[12];
    const float* bo     = (const float*)d_in[13];
    const float* gw     = (const float*)d_in[14];
    const float* gb     = (const float*)d_in[15];
    const float* pw     = (const float*)d_in[16];
    const float* pb     = (const float*)d_in[17];
    const float* fr     = (const float*)d_in[18];
    const float* fi     = (const float*)d_in[19];
    const float* alpha  = (const float*)d_in[20];
    const float* beta   = (const float*)d_in[21];
    const float* gout   = (const float*)d_in[22];
    const float* bout   = (const float*)d_in[23];
    const float* hw1    = (const float*)d_in[24];
    const float* hb1    = (const float*)d_in[25];
    const float* hw2    = (const float*)d_in[26];
    const float* hb2    = (const float*)d_in[27];

    float* ws = (float*)d_ws;
    size_t o = 0;
    auto alloc = [&](size_t n) { float* p = ws + o; o += (n + 15) & ~(size_t)15; return p; };

    const size_t BLnDD = (size_t)BLn * DD;
    float* h      = alloc(BLnDD);
    float* xt1    = alloc(BLnDD);
    float* xn     = alloc(BLnDD);   // also reused as gate fp32 output
    float* xc     = alloc(BLnDD);
    float* delta  = alloc(BLnDD);   // also reused as ssmout
    float* Btm    = alloc((size_t)BLn * NN);
    float* Ctm    = alloc((size_t)BLn * NN);
    float* tab    = alloc(4096);
    float* ysf    = alloc(BLnDD * NN / 2);          // ys bf16 region; later Xre/Xim
    float* sA     = alloc((size_t)BB * 16 * 4096);
    float* sB     = alloc((size_t)BB * 16 * 4096);
    float* hst    = alloc((size_t)BB * 16 * 4096);
    float* xnbf_f = alloc(BLnDD / 2);
    float* xcbf_f = alloc(BLnDD / 2);
    float* xsgf   = alloc(BLnDD / 2);
    float* wdt_f  = alloc((size_t)2 * DD * DD / 2);
    float* gwt_f  = alloc((size_t)DD * DD / 2);
    float* pwt_f  = alloc((size_t)DD * DD / 2);
    float* wot_f  = alloc((size_t)DD * NN * DD / 2);
    float* magp   = alloc(16 * 1280);
    int*   sel    = (int*)alloc(32);
    float* hfin   = alloc((size_t)BB * DD * NN);
    float* lpart  = alloc((size_t)BB * 32 * DD);
    float* outlast= alloc(BB * DD);
    float* xtlast = alloc(BB * DD);
    float* xslast = alloc(BB * DD);

    __hip_bfloat16* ys    = (__hip_bfloat16*)ysf;
    float*          Xre   = ysf;                        // alias: ys dead before FFT
    float*          Xim   = ysf + (size_t)1024 * FSTR;
    __hip_bfloat16* xn_bf = (__hip_bfloat16*)xnbf_f;
    __hip_bfloat16* xc_bf = (__hip_bfloat16*)xcbf_f;
    __hip_bfloat16* xsg_bf= (__hip_bfloat16*)xsgf;
    __hip_bfloat16* wdt0  = (__hip_bfloat16*)wdt_f;
    __hip_bfloat16* wdt1  = wdt0 + (size_t)DD * DD;
    __hip_bfloat16* gwt   = (__hip_bfloat16*)gwt_f;
    __hip_bfloat16* pwt   = (__hip_bfloat16*)pwt_f;
    __hip_bfloat16* wot   = (__hip_bfloat16*)wot_f;

    const dim3 blk(256);

    twiddle_kernel<<<8, blk, 0, stream>>>(tab);
    tcast_kernel<<<dim3(8, 8),   blk, 0, stream>>>(wd,                    wdt0, DD, DD);
    tcast_kernel<<<dim3(8, 8),   blk, 0, stream>>>(wd + (size_t)DD * DD,  wdt1, DD, DD);
    tcast_kernel<<<dim3(8, 8),   blk, 0, stream>>>(gw,                    gwt,  DD, DD);
    tcast_kernel<<<dim3(8, 8),   blk, 0, stream>>>(pw,                    pwt,  DD, DD);
    tcast_kernel<<<dim3(8, 128), blk, 0, stream>>>(wo,                    wot,  DD * NN, DD);

    // h = x @ w_in + b_in  (fp32, K=64)
    gemm64<<<dim3(DD / 64, BLn / 64), blk, 0, stream>>>(x, w_in, b_in, h, BLn, DD, INF_);

    const dim3 mgrid(DD / 64, BLn / 128);
    const dim3 sgrid(16, 16, BB);

    // ---- layer 0 (full sequence) ----
    ln_kernel<<<BLn, blk, 0, stream>>>(h, ln_g, ln_b, xn, xn_bf);
    conv_kernel<<<(BLn * DD) / 256, blk, 0, stream>>>(xn, conv_w, conv_b, xc, xc_bf);
    gemm_mfma<<<mgrid, blk, 0, stream>>>(xc_bf, wdt0, bd, nullptr, delta, BLn, DD, DD, 1);
    gemm_n16<<<BLn / 16, blk, 0, stream>>>(xc, wb, Btm);
    gemm_n16<<<BLn / 16, blk, 0, stream>>>(xc, wc, Ctm);
    ssm_chunk_kernel<0><<<sgrid, blk, 0, stream>>>(delta, Btm, nullptr, loglam,
                                                   nullptr, sA, sB, nullptr);
    ssm_comb_kernel<<<BB * 4096 / 256, blk, 0, stream>>>(sA, sB, hst, nullptr);
    ssm_chunk_kernel<1><<<sgrid, blk, 0, stream>>>(delta, Btm, Ctm, loglam,
                                                   hst, nullptr, nullptr, ys);
    float* ssmout = delta;   // delta dead after phase 1
    gemm_mfma<<<mgrid, blk, 0, stream>>>(ys, wot, bo, nullptr, ssmout, BLn, DD, DD * NN, 0);
    float* gatebuf = xn;     // xn fp32 dead after conv
    gemm_mfma<<<mgrid, blk, 0, stream>>>(xn_bf, gwt, gb, nullptr, gatebuf, BLn, DD, DD, 2);
    mulbf_kernel<<<(BLn * DD) / 256, blk, 0, stream>>>(ssmout, gatebuf, xsg_bf);
    gemm_mfma<<<mgrid, blk, 0, stream>>>(xsg_bf, pwt, pb, h, xt1, BLn, DD, DD, 0);

    // ---- layer 1 (only final state needed downstream) ----
    ln_kernel<<<BLn, blk, 0, stream>>>(xt1, ln_g + DD, ln_b + DD, xn, xn_bf);
    conv_kernel<<<(BLn * DD) / 256, blk, 0, stream>>>(xn, conv_w + DD * 3, conv_b + DD, xc, xc_bf);
    gemm_mfma<<<mgrid, blk, 0, stream>>>(xc_bf, wdt1, bd + DD, nullptr, delta, BLn, DD, DD, 1);
    gemm_n16<<<BLn / 16, blk, 0, stream>>>(xc, wb + DD * NN, Btm);
    gemm_n16<<<BLn / 16, blk, 0, stream>>>(xc, wc + DD * NN, Ctm);
    ssm_chunk_kernel<0><<<sgrid, blk, 0, stream>>>(delta, Btm, nullptr, loglam + DD * NN,
                                                   nullptr, sA, sB, nullptr);
    ssm_comb_kernel<<<BB * 4096 / 256, blk, 0, stream>>>(sA, sB, hst, hfin);
    last_ssm_part_kernel<<<32, blk, 0, stream>>>(hfin, Ctm, wo + (size_t)DD * NN * DD, lpart);
    last_ssm_red_kernel<<<BB, blk, 0, stream>>>(lpart, bo + DD, outlast);
    last_proj_kernel<<<BB, blk, 0, stream>>>(xn, outlast, gw + (size_t)DD * DD, gb + DD,
                                             pw + (size_t)DD * DD, pb + DD, xt1, xtlast);

    // ---- spectral path on h (only t = L-1 needed downstream) ----
    fft_kernel<<<1024, blk, 0, stream>>>(h, tab, Xre, Xim);
    mag_part_kernel<<<dim3(5, 16), blk, 0, stream>>>(Xre, Xim, magp);
    topk_kernel<<<1, blk, 0, stream>>>(magp, sel);
    xslast_kernel<<<BB, blk, 0, stream>>>(Xre, Xim, sel, fr, fi, tab, xslast);

    head_kernel<<<BB, blk, 0, stream>>>(xtlast, xslast, alpha, beta, gout, bout,
                                        hw1, hb1, hw2, hb2, (float*)d_out);
}

// Round 6
// 369.808 us; speedup vs baseline: 6.3436x; 1.2181x over previous
//
#include <hip/hip_runtime.h>
#include <hip/hip_bf16.h>
#include <math.h>

#define BB   4
#define LL   2048
#define INF_ 64
#define DD   256
#define NN   16
#define KK   32
#define BLn  (BB*LL)      // 8192
#define FCNT 1025         // L/2+1
#define FSTR 1056         // padded per-sequence stride for X

typedef short short8 __attribute__((ext_vector_type(8)));
typedef float f32x4  __attribute__((ext_vector_type(4)));

__device__ __forceinline__ float softplusf(float x) {
    return x > 20.f ? x : log1pf(__expf(x));
}
__device__ __forceinline__ float sigmoidf_(float x) {
    return 1.f / (1.f + __expf(-x));
}

// ---------------- twiddle table: tab[k]=cos(2*pi*k/2048), tab[2048+k]=sin ----
__global__ void twiddle_kernel(float* tab) {
    int i = blockIdx.x * 256 + threadIdx.x;
    if (i < 2048) {
        double ang = 2.0 * 3.14159265358979323846 * (double)i / 2048.0;
        tab[i]        = (float)cos(ang);
        tab[2048 + i] = (float)sin(ang);
    }
}

// ---------------- transpose+cast weights: W[K][N] fp32 -> Wt[N][K] bf16 -----
__global__ void tcast_kernel(const float* __restrict__ W, __hip_bfloat16* __restrict__ Wt,
                             int K, int N) {
    __shared__ float t[32][33];
    const int k0 = blockIdx.y * 32, n0 = blockIdx.x * 32;
    const int tx = threadIdx.x & 31, ty = threadIdx.x >> 5;
    for (int r = ty; r < 32; r += 8) t[r][tx] = W[(size_t)(k0 + r) * N + n0 + tx];
    __syncthreads();
    for (int r = ty; r < 32; r += 8)
        Wt[(size_t)(n0 + r) * K + k0 + tx] = __float2bfloat16(t[tx][r]);
}

// ---------------- fp32 GEMM (input projection only, K=64) -------------------
__global__ void gemm64(const float* __restrict__ A, const float* __restrict__ W,
                       const float* __restrict__ bias, float* __restrict__ C,
                       int M, int N, int K) {
    __shared__ float As[16][68];
    __shared__ float Ws[16][64];
    const int tid = threadIdx.x;
    const int tx = tid & 15, ty = tid >> 4;
    const int row0 = blockIdx.y * 64, col0 = blockIdx.x * 64;
    float acc[4][4] = {};
    for (int k0 = 0; k0 < K; k0 += 16) {
#pragma unroll
        for (int e = 0; e < 4; ++e) {
            int p = e * 256 + tid;
            int kk = p & 15, m = p >> 4;
            As[kk][m] = A[(size_t)(row0 + m) * K + k0 + kk];
        }
#pragma unroll
        for (int e = 0; e < 4; ++e) {
            int p = e * 256 + tid;
            int kk = p >> 6, j = p & 63;
            Ws[kk][j] = W[(size_t)(k0 + kk) * N + col0 + j];
        }
        __syncthreads();
#pragma unroll
        for (int kk = 0; kk < 16; ++kk) {
            float4 a4 = *(const float4*)&As[kk][ty * 4];
            float4 w4 = *(const float4*)&Ws[kk][tx * 4];
            float av[4] = {a4.x, a4.y, a4.z, a4.w};
            float wv[4] = {w4.x, w4.y, w4.z, w4.w};
#pragma unroll
            for (int i = 0; i < 4; ++i)
#pragma unroll
                for (int j = 0; j < 4; ++j)
                    acc[i][j] = fmaf(av[i], wv[j], acc[i][j]);
        }
        __syncthreads();
    }
#pragma unroll
    for (int i = 0; i < 4; ++i) {
        int r = row0 + ty * 4 + i;
#pragma unroll
        for (int j = 0; j < 4; ++j) {
            int c = col0 + tx * 4 + j;
            C[(size_t)r * N + c] = acc[i][j] + bias[c];
        }
    }
}

// ---------------- bf16 MFMA GEMM, 64x64 tile, reg-prefetch 2-phase ----------
// C = act(A @ Wt^T + bias) [+ addend]; A:[M,K] bf16, Wt:[N,K] bf16.
__global__ __launch_bounds__(256)
void gemm_mfma(const __hip_bfloat16* __restrict__ Abf, const __hip_bfloat16* __restrict__ Wt,
               const float* __restrict__ bias, const float* __restrict__ addend,
               float* __restrict__ C, int M, int N, int K, int act) {
    __shared__ alignas(16) short As[64][40];
    __shared__ alignas(16) short Bs[64][40];
    const int tid = threadIdx.x;
    const int w = tid >> 6, lane = tid & 63;
    const int hi = lane >> 4, lo = lane & 15;
    const int row0 = blockIdx.y * 64, col0 = blockIdx.x * 64;
    const short* A = (const short*)Abf;
    const short* B = (const short*)Wt;
    f32x4 acc[4];
    f32x4 zz = {0.f, 0.f, 0.f, 0.f};
#pragma unroll
    for (int n = 0; n < 4; ++n) acc[n] = zz;
    const int sr = tid >> 2, sc = (tid & 3) * 8;   // 64x32 tile = 256 short8 chunks
    short8 pa = *(const short8*)&A[(size_t)(row0 + sr) * K + sc];
    short8 pb = *(const short8*)&B[(size_t)(col0 + sr) * K + sc];
    const int NIT = K >> 5;
    for (int it = 0; it < NIT; ++it) {
        __syncthreads();
        *(short8*)&As[sr][sc] = pa;
        *(short8*)&Bs[sr][sc] = pb;
        __syncthreads();
        if (it + 1 < NIT) {
            const int k0 = (it + 1) << 5;
            pa = *(const short8*)&A[(size_t)(row0 + sr) * K + k0 + sc];
            pb = *(const short8*)&B[(size_t)(col0 + sr) * K + k0 + sc];
        }
        short8 af = *(const short8*)&As[w * 16 + lo][hi * 8];
        short8 bfr[4];
#pragma unroll
        for (int n = 0; n < 4; ++n)
            bfr[n] = *(const short8*)&Bs[n * 16 + lo][hi * 8];
#pragma unroll
        for (int n = 0; n < 4; ++n)
            acc[n] = __builtin_amdgcn_mfma_f32_16x16x32_bf16(af, bfr[n], acc[n], 0, 0, 0);
    }
#pragma unroll
    for (int n = 0; n < 4; ++n) {
#pragma unroll
        for (int r = 0; r < 4; ++r) {
            int row = row0 + w * 16 + hi * 4 + r;
            int col = col0 + n * 16 + lo;
            float v = acc[n][r];
            if (bias) v += bias[col];
            if (act == 1) v = softplusf(v);
            else if (act == 2) v = sigmoidf_(v);
            if (addend) v += addend[(size_t)row * N + col];
            C[(size_t)row * N + col] = v;
        }
    }
}

// ---------------- split-K MFMA GEMM for ys@wo (M=8192,N=256,K=4096) ---------
// 128x64 tile, KSPLIT=2, XCD-swizzled so 4 col-blocks sharing A hit one L2.
#define SKM 8192
#define SKN 256
#define SKHALF 2048
__global__ __launch_bounds__(256)
void gemm_sk_kernel(const __hip_bfloat16* __restrict__ Abf, const __hip_bfloat16* __restrict__ Wt,
                    float* __restrict__ P) {
    __shared__ alignas(16) short As[128][40];
    __shared__ alignas(16) short Bs[64][40];
    const int tid = threadIdx.x;
    const int f = blockIdx.x;                   // 0..511
    const int xcd = f & 7, slot = f >> 3;
    const int col = slot & 3;
    const int rk = xcd + (slot >> 2) * 8;       // 0..127
    const int row = rk & 63, kb = rk >> 6;
    const int row0 = row * 128, col0 = col * 64;
    const size_t kbase = (size_t)kb * SKHALF;
    const int w = tid >> 6, lane = tid & 63;
    const int hi = lane >> 4, lo = lane & 15;
    const short* A = (const short*)Abf;
    const short* B = (const short*)Wt;
    f32x4 acc[2][4];
    f32x4 zz = {0.f, 0.f, 0.f, 0.f};
#pragma unroll
    for (int m = 0; m < 2; ++m)
#pragma unroll
        for (int n = 0; n < 4; ++n) acc[m][n] = zz;
    // A tile 128x32 = 512 chunks (2/thread); B 64x32 = 256 chunks (1/thread)
    const int ra0 = tid >> 2,          ca0 = (tid & 3) * 8;
    const int ra1 = (256 + tid) >> 2,  ca1 = ((256 + tid) & 3) * 8;
    short8 pa0 = *(const short8*)&A[(size_t)(row0 + ra0) * 4096 + kbase + ca0];
    short8 pa1 = *(const short8*)&A[(size_t)(row0 + ra1) * 4096 + kbase + ca1];
    short8 pb  = *(const short8*)&B[(size_t)(col0 + ra0) * 4096 + kbase + ca0];
    for (int it = 0; it < 64; ++it) {
        __syncthreads();
        *(short8*)&As[ra0][ca0] = pa0;
        *(short8*)&As[ra1][ca1] = pa1;
        *(short8*)&Bs[ra0][ca0] = pb;
        __syncthreads();
        if (it + 1 < 64) {
            const size_t k0 = kbase + ((it + 1) << 5);
            pa0 = *(const short8*)&A[(size_t)(row0 + ra0) * 4096 + k0 + ca0];
            pa1 = *(const short8*)&A[(size_t)(row0 + ra1) * 4096 + k0 + ca1];
            pb  = *(const short8*)&B[(size_t)(col0 + ra0) * 4096 + k0 + ca0];
        }
        short8 af[2], bfr[4];
#pragma unroll
        for (int m = 0; m < 2; ++m)
            af[m] = *(const short8*)&As[w * 32 + m * 16 + lo][hi * 8];
#pragma unroll
        for (int n = 0; n < 4; ++n)
            bfr[n] = *(const short8*)&Bs[n * 16 + lo][hi * 8];
#pragma unroll
        for (int m = 0; m < 2; ++m)
#pragma unroll
            for (int n = 0; n < 4; ++n)
                acc[m][n] = __builtin_amdgcn_mfma_f32_16x16x32_bf16(af[m], bfr[n], acc[m][n], 0, 0, 0);
    }
    float* Pk = P + (size_t)kb * SKM * SKN;
#pragma unroll
    for (int m = 0; m < 2; ++m)
#pragma unroll
        for (int n = 0; n < 4; ++n)
#pragma unroll
            for (int r = 0; r < 4; ++r) {
                int rr = row0 + w * 32 + m * 16 + hi * 4 + r;
                int cc = col0 + n * 16 + lo;
                Pk[(size_t)rr * SKN + cc] = acc[m][n][r];
            }
}

// C = P0 + P1 + bias  (2M elements, float4 per thread)
__global__ void sk_red_kernel(const float* __restrict__ P, const float* __restrict__ bias,
                              float* __restrict__ C) {
    const int i = (blockIdx.x * 256 + threadIdx.x) * 4;
    float4 a = *(const float4*)&P[i];
    float4 b = *(const float4*)&P[(size_t)SKM * SKN + i];
    float4 bb = *(const float4*)&bias[i & 255];
    float4 o = {a.x + b.x + bb.x, a.y + b.y + bb.y, a.z + b.z + bb.z, a.w + b.w + bb.w};
    *(float4*)&C[i] = o;
}

// ---------------- small GEMM: C[M,16] = A[M,256] @ W[256,16] (no bias) ------
__global__ void gemm_n16(const float* __restrict__ A, const float* __restrict__ W,
                         float* __restrict__ C) {
    __shared__ float As[16][260];
    __shared__ float Ws[256][16];
    const int tid = threadIdx.x;
    const int row0 = blockIdx.x * 16;
#pragma unroll
    for (int e = 0; e < 16; ++e)
        As[e][tid] = A[(size_t)(row0 + e) * 256 + tid];
#pragma unroll
    for (int e = 0; e < 16; ++e) {
        int p = e * 256 + tid;
        Ws[p >> 4][p & 15] = W[p];
    }
    __syncthreads();
    const int r = tid >> 4, n = tid & 15;
    float acc = 0.f;
#pragma unroll 8
    for (int k = 0; k < 256; ++k)
        acc = fmaf(As[r][k], Ws[k][n], acc);
    C[(size_t)(row0 + r) * 16 + n] = acc;
}

// ---------------- LayerNorm over D=256 (fp32 out + bf16 out) ----------------
__global__ void ln_kernel(const float* __restrict__ X, const float* __restrict__ g,
                          const float* __restrict__ b, float* __restrict__ Y,
                          __hip_bfloat16* __restrict__ Ybf) {
    __shared__ float red[256];
    const int row = blockIdx.x, tid = threadIdx.x;
    const size_t base = (size_t)row * DD;
    float v = X[base + tid];
    red[tid] = v; __syncthreads();
    for (int s = 128; s > 0; s >>= 1) { if (tid < s) red[tid] += red[tid + s]; __syncthreads(); }
    float m = red[0] * (1.f / DD);
    __syncthreads();
    float c = v - m;
    red[tid] = c * c; __syncthreads();
    for (int s = 128; s > 0; s >>= 1) { if (tid < s) red[tid] += red[tid + s]; __syncthreads(); }
    float var = red[0] * (1.f / DD);
    float y = c * rsqrtf(var + 1e-5f) * g[tid] + b[tid];
    Y[base + tid] = y;
    Ybf[base + tid] = __float2bfloat16(y);
}

// ---------------- depthwise conv k=3 (fp32 out + bf16 out) ------------------
__global__ void conv_kernel(const float* __restrict__ Xn, const float* __restrict__ cw,
                            const float* __restrict__ cb, float* __restrict__ Xc,
                            __hip_bfloat16* __restrict__ Xcbf) {
    const size_t i = (size_t)blockIdx.x * 256 + threadIdx.x;
    const int d = (int)(i & 255);
    const int l = (int)((i >> 8) & (LL - 1));
    float w0 = cw[d * 3 + 0], w1 = cw[d * 3 + 1], w2 = cw[d * 3 + 2];
    float xm = (l > 0)      ? Xn[i - DD] : 0.f;
    float x0 = Xn[i];
    float xp = (l < LL - 1) ? Xn[i + DD] : 0.f;
    float y = fmaf(w0, xm, fmaf(w1, x0, fmaf(w2, xp, cb[d])));
    Xc[i] = y;
    Xcbf[i] = __float2bfloat16(y);
}

__global__ void mulbf_kernel(const float* __restrict__ a, const float* __restrict__ b,
                             __hip_bfloat16* __restrict__ c) {
    size_t i = (size_t)blockIdx.x * 256 + threadIdx.x;
    c[i] = __float2bfloat16(a[i] * b[i]);
}

// ---------------- chunked SSM scan ------------------------------------------
template<int PHASE>
__global__ void ssm_chunk_kernel(const float* __restrict__ delta, const float* __restrict__ Bt,
                                 const float* __restrict__ Ct, const float* __restrict__ loglam,
                                 const float* __restrict__ hstart,
                                 float* __restrict__ sA, float* __restrict__ sB,
                                 __hip_bfloat16* __restrict__ ys) {
    __shared__ float dl[128][16];
    __shared__ float btl[128][16];
    __shared__ float ctl[128][16];
    const int dblk = blockIdx.x, c = blockIdx.y, b = blockIdx.z;
    const int tid = threadIdx.x;
    const size_t lbase = (size_t)b * LL + c * 128;
    for (int i = tid; i < 2048; i += 256) {
        int l = i >> 4, q = i & 15;
        dl[l][q]  = delta[(lbase + l) * DD + dblk * 16 + q];
        btl[l][q] = Bt[(lbase + l) * NN + q];
        if (PHASE == 1) ctl[l][q] = Ct[(lbase + l) * NN + q];
    }
    __syncthreads();
    const int dloc = tid >> 4, n = tid & 15;
    const float lam = softplusf(loglam[(dblk * 16 + dloc) * NN + n]);
    float hv = 0.f, ap = 1.f;
    if (PHASE == 1) hv = hstart[((size_t)(b * 16 + c)) * 4096 + dblk * 256 + tid];
    for (int l = 0; l < 128; ++l) {
        float dv = dl[l][dloc];
        float a = __expf(-dv * lam);
        hv = fmaf(a, hv, dv * btl[l][n]);
        if (PHASE == 0) ap *= a;
        else ys[(lbase + l) * (DD * NN) + dblk * 256 + tid] = __float2bfloat16(hv * ctl[l][n]);
    }
    if (PHASE == 0) {
        size_t oi = ((size_t)(b * 16 + c)) * 4096 + dblk * 256 + tid;
        sA[oi] = ap; sB[oi] = hv;
    }
}

// chunk-summary combine: h at chunk starts (+ optional final state)
__global__ void ssm_comb_kernel(const float* __restrict__ sA, const float* __restrict__ sB,
                                float* __restrict__ hstart, float* __restrict__ hfin) {
    const int id = blockIdx.x * 256 + threadIdx.x;   // < BB*4096
    const int b = id >> 12, col = id & 4095;
    float h = 0.f;
#pragma unroll
    for (int c = 0; c < 16; ++c) {
        size_t oi = ((size_t)(b * 16 + c)) * 4096 + col;
        hstart[oi] = h;
        h = fmaf(sA[oi], h, sB[oi]);
    }
    if (hfin) hfin[(size_t)b * 4096 + col] = h;
}

// ---------------- layer-2 last-position SSM output, split-K -----------------
__global__ void last_ssm_part_kernel(const float* __restrict__ hfin, const float* __restrict__ Ct,
                                     const float* __restrict__ wo, float* __restrict__ part) {
    __shared__ float hC[4][128];
    const int c = blockIdx.x, tid = threadIdx.x;
    const int p0 = c * 128;
#pragma unroll
    for (int e = 0; e < 2; ++e) {
        int i = e * 256 + tid;                 // < 512
        int b = i >> 7, p = i & 127;
        hC[b][p] = hfin[b * 4096 + p0 + p] *
                   Ct[((size_t)b * LL + (LL - 1)) * NN + (p & 15)];
    }
    __syncthreads();
    float a0 = 0.f, a1 = 0.f, a2 = 0.f, a3 = 0.f;
    for (int p = 0; p < 128; ++p) {
        float wv = wo[(size_t)(p0 + p) * DD + tid];
        a0 = fmaf(hC[0][p], wv, a0);
        a1 = fmaf(hC[1][p], wv, a1);
        a2 = fmaf(hC[2][p], wv, a2);
        a3 = fmaf(hC[3][p], wv, a3);
    }
    part[(0 * 32 + c) * DD + tid] = a0;
    part[(1 * 32 + c) * DD + tid] = a1;
    part[(2 * 32 + c) * DD + tid] = a2;
    part[(3 * 32 + c) * DD + tid] = a3;
}

__global__ void last_ssm_red_kernel(const float* __restrict__ part, const float* __restrict__ bo,
                                    float* __restrict__ outlast) {
    const int b = blockIdx.x, d = threadIdx.x;
    float acc = bo[d];
#pragma unroll
    for (int c = 0; c < 32; ++c) acc += part[(b * 32 + c) * DD + d];
    outlast[b * DD + d] = acc;
}

// ---------------- layer-2 last-position gate + proj + residual --------------
__global__ void last_proj_kernel(const float* __restrict__ xn, const float* __restrict__ outlast,
                                 const float* __restrict__ gw, const float* __restrict__ gb,
                                 const float* __restrict__ pw, const float* __restrict__ pb,
                                 const float* __restrict__ resid, float* __restrict__ xtlast) {
    __shared__ float xrow[256];
    __shared__ float xsg[256];
    const int b = blockIdx.x, d = threadIdx.x;
    const size_t rbase = ((size_t)b * LL + (LL - 1)) * DD;
    xrow[d] = xn[rbase + d];
    __syncthreads();
    float acc = gb[d];
    for (int k = 0; k < 256; ++k) acc = fmaf(xrow[k], gw[(size_t)k * DD + d], acc);
    float g = sigmoidf_(acc);
    xsg[d] = outlast[b * DD + d] * g;
    __syncthreads();
    float acc2 = pb[d];
    for (int k = 0; k < 256; ++k) acc2 = fmaf(xsg[k], pw[(size_t)k * DD + d], acc2);
    xtlast[b * DD + d] = acc2 + resid[rbase + d];
}

// ---------------- radix-2 FFT, 2048-pt, one sequence (b,d) per block --------
__global__ __launch_bounds__(256)
void fft_kernel(const float* __restrict__ h, const float* __restrict__ tab,
                float* __restrict__ Xre, float* __restrict__ Xim) {
    __shared__ float re[2048];
    __shared__ float im[2048];
    __shared__ float ct[1024];
    __shared__ float st[1024];
    const int tid = threadIdx.x;
    const int seq = blockIdx.x;            // b*256 + d
    const int b = seq >> 8, d = seq & 255;
    for (int i = tid; i < 1024; i += 256) { ct[i] = tab[i]; st[i] = tab[2048 + i]; }
    const float* hp = h + (size_t)b * LL * DD + d;
    for (int i = tid; i < 2048; i += 256) {
        int r = (int)(__brev((unsigned)i) >> 21);   // 11-bit reversal
        re[r] = hp[(size_t)i * DD];
        im[r] = 0.f;
    }
    __syncthreads();
#pragma unroll
    for (int s = 1; s <= 11; ++s) {
        const int half = 1 << (s - 1);
        const int tsh = 11 - s;
#pragma unroll
        for (int e = 0; e < 4; ++e) {
            int q = e * 256 + tid;
            int j = q & (half - 1);
            int i0 = ((q >> (s - 1)) << s) + j;
            int i1 = i0 + half;
            int tw = j << tsh;
            float wr = ct[tw], wi = -st[tw];
            float xr = re[i1], xi = im[i1];
            float tr = xr * wr - xi * wi;
            float ti = xr * wi + xi * wr;
            float ur = re[i0], ui = im[i0];
            re[i0] = ur + tr; im[i0] = ui + ti;
            re[i1] = ur - tr; im[i1] = ui - ti;
        }
        __syncthreads();
    }
    float* xr = Xre + (size_t)seq * FSTR;
    float* xi = Xim + (size_t)seq * FSTR;
    for (int f = tid; f < FCNT; f += 256) { xr[f] = re[f]; xi[f] = im[f]; }
}

// ---------------- mag partials: part[sb][f] = sum over 64 seqs of |X| -------
__global__ void mag_part_kernel(const float* __restrict__ Xre, const float* __restrict__ Xim,
                                float* __restrict__ part) {
    const int fb = blockIdx.x;      // 0..4
    const int sb = blockIdx.y;      // 0..15
    const int tid = threadIdx.x;
    const int f = fb * 256 + tid;
    float s = 0.f;
    if (f < FCNT) {
        for (int q = 0; q < 64; ++q) {
            size_t base = (size_t)(sb * 64 + q) * FSTR + f;
            float re = Xre[base], im = Xim[base];
            s += sqrtf(re * re + im * im);
        }
    }
    part[sb * 1280 + fb * 256 + tid] = s;
}

// ---------------- top-32 (wave-shfl argmax; ties -> lower idx) ---------------
__global__ void topk_kernel(const float* __restrict__ part, int* __restrict__ sel) {
    __shared__ float vals[1280];
    __shared__ float wv[4];
    __shared__ int wi[4];
    const int tid = threadIdx.x;
    const int lane = tid & 63, wid = tid >> 6;
    for (int i = tid; i < 1280; i += 256) {
        float v = -1e30f;
        if (i < FCNT) {
            v = 0.f;
#pragma unroll
            for (int sb = 0; sb < 16; ++sb) v += part[sb * 1280 + i];
        }
        vals[i] = v;
    }
    __syncthreads();
    for (int k = 0; k < 32; ++k) {
        float bv = -1e30f; int bi = 0x7fffffff;
        for (int i = tid; i < FCNT; i += 256) {
            float v = vals[i];
            if (v > bv) { bv = v; bi = i; }
        }
#pragma unroll
        for (int off = 32; off > 0; off >>= 1) {
            float ov = __shfl_down(bv, off);
            int   oi = __shfl_down(bi, off);
            if (ov > bv || (ov == bv && oi < bi)) { bv = ov; bi = oi; }
        }
        if (lane == 0) { wv[wid] = bv; wi[wid] = bi; }
        __syncthreads();
        if (tid == 0) {
            float fv = wv[0]; int fi = wi[0];
#pragma unroll
            for (int q = 1; q < 4; ++q)
                if (wv[q] > fv || (wv[q] == fv && wi[q] < fi)) { fv = wv[q]; fi = wi[q]; }
            sel[k] = fi;
            vals[fi] = -1e30f;
        }
        __syncthreads();
    }
}

// ---------------- xs_spectral at t = L-1 only --------------------------------
__global__ void xslast_kernel(const float* __restrict__ Xre, const float* __restrict__ Xim,
                              const int* __restrict__ sel, const float* __restrict__ fr,
                              const float* __restrict__ fi, const float* __restrict__ tab,
                              float* __restrict__ xsl) {
    const int b = blockIdx.x, d = threadIdx.x;
    const size_t sbase = (size_t)(b * 256 + d) * FSTR;
    float acc = 0.f;
    for (int j = 0; j < 32; ++j) {
        int f = sel[j];
        float xr = Xre[sbase + f];
        float xi = Xim[sbase + f];
        float frv = fr[d * KK + j], fiv = fi[d * KK + j];
        float xor_ = xr * frv - xi * fiv;
        float xoi  = xr * fiv + xi * frv;
        int kk2 = (f * (LL - 1)) & (LL - 1);
        float c = tab[kk2], s = tab[2048 + kk2];
        float w = (f == 0 || f == 1024) ? 1.f : 2.f;
        acc = fmaf(w, xor_ * c - xoi * s, acc);
    }
    xsl[b * DD + d] = acc * (1.f / LL);
}

// ---------------- final head: mix, LN, MLP -> out (B,2) ----------------------
__global__ void head_kernel(const float* __restrict__ xtlast, const float* __restrict__ xslast,
                            const float* __restrict__ alpha, const float* __restrict__ beta,
                            const float* __restrict__ gout, const float* __restrict__ bout,
                            const float* __restrict__ hw1, const float* __restrict__ hb1,
                            const float* __restrict__ hw2, const float* __restrict__ hb2,
                            float* __restrict__ out) {
    __shared__ float red[256];
    __shared__ float z[256];
    __shared__ float hid[128];
    const int b = blockIdx.x, tid = threadIdx.x;
    float zv = alpha[tid] * xtlast[b * 256 + tid] + beta[tid] * xslast[b * 256 + tid];
    red[tid] = zv; __syncthreads();
    for (int s = 128; s > 0; s >>= 1) { if (tid < s) red[tid] += red[tid + s]; __syncthreads(); }
    float m = red[0] * (1.f / DD);
    __syncthreads();
    float c = zv - m;
    red[tid] = c * c; __syncthreads();
    for (int s = 128; s > 0; s >>= 1) { if (tid < s) red[tid] += red[tid + s]; __syncthreads(); }
    float var = red[0] * (1.f / DD);
    z[tid] = c * rsqrtf(var + 1e-5f) * gout[tid] + bout[tid];
    __syncthreads();
    if (tid < 128) {
        float a = hb1[tid];
        for (int k = 0; k < 256; ++k) a = fmaf(z[k], hw1[(size_t)k * 128 + tid], a);
        hid[tid] = a * sigmoidf_(a);
    }
    __syncthreads();
    if (tid < 2) {
        float a = hb2[tid];
        for (int k = 0; k < 128; ++k) a = fmaf(hid[k], hw2[(size_t)k * 2 + tid], a);
        out[b * 2 + tid] = a;
    }
}

extern "C" void kernel_launch(void* const* d_in, const int* in_sizes, int n_in,
                              void* d_out, int out_size, void* d_ws, size_t ws_size,
                              hipStream_t stream) {
    const float* x      = (const float*)d_in[0];
    const float* w_in   = (const float*)d_in[1];
    const float* b_in   = (const float*)d_in[2];
    const float* ln_g   = (const float*)d_in[3];
    const float* ln_b   = (const float*)d_in[4];
    const float* conv_w = (const float*)d_in[5];
    const float* conv_b = (const float*)d_in[6];
    const float* loglam = (const float*)d_in[7];
    const float* wd     = (const float*)d_in[8];
    const float* bd     = (const float*)d_in[9];
    const float* wb     = (const float*)d_in[10];
    const float* wc     = (const float*)d_in[11];
    const float* wo     = (const float*)d_in[12];
    const float* bo     = (const float*)d_in[13];
    const float* gw     = (const float*)d_in[14];
    const float* gb     = (const float*)d_in[15];
    const float* pw     = (const float*)d_in[16];
    const float* pb     = (const float*)d_in[17];
    const float* fr     = (const float*)d_in[18];
    const float* fi     = (const float*)d_in[19];
    const float* alpha  = (const float*)d_in[20];
    const float* beta   = (const float*)d_in[21];
    const float* gout   = (const float*)d_in[22];
    const float* bout   = (const float*)d_in[23];
    const float* hw1    = (const float*)d_in[24];
    const float* hb1    = (const float*)d_in[25];
    const float* hw2    = (const float*)d_in[26];
    const float* hb2    = (const float*)d_in[27];

    float* ws = (float*)d_ws;
    size_t o = 0;
    auto alloc = [&](size_t n) { float* p = ws + o; o += (n + 15) & ~(size_t)15; return p; };

    const size_t BLnDD = (size_t)BLn * DD;
    float* h      = alloc(BLnDD);
    float* xt1    = alloc(BLnDD);   // with xn: also split-K partial buffer (16 MB)
    float* xn     = alloc(BLnDD);   // also reused as gate fp32 output
    float* xc     = alloc(BLnDD);
    float* delta  = alloc(BLnDD);   // also reused as ssmout
    float* Btm    = alloc((size_t)BLn * NN);
    float* Ctm    = alloc((size_t)BLn * NN);
    float* tab    = alloc(4096);
    float* ysf    = alloc(BLnDD * NN / 2);          // ys bf16 region; later Xre/Xim
    float* sA     = alloc((size_t)BB * 16 * 4096);
    float* sB     = alloc((size_t)BB * 16 * 4096);
    float* hst    = alloc((size_t)BB * 16 * 4096);
    float* xnbf_f = alloc(BLnDD / 2);
    float* xcbf_f = alloc(BLnDD / 2);
    float* xsgf   = alloc(BLnDD / 2);
    float* wdt_f  = alloc((size_t)2 * DD * DD / 2);
    float* gwt_f  = alloc((size_t)DD * DD / 2);
    float* pwt_f  = alloc((size_t)DD * DD / 2);
    float* wot_f  = alloc((size_t)DD * NN * DD / 2);
    float* magp   = alloc(16 * 1280);
    int*   sel    = (int*)alloc(32);
    float* hfin   = alloc((size_t)BB * DD * NN);
    float* lpart  = alloc((size_t)BB * 32 * DD);
    float* outlast= alloc(BB * DD);
    float* xtlast = alloc(BB * DD);
    float* xslast = alloc(BB * DD);

    __hip_bfloat16* ys    = (__hip_bfloat16*)ysf;
    float*          Xre   = ysf;                        // alias: ys dead before FFT
    float*          Xim   = ysf + (size_t)1024 * FSTR;
    __hip_bfloat16* xn_bf = (__hip_bfloat16*)xnbf_f;
    __hip_bfloat16* xc_bf = (__hip_bfloat16*)xcbf_f;
    __hip_bfloat16* xsg_bf= (__hip_bfloat16*)xsgf;
    __hip_bfloat16* wdt0  = (__hip_bfloat16*)wdt_f;
    __hip_bfloat16* wdt1  = wdt0 + (size_t)DD * DD;
    __hip_bfloat16* gwt   = (__hip_bfloat16*)gwt_f;
    __hip_bfloat16* pwt   = (__hip_bfloat16*)pwt_f;
    __hip_bfloat16* wot   = (__hip_bfloat16*)wot_f;
    float*          Pbuf  = xt1;    // xt1+xn contiguous: 16 MB split-K partials

    const dim3 blk(256);

    twiddle_kernel<<<8, blk, 0, stream>>>(tab);
    tcast_kernel<<<dim3(8, 8),   blk, 0, stream>>>(wd,                    wdt0, DD, DD);
    tcast_kernel<<<dim3(8, 8),   blk, 0, stream>>>(wd + (size_t)DD * DD,  wdt1, DD, DD);
    tcast_kernel<<<dim3(8, 8),   blk, 0, stream>>>(gw,                    gwt,  DD, DD);
    tcast_kernel<<<dim3(8, 8),   blk, 0, stream>>>(pw,                    pwt,  DD, DD);
    tcast_kernel<<<dim3(8, 128), blk, 0, stream>>>(wo,                    wot,  DD * NN, DD);

    // h = x @ w_in + b_in  (fp32, K=64)
    gemm64<<<dim3(DD / 64, BLn / 64), blk, 0, stream>>>(x, w_in, b_in, h, BLn, DD, INF_);

    const dim3 mgrid(DD / 64, BLn / 64);     // 64x64-tile MFMA GEMMs: 512 blocks
    const dim3 sgrid(16, 16, BB);

    // ---- layer 0 (full sequence) ----
    ln_kernel<<<BLn, blk, 0, stream>>>(h, ln_g, ln_b, xn, xn_bf);
    conv_kernel<<<(BLn * DD) / 256, blk, 0, stream>>>(xn, conv_w, conv_b, xc, xc_bf);
    gemm_mfma<<<mgrid, blk, 0, stream>>>(xc_bf, wdt0, bd, nullptr, delta, BLn, DD, DD, 1);
    gemm_n16<<<BLn / 16, blk, 0, stream>>>(xc, wb, Btm);
    gemm_n16<<<BLn / 16, blk, 0, stream>>>(xc, wc, Ctm);
    ssm_chunk_kernel<0><<<sgrid, blk, 0, stream>>>(delta, Btm, nullptr, loglam,
                                                   nullptr, sA, sB, nullptr);
    ssm_comb_kernel<<<BB * 4096 / 256, blk, 0, stream>>>(sA, sB, hst, nullptr);
    ssm_chunk_kernel<1><<<sgrid, blk, 0, stream>>>(delta, Btm, Ctm, loglam,
                                                   hst, nullptr, nullptr, ys);
    float* ssmout = delta;   // delta dead after phase 1
    gemm_sk_kernel<<<512, blk, 0, stream>>>(ys, wot, Pbuf);
    sk_red_kernel<<<(SKM * SKN) / 1024, blk, 0, stream>>>(Pbuf, bo, ssmout);
    float* gatebuf = xn;     // xn fp32 dead (and P dead after reduce)
    gemm_mfma<<<mgrid, blk, 0, stream>>>(xn_bf, gwt, gb, nullptr, gatebuf, BLn, DD, DD, 2);
    mulbf_kernel<<<(BLn * DD) / 256, blk, 0, stream>>>(ssmout, gatebuf, xsg_bf);
    gemm_mfma<<<mgrid, blk, 0, stream>>>(xsg_bf, pwt, pb, h, xt1, BLn, DD, DD, 0);

    // ---- layer 1 (only final state needed downstream) ----
    ln_kernel<<<BLn, blk, 0, stream>>>(xt1, ln_g + DD, ln_b + DD, xn, xn_bf);
    conv_kernel<<<(BLn * DD) / 256, blk, 0, stream>>>(xn, conv_w + DD * 3, conv_b + DD, xc, xc_bf);
    gemm_mfma<<<mgrid, blk, 0, stream>>>(xc_bf, wdt1, bd + DD, nullptr, delta, BLn, DD, DD, 1);
    gemm_n16<<<BLn / 16, blk, 0, stream>>>(xc, wb + DD * NN, Btm);
    gemm_n16<<<BLn / 16, blk, 0, stream>>>(xc, wc + DD * NN, Ctm);
    ssm_chunk_kernel<0><<<sgrid, blk, 0, stream>>>(delta, Btm, nullptr, loglam + DD * NN,
                                                   nullptr, sA, sB, nullptr);
    ssm_comb_kernel<<<BB * 4096 / 256, blk, 0, stream>>>(sA, sB, hst, hfin);
    last_ssm_part_kernel<<<32, blk, 0, stream>>>(hfin, Ctm, wo + (size_t)DD * NN * DD, lpart);
    last_ssm_red_kernel<<<BB, blk, 0, stream>>>(lpart, bo + DD, outlast);
    last_proj_kernel<<<BB, blk, 0, stream>>>(xn, outlast, gw + (size_t)DD * DD, gb + DD,
                                             pw + (size_t)DD * DD, pb + DD, xt1, xtlast);

    // ---- spectral path on h (only t = L-1 needed downstream) ----
    fft_kernel<<<1024, blk, 0, stream>>>(h, tab, Xre, Xim);
    mag_part_kernel<<<dim3(5, 16), blk, 0, stream>>>(Xre, Xim, magp);
    topk_kernel<<<1, blk, 0, stream>>>(magp, sel);
    xslast_kernel<<<BB, blk, 0, stream>>>(Xre, Xim, sel, fr, fi, tab, xslast);

    head_kernel<<<BB, blk, 0, stream>>>(xtlast, xslast, alpha, beta, gout, bout,
                                        hw1, hb1, hw2, hb2, (float*)d_out);
}

// Round 7
// 315.528 us; speedup vs baseline: 7.4348x; 1.1720x over previous
//
#include <hip/hip_runtime.h>
#include <hip/hip_bf16.h>
#include <math.h>

#define BB   4
#define LL   2048
#define INF_ 64
#define DD   256
#define NN   16
#define KK   32
#define BLn  (BB*LL)      // 8192
#define FCNT 1025
#define FSTR 1056
#define SKM  8192
#define SKN  256
#define PSZ  ((size_t)SKM * SKN)
#define IX(x) ((x) + ((x) >> 6))

typedef short short8 __attribute__((ext_vector_type(8)));
typedef float f32x4  __attribute__((ext_vector_type(4)));

__device__ __forceinline__ float softplusf(float x) {
    return x > 20.f ? x : log1pf(__expf(x));
}
__device__ __forceinline__ float sigmoidf_(float x) {
    return 1.f / (1.f + __expf(-x));
}

// ---------------- twiddle: tab[k]=cos(2pi k/2048), tab[2048+k]=sin ----------
__global__ void twiddle_kernel(float* tab) {
    int i = blockIdx.x * 256 + threadIdx.x;
    if (i < 2048) {
        double ang = 2.0 * 3.14159265358979323846 * (double)i / 2048.0;
        tab[i]        = (float)cos(ang);
        tab[2048 + i] = (float)sin(ang);
    }
}

// ---------------- transpose+cast: W[K][N] fp32 -> Wt[N][K] bf16 -------------
__global__ void tcast_kernel(const float* __restrict__ W, __hip_bfloat16* __restrict__ Wt,
                             int K, int N) {
    __shared__ float t[32][33];
    const int k0 = blockIdx.y * 32, n0 = blockIdx.x * 32;
    const int tx = threadIdx.x & 31, ty = threadIdx.x >> 5;
    for (int r = ty; r < 32; r += 8) t[r][tx] = W[(size_t)(k0 + r) * N + n0 + tx];
    __syncthreads();
    for (int r = ty; r < 32; r += 8)
        Wt[(size_t)(n0 + r) * K + k0 + tx] = __float2bfloat16(t[tx][r]);
}

// pack wb/wc columns into cat rows 256..287 (cat[n][k] bf16, K=256)
__global__ void pack16_kernel(const float* __restrict__ wb, const float* __restrict__ wc,
                              __hip_bfloat16* __restrict__ cat) {
    const int j = blockIdx.x;          // 0..31
    const int k = threadIdx.x;         // 0..255
    const float* src = (j < 16) ? wb : wc;
    const int jj = j & 15;
    cat[(size_t)(256 + j) * 256 + k] = __float2bfloat16(src[k * 16 + jj]);
}

// ---------------- h transpose: [b][l][d] -> ht [b][d][l] ---------------------
__global__ void htrans_kernel(const float* __restrict__ h, float* __restrict__ ht) {
    __shared__ float t[32][33];
    const int b = blockIdx.z;
    const int l0 = blockIdx.x * 32, d0 = blockIdx.y * 32;
    const int tx = threadIdx.x & 31, ty = threadIdx.x >> 5;
    for (int r = ty; r < 32; r += 8)
        t[r][tx] = h[((size_t)b * LL + l0 + r) * DD + d0 + tx];
    __syncthreads();
    for (int r = ty; r < 32; r += 8)
        ht[((size_t)b * DD + d0 + r) * LL + l0 + tx] = t[tx][r];
}

// ---------------- fp32 GEMM (input projection, K=64) ------------------------
__global__ void gemm64(const float* __restrict__ A, const float* __restrict__ W,
                       const float* __restrict__ bias, float* __restrict__ C,
                       int M, int N, int K) {
    __shared__ float As[16][68];
    __shared__ float Ws[16][64];
    const int tid = threadIdx.x;
    const int tx = tid & 15, ty = tid >> 4;
    const int row0 = blockIdx.y * 64, col0 = blockIdx.x * 64;
    float acc[4][4] = {};
    for (int k0 = 0; k0 < K; k0 += 16) {
#pragma unroll
        for (int e = 0; e < 4; ++e) {
            int p = e * 256 + tid;
            As[p & 15][p >> 4] = A[(size_t)(row0 + (p >> 4)) * K + k0 + (p & 15)];
        }
#pragma unroll
        for (int e = 0; e < 4; ++e) {
            int p = e * 256 + tid;
            Ws[p >> 6][p & 63] = W[(size_t)(k0 + (p >> 6)) * N + col0 + (p & 63)];
        }
        __syncthreads();
#pragma unroll
        for (int kk = 0; kk < 16; ++kk) {
            float4 a4 = *(const float4*)&As[kk][ty * 4];
            float4 w4 = *(const float4*)&Ws[kk][tx * 4];
            float av[4] = {a4.x, a4.y, a4.z, a4.w};
            float wv[4] = {w4.x, w4.y, w4.z, w4.w};
#pragma unroll
            for (int i = 0; i < 4; ++i)
#pragma unroll
                for (int j = 0; j < 4; ++j)
                    acc[i][j] = fmaf(av[i], wv[j], acc[i][j]);
        }
        __syncthreads();
    }
#pragma unroll
    for (int i = 0; i < 4; ++i) {
        int r = row0 + ty * 4 + i;
#pragma unroll
        for (int j = 0; j < 4; ++j) {
            int c = col0 + tx * 4 + j;
            C[(size_t)r * N + c] = acc[i][j] + bias[c];
        }
    }
}

// ---------------- 64x64 MFMA core, LDS double-buffer, K=256 -----------------
// MODE 0 (qbc):  A=xc_bf, B=cat[320][256]; epilogue -> delta/Bt/Ct
// MODE 1 (gate): A=xn_bf, B=gwt; epilogue sigmoid(v+gb)*(P0+P1+bo) -> xsg bf16
// MODE 2 (proj): A=xsg_bf, B=pwt; epilogue v+pb+h -> xt1 fp32
template<int MODE>
__global__ __launch_bounds__(256)
void gemm_core(const short* __restrict__ A, const short* __restrict__ Bw,
               const float* __restrict__ bias, const float* __restrict__ x1,
               const float* __restrict__ x2, float* __restrict__ o0,
               float* __restrict__ o1, float* __restrict__ o2,
               __hip_bfloat16* __restrict__ ob) {
    __shared__ alignas(16) short As[2][64][40];
    __shared__ alignas(16) short Bs[2][64][40];
    const int tid = threadIdx.x;
    const int w = tid >> 6, lane = tid & 63;
    const int hi = lane >> 4, lo = lane & 15;
    const int row0 = blockIdx.y * 64, col0 = blockIdx.x * 64;
    f32x4 acc[4];
    f32x4 zz = {0.f, 0.f, 0.f, 0.f};
#pragma unroll
    for (int n = 0; n < 4; ++n) acc[n] = zz;
    const int sr = tid >> 2, sc = (tid & 3) * 8;
    // prologue: stage tile 0, prefetch tile 1
    short8 pa = *(const short8*)&A[(size_t)(row0 + sr) * 256 + sc];
    short8 pb = *(const short8*)&Bw[(size_t)(col0 + sr) * 256 + sc];
    *(short8*)&As[0][sr][sc] = pa;
    *(short8*)&Bs[0][sr][sc] = pb;
    pa = *(const short8*)&A[(size_t)(row0 + sr) * 256 + 32 + sc];
    pb = *(const short8*)&Bw[(size_t)(col0 + sr) * 256 + 32 + sc];
    __syncthreads();
    int cur = 0;
    for (int it = 0; it < 8; ++it) {
        if (it + 1 < 8) {
            *(short8*)&As[cur ^ 1][sr][sc] = pa;
            *(short8*)&Bs[cur ^ 1][sr][sc] = pb;
        }
        if (it + 2 < 8) {
            const int k0 = (it + 2) << 5;
            pa = *(const short8*)&A[(size_t)(row0 + sr) * 256 + k0 + sc];
            pb = *(const short8*)&Bw[(size_t)(col0 + sr) * 256 + k0 + sc];
        }
        short8 af = *(const short8*)&As[cur][w * 16 + lo][hi * 8];
        short8 bfr[4];
#pragma unroll
        for (int n = 0; n < 4; ++n)
            bfr[n] = *(const short8*)&Bs[cur][n * 16 + lo][hi * 8];
#pragma unroll
        for (int n = 0; n < 4; ++n)
            acc[n] = __builtin_amdgcn_mfma_f32_16x16x32_bf16(af, bfr[n], acc[n], 0, 0, 0);
        __syncthreads();
        cur ^= 1;
    }
#pragma unroll
    for (int n = 0; n < 4; ++n) {
#pragma unroll
        for (int r = 0; r < 4; ++r) {
            const int row = row0 + w * 16 + hi * 4 + r;
            const int col = col0 + n * 16 + lo;
            float v = acc[n][r];
            if constexpr (MODE == 0) {
                if (col < 256)      o0[(size_t)row * 256 + col] = softplusf(v + bias[col]);
                else if (col < 272) o1[(size_t)row * 16 + col - 256] = v;
                else if (col < 288) o2[(size_t)row * 16 + col - 272] = v;
            } else if constexpr (MODE == 1) {
                float g = sigmoidf_(v + bias[col]);
                float s = x1[(size_t)row * 256 + col] + x1[PSZ + (size_t)row * 256 + col] + x2[col];
                ob[(size_t)row * 256 + col] = __float2bfloat16(g * s);
            } else {
                o0[(size_t)row * 256 + col] = v + bias[col] + x1[(size_t)row * 256 + col];
            }
        }
    }
}

// ---------------- split-K GEMM ys@wo, 128x64 tile, LDS dbuf -----------------
__global__ __launch_bounds__(256)
void gemm_sk_kernel(const __hip_bfloat16* __restrict__ Abf, const __hip_bfloat16* __restrict__ Wt,
                    float* __restrict__ P) {
    __shared__ alignas(16) short As[2][128][40];
    __shared__ alignas(16) short Bs[2][64][40];
    const int tid = threadIdx.x;
    const int f = blockIdx.x;                   // 0..511
    const int xcd = f & 7, slot = f >> 3;
    const int col = slot & 3;
    const int rk = xcd + (slot >> 2) * 8;       // 0..127
    const int row = rk & 63, kb = rk >> 6;
    const int row0 = row * 128, col0 = col * 64;
    const size_t kbase = (size_t)kb * 2048;
    const int w = tid >> 6, lane = tid & 63;
    const int hi = lane >> 4, lo = lane & 15;
    const short* A = (const short*)Abf;
    const short* B = (const short*)Wt;
    f32x4 acc[2][4];
    f32x4 zz = {0.f, 0.f, 0.f, 0.f};
#pragma unroll
    for (int m = 0; m < 2; ++m)
#pragma unroll
        for (int n = 0; n < 4; ++n) acc[m][n] = zz;
    const int ra0 = tid >> 2,          ca0 = (tid & 3) * 8;
    const int ra1 = (256 + tid) >> 2,  ca1 = ((256 + tid) & 3) * 8;
    short8 pa0 = *(const short8*)&A[(size_t)(row0 + ra0) * 4096 + kbase + ca0];
    short8 pa1 = *(const short8*)&A[(size_t)(row0 + ra1) * 4096 + kbase + ca1];
    short8 pb  = *(const short8*)&B[(size_t)(col0 + ra0) * 4096 + kbase + ca0];
    *(short8*)&As[0][ra0][ca0] = pa0;
    *(short8*)&As[0][ra1][ca1] = pa1;
    *(short8*)&Bs[0][ra0][ca0] = pb;
    pa0 = *(const short8*)&A[(size_t)(row0 + ra0) * 4096 + kbase + 32 + ca0];
    pa1 = *(const short8*)&A[(size_t)(row0 + ra1) * 4096 + kbase + 32 + ca1];
    pb  = *(const short8*)&B[(size_t)(col0 + ra0) * 4096 + kbase + 32 + ca0];
    __syncthreads();
    int cur = 0;
    for (int it = 0; it < 64; ++it) {
        if (it + 1 < 64) {
            *(short8*)&As[cur ^ 1][ra0][ca0] = pa0;
            *(short8*)&As[cur ^ 1][ra1][ca1] = pa1;
            *(short8*)&Bs[cur ^ 1][ra0][ca0] = pb;
        }
        if (it + 2 < 64) {
            const size_t k0 = kbase + ((it + 2) << 5);
            pa0 = *(const short8*)&A[(size_t)(row0 + ra0) * 4096 + k0 + ca0];
            pa1 = *(const short8*)&A[(size_t)(row0 + ra1) * 4096 + k0 + ca1];
            pb  = *(const short8*)&B[(size_t)(col0 + ra0) * 4096 + k0 + ca0];
        }
        short8 af[2], bfr[4];
#pragma unroll
        for (int m = 0; m < 2; ++m)
            af[m] = *(const short8*)&As[cur][w * 32 + m * 16 + lo][hi * 8];
#pragma unroll
        for (int n = 0; n < 4; ++n)
            bfr[n] = *(const short8*)&Bs[cur][n * 16 + lo][hi * 8];
#pragma unroll
        for (int m = 0; m < 2; ++m)
#pragma unroll
            for (int n = 0; n < 4; ++n)
                acc[m][n] = __builtin_amdgcn_mfma_f32_16x16x32_bf16(af[m], bfr[n], acc[m][n], 0, 0, 0);
        __syncthreads();
        cur ^= 1;
    }
    float* Pk = P + (size_t)kb * PSZ;
#pragma unroll
    for (int m = 0; m < 2; ++m)
#pragma unroll
        for (int n = 0; n < 4; ++n)
#pragma unroll
            for (int r = 0; r < 4; ++r) {
                int rr = row0 + w * 32 + m * 16 + hi * 4 + r;
                int cc = col0 + n * 16 + lo;
                Pk[(size_t)rr * SKN + cc] = acc[m][n][r];
            }
}

// ---------------- LayerNorm over D=256 -> bf16 -------------------------------
__global__ void ln_kernel(const float* __restrict__ X, const float* __restrict__ g,
                          const float* __restrict__ b, __hip_bfloat16* __restrict__ Ybf) {
    __shared__ float red[256];
    const int row = blockIdx.x, tid = threadIdx.x;
    const size_t base = (size_t)row * DD;
    float v = X[base + tid];
    red[tid] = v; __syncthreads();
    for (int s = 128; s > 0; s >>= 1) { if (tid < s) red[tid] += red[tid + s]; __syncthreads(); }
    float m = red[0] * (1.f / DD);
    __syncthreads();
    float c = v - m;
    red[tid] = c * c; __syncthreads();
    for (int s = 128; s > 0; s >>= 1) { if (tid < s) red[tid] += red[tid + s]; __syncthreads(); }
    float var = red[0] * (1.f / DD);
    Ybf[base + tid] = __float2bfloat16(c * rsqrtf(var + 1e-5f) * g[tid] + b[tid]);
}

// ---------------- depthwise conv k=3 (bf16 in, bf16 out) --------------------
__global__ void conv_kernel(const __hip_bfloat16* __restrict__ Xn, const float* __restrict__ cw,
                            const float* __restrict__ cb, __hip_bfloat16* __restrict__ Xcbf) {
    const size_t i = (size_t)blockIdx.x * 256 + threadIdx.x;
    const int d = (int)(i & 255);
    const int l = (int)((i >> 8) & (LL - 1));
    float w0 = cw[d * 3 + 0], w1 = cw[d * 3 + 1], w2 = cw[d * 3 + 2];
    float xm = (l > 0)      ? __bfloat162float(Xn[i - DD]) : 0.f;
    float x0 = __bfloat162float(Xn[i]);
    float xp = (l < LL - 1) ? __bfloat162float(Xn[i + DD]) : 0.f;
    Xcbf[i] = __float2bfloat16(fmaf(w0, xm, fmaf(w1, x0, fmaf(w2, xp, cb[d]))));
}

// ---------------- chunked SSM scan ------------------------------------------
template<int PHASE>
__global__ void ssm_chunk_kernel(const float* __restrict__ delta, const float* __restrict__ Bt,
                                 const float* __restrict__ Ct, const float* __restrict__ loglam,
                                 const float* __restrict__ hstart,
                                 float* __restrict__ sA, float* __restrict__ sB,
                                 __hip_bfloat16* __restrict__ ys) {
    __shared__ float dl[128][16];
    __shared__ float btl[128][16];
    __shared__ float ctl[128][16];
    const int dblk = blockIdx.x, c = blockIdx.y, b = blockIdx.z;
    const int tid = threadIdx.x;
    const size_t lbase = (size_t)b * LL + c * 128;
    for (int i = tid; i < 2048; i += 256) {
        int l = i >> 4, q = i & 15;
        dl[l][q]  = delta[(lbase + l) * DD + dblk * 16 + q];
        btl[l][q] = Bt[(lbase + l) * NN + q];
        if (PHASE == 1) ctl[l][q] = Ct[(lbase + l) * NN + q];
    }
    __syncthreads();
    const int dloc = tid >> 4, n = tid & 15;
    const float lam = softplusf(loglam[(dblk * 16 + dloc) * NN + n]);
    float hv = 0.f, ap = 1.f;
    if (PHASE == 1) hv = hstart[((size_t)(b * 16 + c)) * 4096 + dblk * 256 + tid];
    for (int l = 0; l < 128; ++l) {
        float dv = dl[l][dloc];
        float a = __expf(-dv * lam);
        hv = fmaf(a, hv, dv * btl[l][n]);
        if (PHASE == 0) ap *= a;
        else ys[(lbase + l) * (DD * NN) + dblk * 256 + tid] = __float2bfloat16(hv * ctl[l][n]);
    }
    if (PHASE == 0) {
        size_t oi = ((size_t)(b * 16 + c)) * 4096 + dblk * 256 + tid;
        sA[oi] = ap; sB[oi] = hv;
    }
}

__global__ void ssm_comb_kernel(const float* __restrict__ sA, const float* __restrict__ sB,
                                float* __restrict__ hstart, float* __restrict__ hfin) {
    const int id = blockIdx.x * 256 + threadIdx.x;
    const int b = id >> 12, col = id & 4095;
    float h = 0.f;
#pragma unroll
    for (int c = 0; c < 16; ++c) {
        size_t oi = ((size_t)(b * 16 + c)) * 4096 + col;
        hstart[oi] = h;
        h = fmaf(sA[oi], h, sB[oi]);
    }
    if (hfin) hfin[(size_t)b * 4096 + col] = h;
}

// ---------------- layer-2 last-position SSM output, split-K -----------------
__global__ void last_ssm_part_kernel(const float* __restrict__ hfin, const float* __restrict__ Ct,
                                     const float* __restrict__ wo, float* __restrict__ part) {
    __shared__ float hC[4][128];
    const int c = blockIdx.x, tid = threadIdx.x;
    const int p0 = c * 128;
#pragma unroll
    for (int e = 0; e < 2; ++e) {
        int i = e * 256 + tid;
        int b = i >> 7, p = i & 127;
        hC[b][p] = hfin[b * 4096 + p0 + p] *
                   Ct[((size_t)b * LL + (LL - 1)) * NN + (p & 15)];
    }
    __syncthreads();
    float a0 = 0.f, a1 = 0.f, a2 = 0.f, a3 = 0.f;
    for (int p = 0; p < 128; ++p) {
        float wv = wo[(size_t)(p0 + p) * DD + tid];
        a0 = fmaf(hC[0][p], wv, a0);
        a1 = fmaf(hC[1][p], wv, a1);
        a2 = fmaf(hC[2][p], wv, a2);
        a3 = fmaf(hC[3][p], wv, a3);
    }
    part[(0 * 32 + c) * DD + tid] = a0;
    part[(1 * 32 + c) * DD + tid] = a1;
    part[(2 * 32 + c) * DD + tid] = a2;
    part[(3 * 32 + c) * DD + tid] = a3;
}

__global__ void last_ssm_red_kernel(const float* __restrict__ part, const float* __restrict__ bo,
                                    float* __restrict__ outlast) {
    const int b = blockIdx.x, d = threadIdx.x;
    float acc = bo[d];
#pragma unroll
    for (int c = 0; c < 32; ++c) acc += part[(b * 32 + c) * DD + d];
    outlast[b * DD + d] = acc;
}

// ---------------- layer-2 last-position gate + proj + residual --------------
__global__ void last_proj_kernel(const __hip_bfloat16* __restrict__ xn, const float* __restrict__ outlast,
                                 const float* __restrict__ gw, const float* __restrict__ gb,
                                 const float* __restrict__ pw, const float* __restrict__ pb,
                                 const float* __restrict__ resid, float* __restrict__ xtlast) {
    __shared__ float xrow[256];
    __shared__ float xsg[256];
    const int b = blockIdx.x, d = threadIdx.x;
    const size_t rbase = ((size_t)b * LL + (LL - 1)) * DD;
    xrow[d] = __bfloat162float(xn[rbase + d]);
    __syncthreads();
    float acc = gb[d];
    for (int k = 0; k < 256; ++k) acc = fmaf(xrow[k], gw[(size_t)k * DD + d], acc);
    float g = sigmoidf_(acc);
    xsg[d] = outlast[b * DD + d] * g;
    __syncthreads();
    float acc2 = pb[d];
    for (int k = 0; k < 256; ++k) acc2 = fmaf(xsg[k], pw[(size_t)k * DD + d], acc2);
    xtlast[b * DD + d] = acc2 + resid[rbase + d];
}

// ---------------- packed radix-2 FFT: 2 real seqs per block ------------------
// input ht [b][d][l]; block handles (b,d) and (b,d+128); rfft convention.
__global__ __launch_bounds__(256)
void fft2_kernel(const float* __restrict__ ht, const float* __restrict__ tab,
                 float* __restrict__ Xre, float* __restrict__ Xim) {
    __shared__ float re[2080];
    __shared__ float im[2080];
    __shared__ float c2[2048];
    __shared__ float s2[2048];
    const int tid = threadIdx.x;
    const int pair = blockIdx.x;           // 0..511
    const int b = pair >> 7, d0 = pair & 127;
    // stage-major twiddle table: c2[half+j] = cos(2pi j / 2^s)
    for (int p = tid; p < 2048; p += 256) {
        if (p >= 1) {
            int lh = 31 - __clz((unsigned)p);
            int j = p - (1 << lh);
            int t = j << (10 - lh);
            c2[p] = tab[t]; s2[p] = tab[2048 + t];
        }
    }
    const float* ha = ht + ((size_t)b * 256 + d0) * LL;
    const float* hb = ha + (size_t)128 * LL;
    for (int i = tid; i < 2048; i += 256) {
        int r = (int)(__brev((unsigned)i) >> 21);
        re[IX(r)] = ha[i];
        im[IX(r)] = hb[i];
    }
    __syncthreads();
#pragma unroll
    for (int s = 1; s <= 11; ++s) {
        const int half = 1 << (s - 1);
#pragma unroll
        for (int e = 0; e < 4; ++e) {
            int q = e * 256 + tid;
            int j = q & (half - 1);
            int i0 = ((q >> (s - 1)) << s) + j;
            int i1 = i0 + half;
            float wr = c2[half + j], wi = -s2[half + j];
            float xr = re[IX(i1)], xi = im[IX(i1)];
            float tr = xr * wr - xi * wi;
            float ti = xr * wi + xi * wr;
            float ur = re[IX(i0)], ui = im[IX(i0)];
            re[IX(i0)] = ur + tr; im[IX(i0)] = ui + ti;
            re[IX(i1)] = ur - tr; im[IX(i1)] = ui - ti;
        }
        __syncthreads();
    }
    const int seqa = b * 256 + d0;
    float* xra = Xre + (size_t)seqa * FSTR;
    float* xia = Xim + (size_t)seqa * FSTR;
    float* xrb = xra + (size_t)128 * FSTR;
    float* xib = xia + (size_t)128 * FSTR;
    for (int f = tid; f < FCNT; f += 256) {
        int nf = (2048 - f) & 2047;
        float zrf = re[IX(f)], zif = im[IX(f)];
        float zrn = re[IX(nf)], zin = im[IX(nf)];
        xra[f] = 0.5f * (zrf + zrn);
        xia[f] = 0.5f * (zif - zin);
        xrb[f] = 0.5f * (zif + zin);
        xib[f] = 0.5f * (zrn - zrf);
    }
}

// ---------------- mag partials ----------------------------------------------
__global__ void mag_part_kernel(const float* __restrict__ Xre, const float* __restrict__ Xim,
                                float* __restrict__ part) {
    const int fb = blockIdx.x, sb = blockIdx.y;
    const int tid = threadIdx.x;
    const int f = fb * 256 + tid;
    float s = 0.f;
    if (f < FCNT) {
        for (int q = 0; q < 64; ++q) {
            size_t base = (size_t)(sb * 64 + q) * FSTR + f;
            float re = Xre[base], im = Xim[base];
            s += sqrtf(re * re + im * im);
        }
    }
    part[sb * 1280 + fb * 256 + tid] = s;
}

// ---------------- top-32 (wave-shfl argmax; ties -> lower idx) ---------------
__global__ void topk_kernel(const float* __restrict__ part, int* __restrict__ sel) {
    __shared__ float vals[1280];
    __shared__ float wv[4];
    __shared__ int wi[4];
    const int tid = threadIdx.x;
    const int lane = tid & 63, wid = tid >> 6;
    for (int i = tid; i < 1280; i += 256) {
        float v = -1e30f;
        if (i < FCNT) {
            v = 0.f;
#pragma unroll
            for (int sb = 0; sb < 16; ++sb) v += part[sb * 1280 + i];
        }
        vals[i] = v;
    }
    __syncthreads();
    for (int k = 0; k < 32; ++k) {
        float bv = -1e30f; int bi = 0x7fffffff;
        for (int i = tid; i < FCNT; i += 256) {
            float v = vals[i];
            if (v > bv) { bv = v; bi = i; }
        }
#pragma unroll
        for (int off = 32; off > 0; off >>= 1) {
            float ov = __shfl_down(bv, off);
            int   oi = __shfl_down(bi, off);
            if (ov > bv || (ov == bv && oi < bi)) { bv = ov; bi = oi; }
        }
        if (lane == 0) { wv[wid] = bv; wi[wid] = bi; }
        __syncthreads();
        if (tid == 0) {
            float fv = wv[0]; int fi = wi[0];
#pragma unroll
            for (int q = 1; q < 4; ++q)
                if (wv[q] > fv || (wv[q] == fv && wi[q] < fi)) { fv = wv[q]; fi = wi[q]; }
            sel[k] = fi;
            vals[fi] = -1e30f;
        }
        __syncthreads();
    }
}

// ---------------- xs_spectral at t = L-1 only --------------------------------
__global__ void xslast_kernel(const float* __restrict__ Xre, const float* __restrict__ Xim,
                              const int* __restrict__ sel, const float* __restrict__ fr,
                              const float* __restrict__ fi, const float* __restrict__ tab,
                              float* __restrict__ xsl) {
    const int b = blockIdx.x, d = threadIdx.x;
    const size_t sbase = (size_t)(b * 256 + d) * FSTR;
    float acc = 0.f;
    for (int j = 0; j < 32; ++j) {
        int f = sel[j];
        float xr = Xre[sbase + f];
        float xi = Xim[sbase + f];
        float frv = fr[d * KK + j], fiv = fi[d * KK + j];
        float xor_ = xr * frv - xi * fiv;
        float xoi  = xr * fiv + xi * frv;
        int kk2 = (f * (LL - 1)) & (LL - 1);
        float c = tab[kk2], s = tab[2048 + kk2];
        float w = (f == 0 || f == 1024) ? 1.f : 2.f;
        acc = fmaf(w, xor_ * c - xoi * s, acc);
    }
    xsl[b * DD + d] = acc * (1.f / LL);
}

// ---------------- final head ------------------------------------------------
__global__ void head_kernel(const float* __restrict__ xtlast, const float* __restrict__ xslast,
                            const float* __restrict__ alpha, const float* __restrict__ beta,
                            const float* __restrict__ gout, const float* __restrict__ bout,
                            const float* __restrict__ hw1, const float* __restrict__ hb1,
                            const float* __restrict__ hw2, const float* __restrict__ hb2,
                            float* __restrict__ out) {
    __shared__ float red[256];
    __shared__ float z[256];
    __shared__ float hid[128];
    const int b = blockIdx.x, tid = threadIdx.x;
    float zv = alpha[tid] * xtlast[b * 256 + tid] + beta[tid] * xslast[b * 256 + tid];
    red[tid] = zv; __syncthreads();
    for (int s = 128; s > 0; s >>= 1) { if (tid < s) red[tid] += red[tid + s]; __syncthreads(); }
    float m = red[0] * (1.f / DD);
    __syncthreads();
    float c = zv - m;
    red[tid] = c * c; __syncthreads();
    for (int s = 128; s > 0; s >>= 1) { if (tid < s) red[tid] += red[tid + s]; __syncthreads(); }
    float var = red[0] * (1.f / DD);
    z[tid] = c * rsqrtf(var + 1e-5f) * gout[tid] + bout[tid];
    __syncthreads();
    if (tid < 128) {
        float a = hb1[tid];
        for (int k = 0; k < 256; ++k) a = fmaf(z[k], hw1[(size_t)k * 128 + tid], a);
        hid[tid] = a * sigmoidf_(a);
    }
    __syncthreads();
    if (tid < 2) {
        float a = hb2[tid];
        for (int k = 0; k < 128; ++k) a = fmaf(hid[k], hw2[(size_t)k * 2 + tid], a);
        out[b * 2 + tid] = a;
    }
}

extern "C" void kernel_launch(void* const* d_in, const int* in_sizes, int n_in,
                              void* d_out, int out_size, void* d_ws, size_t ws_size,
                              hipStream_t stream) {
    const float* x      = (const float*)d_in[0];
    const float* w_in   = (const float*)d_in[1];
    const float* b_in   = (const float*)d_in[2];
    const float* ln_g   = (const float*)d_in[3];
    const float* ln_b   = (const float*)d_in[4];
    const float* conv_w = (const float*)d_in[5];
    const float* conv_b = (const float*)d_in[6];
    const float* loglam = (const float*)d_in[7];
    const float* wd     = (const float*)d_in[8];
    const float* bd     = (const float*)d_in[9];
    const float* wb     = (const float*)d_in[10];
    const float* wc     = (const float*)d_in[11];
    const float* wo     = (const float*)d_in[12];
    const float* bo     = (const float*)d_in[13];
    const float* gw     = (const float*)d_in[14];
    const float* gb     = (const float*)d_in[15];
    const float* pw     = (const float*)d_in[16];
    const float* pb     = (const float*)d_in[17];
    const float* fr     = (const float*)d_in[18];
    const float* fi     = (const float*)d_in[19];
    const float* alpha  = (const float*)d_in[20];
    const float* beta   = (const float*)d_in[21];
    const float* gout   = (const float*)d_in[22];
    const float* bout   = (const float*)d_in[23];
    const float* hw1    = (const float*)d_in[24];
    const float* hb1    = (const float*)d_in[25];
    const float* hw2    = (const float*)d_in[26];
    const float* hb2    = (const float*)d_in[27];

    float* ws = (float*)d_ws;
    size_t o = 0;
    auto alloc = [&](size_t n) { float* p = ws + o; o += (n + 15) & ~(size_t)15; return p; };

    const size_t BLnDD = (size_t)BLn * DD;
    float* h      = alloc(BLnDD);
    float* xt1    = alloc(BLnDD);   // xt1+xn contiguous: split-K partials P0,P1
    float* xn     = alloc(BLnDD);
    float* ht     = alloc(BLnDD);
    float* delta  = alloc(BLnDD);
    float* Btm    = alloc((size_t)BLn * NN);
    float* Ctm    = alloc((size_t)BLn * NN);
    float* tab    = alloc(4096);
    float* ysf    = alloc(BLnDD * NN / 2);          // ys bf16; later Xre/Xim
    float* sA     = alloc((size_t)BB * 16 * 4096);
    float* sB     = alloc((size_t)BB * 16 * 4096);
    float* hst    = alloc((size_t)BB * 16 * 4096);
    float* xnbf_f = alloc(BLnDD / 2);
    float* xcbf_f = alloc(BLnDD / 2);
    float* xsgf   = alloc(BLnDD / 2);
    float* cat0_f = alloc((size_t)320 * 256 / 2);
    float* cat1_f = alloc((size_t)320 * 256 / 2);
    float* gwt_f  = alloc((size_t)DD * DD / 2);
    float* pwt_f  = alloc((size_t)DD * DD / 2);
    float* wot_f  = alloc((size_t)DD * NN * DD / 2);
    float* magp   = alloc(16 * 1280);
    int*   sel    = (int*)alloc(32);
    float* hfin   = alloc((size_t)BB * DD * NN);
    float* lpart  = alloc((size_t)BB * 32 * DD);
    float* outlast= alloc(BB * DD);
    float* xtlast = alloc(BB * DD);
    float* xslast = alloc(BB * DD);

    __hip_bfloat16* ys    = (__hip_bfloat16*)ysf;
    float*          Xre   = ysf;
    float*          Xim   = ysf + (size_t)1024 * FSTR;
    __hip_bfloat16* xn_bf = (__hip_bfloat16*)xnbf_f;
    __hip_bfloat16* xc_bf = (__hip_bfloat16*)xcbf_f;
    __hip_bfloat16* xsg_bf= (__hip_bfloat16*)xsgf;
    __hip_bfloat16* cat0  = (__hip_bfloat16*)cat0_f;
    __hip_bfloat16* cat1  = (__hip_bfloat16*)cat1_f;
    __hip_bfloat16* gwt   = (__hip_bfloat16*)gwt_f;
    __hip_bfloat16* pwt   = (__hip_bfloat16*)pwt_f;
    __hip_bfloat16* wot   = (__hip_bfloat16*)wot_f;
    float*          Pbuf  = xt1;

    const dim3 blk(256);

    twiddle_kernel<<<8, blk, 0, stream>>>(tab);
    tcast_kernel<<<dim3(8, 8),   blk, 0, stream>>>(wd,                   cat0, DD, DD);
    tcast_kernel<<<dim3(8, 8),   blk, 0, stream>>>(wd + (size_t)DD * DD, cat1, DD, DD);
    pack16_kernel<<<32, blk, 0, stream>>>(wb,            wc,            cat0);
    pack16_kernel<<<32, blk, 0, stream>>>(wb + DD * NN,  wc + DD * NN,  cat1);
    tcast_kernel<<<dim3(8, 8),   blk, 0, stream>>>(gw, gwt, DD, DD);
    tcast_kernel<<<dim3(8, 8),   blk, 0, stream>>>(pw, pwt, DD, DD);
    tcast_kernel<<<dim3(8, 128), blk, 0, stream>>>(wo, wot, DD * NN, DD);

    gemm64<<<dim3(DD / 64, BLn / 64), blk, 0, stream>>>(x, w_in, b_in, h, BLn, DD, INF_);
    htrans_kernel<<<dim3(64, 8, BB), blk, 0, stream>>>(h, ht);

    const dim3 qgrid(5, BLn / 64);
    const dim3 ggrid(4, BLn / 64);
    const dim3 sgrid(16, 16, BB);

    // ---- layer 0 (full sequence) ----
    ln_kernel<<<BLn, blk, 0, stream>>>(h, ln_g, ln_b, xn_bf);
    conv_kernel<<<(BLn * DD) / 256, blk, 0, stream>>>(xn_bf, conv_w, conv_b, xc_bf);
    gemm_core<0><<<qgrid, blk, 0, stream>>>((const short*)xc_bf, (const short*)cat0,
                                            bd, nullptr, nullptr, delta, Btm, Ctm, nullptr);
    ssm_chunk_kernel<0><<<sgrid, blk, 0, stream>>>(delta, Btm, nullptr, loglam,
                                                   nullptr, sA, sB, nullptr);
    ssm_comb_kernel<<<BB * 4096 / 256, blk, 0, stream>>>(sA, sB, hst, nullptr);
    ssm_chunk_kernel<1><<<sgrid, blk, 0, stream>>>(delta, Btm, Ctm, loglam,
                                                   hst, nullptr, nullptr, ys);
    gemm_sk_kernel<<<512, blk, 0, stream>>>(ys, wot, Pbuf);
    gemm_core<1><<<ggrid, blk, 0, stream>>>((const short*)xn_bf, (const short*)gwt,
                                            gb, Pbuf, bo, nullptr, nullptr, nullptr, xsg_bf);
    gemm_core<2><<<ggrid, blk, 0, stream>>>((const short*)xsg_bf, (const short*)pwt,
                                            pb, h, nullptr, xt1, nullptr, nullptr, nullptr);

    // ---- layer 1 (only final state needed downstream) ----
    ln_kernel<<<BLn, blk, 0, stream>>>(xt1, ln_g + DD, ln_b + DD, xn_bf);
    conv_kernel<<<(BLn * DD) / 256, blk, 0, stream>>>(xn_bf, conv_w + DD * 3, conv_b + DD, xc_bf);
    gemm_core<0><<<qgrid, blk, 0, stream>>>((const short*)xc_bf, (const short*)cat1,
                                            bd + DD, nullptr, nullptr, delta, Btm, Ctm, nullptr);
    ssm_chunk_kernel<0><<<sgrid, blk, 0, stream>>>(delta, Btm, nullptr, loglam + DD * NN,
                                                   nullptr, sA, sB, nullptr);
    ssm_comb_kernel<<<BB * 4096 / 256, blk, 0, stream>>>(sA, sB, hst, hfin);
    last_ssm_part_kernel<<<32, blk, 0, stream>>>(hfin, Ctm, wo + (size_t)DD * NN * DD, lpart);
    last_ssm_red_kernel<<<BB, blk, 0, stream>>>(lpart, bo + DD, outlast);
    last_proj_kernel<<<BB, blk, 0, stream>>>(xn_bf, outlast, gw + (size_t)DD * DD, gb + DD,
                                             pw + (size_t)DD * DD, pb + DD, xt1, xtlast);

    // ---- spectral path ----
    fft2_kernel<<<512, blk, 0, stream>>>(ht, tab, Xre, Xim);
    mag_part_kernel<<<dim3(5, 16), blk, 0, stream>>>(Xre, Xim, magp);
    topk_kernel<<<1, blk, 0, stream>>>(magp, sel);
    xslast_kernel<<<BB, blk, 0, stream>>>(Xre, Xim, sel, fr, fi, tab, xslast);

    head_kernel<<<BB, blk, 0, stream>>>(xtlast, xslast, alpha, beta, gout, bout,
                                        hw1, hb1, hw2, hb2, (float*)d_out);
}

// Round 9
// 278.907 us; speedup vs baseline: 8.4110x; 1.1313x over previous
//
#include <hip/hip_runtime.h>
#include <hip/hip_bf16.h>
#include <math.h>

#define BB   4
#define LL   2048
#define INF_ 64
#define DD   256
#define NN   16
#define KK   32
#define BLn  (BB*LL)      // 8192
#define FCNT 1025
#define FSTR 1056
#define SKM  8192
#define SKN  256
#define PSZ  ((size_t)SKM * SKN)
#define IX(x) ((x) + ((x) >> 6))

typedef short short4v __attribute__((ext_vector_type(4)));
typedef short short8 __attribute__((ext_vector_type(8)));
typedef float f32x4  __attribute__((ext_vector_type(4)));

__device__ __forceinline__ float softplusf(float x) {
    return x > 20.f ? x : log1pf(__expf(x));
}
__device__ __forceinline__ float sigmoidf_(float x) {
    return 1.f / (1.f + __expf(-x));
}
__device__ __forceinline__ short bfs(float v) {
    __hip_bfloat16 h = __float2bfloat16(v);
    return *reinterpret_cast<short*>(&h);
}

// ============ fused prep: twiddle + all weight transpose/cast/pack ==========
// blocks: 0..7 twiddle | 8..71 wd0 | 72..135 wd1 | 136..199 gw | 200..263 pw
//         264..1287 wo | 1288..1351 pack | 1352..1367 w_in
__global__ void prep_kernel(const float* __restrict__ wd, const float* __restrict__ gw,
                            const float* __restrict__ pw, const float* __restrict__ wo,
                            const float* __restrict__ wb, const float* __restrict__ wc,
                            const float* __restrict__ w_in, float* __restrict__ tab,
                            __hip_bfloat16* __restrict__ cat0, __hip_bfloat16* __restrict__ cat1,
                            __hip_bfloat16* __restrict__ gwt, __hip_bfloat16* __restrict__ pwt,
                            __hip_bfloat16* __restrict__ wot, __hip_bfloat16* __restrict__ wint) {
    __shared__ float t[32][33];
    const int tid = threadIdx.x;
    int blk = blockIdx.x;
    if (blk < 8) {
        int i = blk * 256 + tid;
        if (i < 2048) {
            double ang = 2.0 * 3.14159265358979323846 * (double)i / 2048.0;
            tab[i]        = (float)cos(ang);
            tab[2048 + i] = (float)sin(ang);
        }
        return;
    }
    blk -= 8;
    const float* W; __hip_bfloat16* Wt; int K, N, bx, by;
    if (blk < 64)        { W = wd;                     Wt = cat0; K = 256;  N = 256; bx = blk & 7; by = blk >> 3; }
    else if (blk < 128)  { int q = blk - 64;  W = wd + 65536; Wt = cat1; K = 256; N = 256; bx = q & 7; by = q >> 3; }
    else if (blk < 192)  { int q = blk - 128; W = gw;  Wt = gwt;  K = 256;  N = 256; bx = q & 7; by = q >> 3; }
    else if (blk < 256)  { int q = blk - 192; W = pw;  Wt = pwt;  K = 256;  N = 256; bx = q & 7; by = q >> 3; }
    else if (blk < 1280) { int q = blk - 256; W = wo;  Wt = wot;  K = 4096; N = 256; bx = q & 7; by = q >> 3; }
    else if (blk < 1344) {
        int j = (blk - 1280) & 31;
        const float* src0 = (blk < 1312) ? wb : wb + DD * NN;
        const float* src1 = (blk < 1312) ? wc : wc + DD * NN;
        __hip_bfloat16* cat = (blk < 1312) ? cat0 : cat1;
        const float* src = (j < 16) ? src0 : src1;
        cat[(size_t)(256 + j) * 256 + tid] = __float2bfloat16(src[tid * 16 + (j & 15)]);
        return;
    } else { int q = blk - 1344; W = w_in; Wt = wint; K = 64; N = 256; bx = q & 7; by = q >> 3; }
    const int k0 = by * 32, n0 = bx * 32;
    if (k0 >= K) return;
    const int tx = tid & 31, ty = tid >> 5;
    for (int r = ty; r < 32; r += 8) t[r][tx] = W[(size_t)(k0 + r) * N + n0 + tx];
    __syncthreads();
    for (int r = ty; r < 32; r += 8)
        Wt[(size_t)(n0 + r) * K + k0 + tx] = __float2bfloat16(t[tx][r]);
}

// ============ input proj: h = x@w_in + b_in (MFMA), also writes ht ==========
__global__ __launch_bounds__(256)
void gemm_in_kernel(const float* __restrict__ x, const __hip_bfloat16* __restrict__ wint,
                    const float* __restrict__ b_in, float* __restrict__ h,
                    float* __restrict__ ht) {
    __shared__ alignas(16) short As[64][72];
    __shared__ alignas(16) short Bs[64][72];
    __shared__ float ts[64][68];
    const int tid = threadIdx.x;
    const int w = tid >> 6, lane = tid & 63;
    const int hi = lane >> 4, lo = lane & 15;
    const int row0 = blockIdx.y * 64, col0 = blockIdx.x * 64;
    const short* B = (const short*)wint;
#pragma unroll
    for (int e = 0; e < 4; ++e) {
        int q = e * 256 + tid;
        int r = q >> 4, c4 = (q & 15) * 4;
        float4 v = *(const float4*)&x[(size_t)(row0 + r) * 64 + c4];
        short4v s = {bfs(v.x), bfs(v.y), bfs(v.z), bfs(v.w)};
        *(short4v*)&As[r][c4] = s;
    }
#pragma unroll
    for (int e = 0; e < 2; ++e) {
        int q = e * 256 + tid;
        int r = q >> 3, c8 = (q & 7) * 8;
        *(short8*)&Bs[r][c8] = *(const short8*)&B[(size_t)(col0 + r) * 64 + c8];
    }
    __syncthreads();
    f32x4 acc[4];
    f32x4 zz = {0.f, 0.f, 0.f, 0.f};
#pragma unroll
    for (int n = 0; n < 4; ++n) acc[n] = zz;
#pragma unroll
    for (int s = 0; s < 2; ++s) {
        short8 af = *(const short8*)&As[w * 16 + lo][s * 32 + hi * 8];
#pragma unroll
        for (int n = 0; n < 4; ++n) {
            short8 bf = *(const short8*)&Bs[n * 16 + lo][s * 32 + hi * 8];
            acc[n] = __builtin_amdgcn_mfma_f32_16x16x32_bf16(af, bf, acc[n], 0, 0, 0);
        }
    }
#pragma unroll
    for (int n = 0; n < 4; ++n)
#pragma unroll
        for (int r = 0; r < 4; ++r) {
            const int row = row0 + w * 16 + hi * 4 + r;
            const int col = col0 + n * 16 + lo;
            float v = acc[n][r] + b_in[col];
            h[(size_t)row * 256 + col] = v;
            ts[n * 16 + lo][w * 16 + hi * 4 + r] = v;
        }
    __syncthreads();
    const int b = row0 >> 11, l0 = row0 & 2047, d0 = col0;
    const int dr = tid >> 2, seg = tid & 3;
    float* dst = ht + ((size_t)(b * 256 + d0 + dr)) * LL + l0 + seg * 16;
#pragma unroll
    for (int j = 0; j < 4; ++j)
        *(f32x4*)&dst[j * 4] = *(const f32x4*)&ts[dr][seg * 16 + j * 4];
}

// ============ fused LayerNorm + depthwise conv (32 rows/block) ==============
__global__ __launch_bounds__(256)
void lnconv_kernel(const float* __restrict__ X, const float* __restrict__ g,
                   const float* __restrict__ bln, const float* __restrict__ cw,
                   const float* __restrict__ cb, __hip_bfloat16* __restrict__ xn_bf,
                   __hip_bfloat16* __restrict__ xc_bf) {
    __shared__ float xs[34][260];
    const int tid = threadIdx.x;
    const int w = tid >> 6, lane = tid & 63;
    const int blk = blockIdx.x;
    const int b = (blk * 32) >> 11, L0 = (blk * 32) & 2047;
    const float4 g4 = *(const float4*)&g[lane * 4];
    const float4 b4 = *(const float4*)&bln[lane * 4];
    for (int slot = w; slot < 34; slot += 4) {
        const int l = L0 - 1 + slot;
        if (l < 0 || l >= LL) {
            f32x4 z = {0.f, 0.f, 0.f, 0.f};
            *(f32x4*)&xs[slot][lane * 4] = z;
            continue;
        }
        float4 v = *(const float4*)&X[((size_t)b * LL + l) * DD + lane * 4];
        float s = v.x + v.y + v.z + v.w;
#pragma unroll
        for (int off = 1; off < 64; off <<= 1) s += __shfl_xor(s, off);
        float m = s * (1.f / DD);
        float cx = v.x - m, cy = v.y - m, cz = v.z - m, cw_ = v.w - m;
        float q = cx * cx + cy * cy + cz * cz + cw_ * cw_;
#pragma unroll
        for (int off = 1; off < 64; off <<= 1) q += __shfl_xor(q, off);
        float inv = rsqrtf(q * (1.f / DD) + 1e-5f);
        f32x4 y;
        y[0] = cx * inv * g4.x + b4.x;
        y[1] = cy * inv * g4.y + b4.y;
        y[2] = cz * inv * g4.z + b4.z;
        y[3] = cw_ * inv * g4.w + b4.w;
        *(f32x4*)&xs[slot][lane * 4] = y;
        if (slot >= 1 && slot <= 32) {
            short4v s4 = {bfs(y[0]), bfs(y[1]), bfs(y[2]), bfs(y[3])};
            *(short4v*)&xn_bf[((size_t)b * LL + l) * DD + lane * 4] = s4;
        }
    }
    __syncthreads();
    const int d = tid;
    const float w0 = cw[d * 3 + 0], w1 = cw[d * 3 + 1], w2 = cw[d * 3 + 2], cbd = cb[d];
    float xm = xs[0][d], x0 = xs[1][d];
    for (int rw = 0; rw < 32; ++rw) {
        float xp = xs[rw + 2][d];
        xc_bf[((size_t)b * LL + L0 + rw) * DD + d] =
            __float2bfloat16(fmaf(w0, xm, fmaf(w1, x0, fmaf(w2, xp, cbd))));
        xm = x0; x0 = xp;
    }
}

// ============ 64x64 MFMA core, LDS dbuf, K=256 (3 fused epilogues) ==========
template<int MODE>
__global__ __launch_bounds__(256)
void gemm_core(const short* __restrict__ A, const short* __restrict__ Bw,
               const float* __restrict__ bias, const float* __restrict__ x1,
               const float* __restrict__ x2, float* __restrict__ o0,
               float* __restrict__ o1, float* __restrict__ o2,
               __hip_bfloat16* __restrict__ ob) {
    __shared__ alignas(16) short As[2][64][40];
    __shared__ alignas(16) short Bs[2][64][40];
    const int tid = threadIdx.x;
    const int w = tid >> 6, lane = tid & 63;
    const int hi = lane >> 4, lo = lane & 15;
    const int row0 = blockIdx.y * 64, col0 = blockIdx.x * 64;
    f32x4 acc[4];
    f32x4 zz = {0.f, 0.f, 0.f, 0.f};
#pragma unroll
    for (int n = 0; n < 4; ++n) acc[n] = zz;
    const int sr = tid >> 2, sc = (tid & 3) * 8;
    short8 pa = *(const short8*)&A[(size_t)(row0 + sr) * 256 + sc];
    short8 pb = *(const short8*)&Bw[(size_t)(col0 + sr) * 256 + sc];
    *(short8*)&As[0][sr][sc] = pa;
    *(short8*)&Bs[0][sr][sc] = pb;
    pa = *(const short8*)&A[(size_t)(row0 + sr) * 256 + 32 + sc];
    pb = *(const short8*)&Bw[(size_t)(col0 + sr) * 256 + 32 + sc];
    __syncthreads();
    int cur = 0;
    for (int it = 0; it < 8; ++it) {
        if (it + 1 < 8) {
            *(short8*)&As[cur ^ 1][sr][sc] = pa;
            *(short8*)&Bs[cur ^ 1][sr][sc] = pb;
        }
        if (it + 2 < 8) {
            const int k0 = (it + 2) << 5;
            pa = *(const short8*)&A[(size_t)(row0 + sr) * 256 + k0 + sc];
            pb = *(const short8*)&Bw[(size_t)(col0 + sr) * 256 + k0 + sc];
        }
        short8 af = *(const short8*)&As[cur][w * 16 + lo][hi * 8];
        short8 bfr[4];
#pragma unroll
        for (int n = 0; n < 4; ++n)
            bfr[n] = *(const short8*)&Bs[cur][n * 16 + lo][hi * 8];
#pragma unroll
        for (int n = 0; n < 4; ++n)
            acc[n] = __builtin_amdgcn_mfma_f32_16x16x32_bf16(af, bfr[n], acc[n], 0, 0, 0);
        __syncthreads();
        cur ^= 1;
    }
#pragma unroll
    for (int n = 0; n < 4; ++n) {
#pragma unroll
        for (int r = 0; r < 4; ++r) {
            const int row = row0 + w * 16 + hi * 4 + r;
            const int col = col0 + n * 16 + lo;
            float v = acc[n][r];
            if constexpr (MODE == 0) {
                if (col < 256)      o0[(size_t)row * 256 + col] = softplusf(v + bias[col]);
                else if (col < 272) o1[(size_t)row * 16 + col - 256] = v;
                else if (col < 288) o2[(size_t)row * 16 + col - 272] = v;
            } else if constexpr (MODE == 1) {
                float gv = sigmoidf_(v + bias[col]);
                float s = x1[(size_t)row * 256 + col] + x1[PSZ + (size_t)row * 256 + col] + x2[col];
                ob[(size_t)row * 256 + col] = __float2bfloat16(gv * s);
            } else {
                o0[(size_t)row * 256 + col] = v + bias[col] + x1[(size_t)row * 256 + col];
            }
        }
    }
}

// ============ split-K GEMM ys@wo, 128x64 tile, BK=64, LDS dbuf ==============
__global__ __launch_bounds__(256)
void gemm_sk_kernel(const __hip_bfloat16* __restrict__ Abf, const __hip_bfloat16* __restrict__ Wt,
                    float* __restrict__ P) {
    __shared__ alignas(16) short As[2][128][72];
    __shared__ alignas(16) short Bs[2][64][72];
    const int tid = threadIdx.x;
    const int f = blockIdx.x;                   // 0..511
    const int xcd = f & 7, slot = f >> 3;
    const int col = slot & 3;
    const int rk = xcd + (slot >> 2) * 8;       // 0..127
    const int row = rk & 63, kb = rk >> 6;
    const int row0 = row * 128, col0 = col * 64;
    const size_t kbase = (size_t)kb * 2048;
    const int w = tid >> 6, lane = tid & 63;
    const int hi = lane >> 4, lo = lane & 15;
    const short* A = (const short*)Abf;
    const short* B = (const short*)Wt;
    f32x4 acc[2][4];
    f32x4 zz = {0.f, 0.f, 0.f, 0.f};
#pragma unroll
    for (int m = 0; m < 2; ++m)
#pragma unroll
        for (int n = 0; n < 4; ++n) acc[m][n] = zz;
    const int sr = tid >> 3, sc = (tid & 7) * 8;
    const int sr1 = (256 + tid) >> 3, sc1 = ((256 + tid) & 7) * 8;
    const int sr2 = (512 + tid) >> 3, sc2 = ((512 + tid) & 7) * 8;
    const int sr3 = (768 + tid) >> 3, sc3 = ((768 + tid) & 7) * 8;
    short8 pa0 = *(const short8*)&A[(size_t)(row0 + sr ) * 4096 + kbase + sc ];
    short8 pa1 = *(const short8*)&A[(size_t)(row0 + sr1) * 4096 + kbase + sc1];
    short8 pa2 = *(const short8*)&A[(size_t)(row0 + sr2) * 4096 + kbase + sc2];
    short8 pa3 = *(const short8*)&A[(size_t)(row0 + sr3) * 4096 + kbase + sc3];
    short8 pb0 = *(const short8*)&B[(size_t)(col0 + sr ) * 4096 + kbase + sc ];
    short8 pb1 = *(const short8*)&B[(size_t)(col0 + sr1) * 4096 + kbase + sc1];
    *(short8*)&As[0][sr ][sc ] = pa0;
    *(short8*)&As[0][sr1][sc1] = pa1;
    *(short8*)&As[0][sr2][sc2] = pa2;
    *(short8*)&As[0][sr3][sc3] = pa3;
    *(short8*)&Bs[0][sr ][sc ] = pb0;
    *(short8*)&Bs[0][sr1][sc1] = pb1;
    {
        const size_t k0 = kbase + 64;
        pa0 = *(const short8*)&A[(size_t)(row0 + sr ) * 4096 + k0 + sc ];
        pa1 = *(const short8*)&A[(size_t)(row0 + sr1) * 4096 + k0 + sc1];
        pa2 = *(const short8*)&A[(size_t)(row0 + sr2) * 4096 + k0 + sc2];
        pa3 = *(const short8*)&A[(size_t)(row0 + sr3) * 4096 + k0 + sc3];
        pb0 = *(const short8*)&B[(size_t)(col0 + sr ) * 4096 + k0 + sc ];
        pb1 = *(const short8*)&B[(size_t)(col0 + sr1) * 4096 + k0 + sc1];
    }
    __syncthreads();
    int cur = 0;
    for (int it = 0; it < 32; ++it) {
        if (it + 1 < 32) {
            *(short8*)&As[cur ^ 1][sr ][sc ] = pa0;
            *(short8*)&As[cur ^ 1][sr1][sc1] = pa1;
            *(short8*)&As[cur ^ 1][sr2][sc2] = pa2;
            *(short8*)&As[cur ^ 1][sr3][sc3] = pa3;
            *(short8*)&Bs[cur ^ 1][sr ][sc ] = pb0;
            *(short8*)&Bs[cur ^ 1][sr1][sc1] = pb1;
        }
        if (it + 2 < 32) {
            const size_t k0 = kbase + (size_t)(it + 2) * 64;
            pa0 = *(const short8*)&A[(size_t)(row0 + sr ) * 4096 + k0 + sc ];
            pa1 = *(const short8*)&A[(size_t)(row0 + sr1) * 4096 + k0 + sc1];
            pa2 = *(const short8*)&A[(size_t)(row0 + sr2) * 4096 + k0 + sc2];
            pa3 = *(const short8*)&A[(size_t)(row0 + sr3) * 4096 + k0 + sc3];
            pb0 = *(const short8*)&B[(size_t)(col0 + sr ) * 4096 + k0 + sc ];
            pb1 = *(const short8*)&B[(size_t)(col0 + sr1) * 4096 + k0 + sc1];
        }
#pragma unroll
        for (int kk = 0; kk < 2; ++kk) {
            short8 af[2], bfr[4];
#pragma unroll
            for (int m = 0; m < 2; ++m)
                af[m] = *(const short8*)&As[cur][w * 32 + m * 16 + lo][kk * 32 + hi * 8];
#pragma unroll
            for (int n = 0; n < 4; ++n)
                bfr[n] = *(const short8*)&Bs[cur][n * 16 + lo][kk * 32 + hi * 8];
#pragma unroll
            for (int m = 0; m < 2; ++m)
#pragma unroll
                for (int n = 0; n < 4; ++n)
                    acc[m][n] = __builtin_amdgcn_mfma_f32_16x16x32_bf16(af[m], bfr[n], acc[m][n], 0, 0, 0);
        }
        __syncthreads();
        cur ^= 1;
    }
    float* Pk = P + (size_t)kb * PSZ;
#pragma unroll
    for (int m = 0; m < 2; ++m)
#pragma unroll
        for (int n = 0; n < 4; ++n)
#pragma unroll
            for (int r = 0; r < 4; ++r) {
                int rr = row0 + w * 32 + m * 16 + hi * 4 + r;
                int cc = col0 + n * 16 + lo;
                Pk[(size_t)rr * SKN + cc] = acc[m][n][r];
            }
}

// ============ chunked SSM scan ==============================================
template<int PHASE>
__global__ void ssm_chunk_kernel(const float* __restrict__ delta, const float* __restrict__ Bt,
                                 const float* __restrict__ Ct, const float* __restrict__ loglam,
                                 const float* __restrict__ hstart,
                                 float* __restrict__ sA, float* __restrict__ sB,
                                 __hip_bfloat16* __restrict__ ys) {
    __shared__ float dl[128][16];
    __shared__ float btl[128][16];
    __shared__ float ctl[128][16];
    const int dblk = blockIdx.x, c = blockIdx.y, b = blockIdx.z;
    const int tid = threadIdx.x;
    const size_t lbase = (size_t)b * LL + c * 128;
    for (int i = tid; i < 2048; i += 256) {
        int l = i >> 4, q = i & 15;
        dl[l][q]  = delta[(lbase + l) * DD + dblk * 16 + q];
        btl[l][q] = Bt[(lbase + l) * NN + q];
        if (PHASE == 1) ctl[l][q] = Ct[(lbase + l) * NN + q];
    }
    __syncthreads();
    const int dloc = tid >> 4, n = tid & 15;
    const float lam = softplusf(loglam[(dblk * 16 + dloc) * NN + n]);
    float hv = 0.f, ap = 1.f;
    if (PHASE == 1) hv = hstart[((size_t)(b * 16 + c)) * 4096 + dblk * 256 + tid];
    for (int l = 0; l < 128; ++l) {
        float dv = dl[l][dloc];
        float a = __expf(-dv * lam);
        hv = fmaf(a, hv, dv * btl[l][n]);
        if (PHASE == 0) ap *= a;
        else ys[(lbase + l) * (DD * NN) + dblk * 256 + tid] = __float2bfloat16(hv * ctl[l][n]);
    }
    if (PHASE == 0) {
        size_t oi = ((size_t)(b * 16 + c)) * 4096 + dblk * 256 + tid;
        sA[oi] = ap; sB[oi] = hv;
    }
}

__global__ void ssm_comb_kernel(const float* __restrict__ sA, const float* __restrict__ sB,
                                float* __restrict__ hstart, float* __restrict__ hfin) {
    const int id = blockIdx.x * 256 + threadIdx.x;
    const int b = id >> 12, col = id & 4095;
    float h = 0.f;
#pragma unroll
    for (int c = 0; c < 16; ++c) {
        size_t oi = ((size_t)(b * 16 + c)) * 4096 + col;
        hstart[oi] = h;
        h = fmaf(sA[oi], h, sB[oi]);
    }
    if (hfin) hfin[(size_t)b * 4096 + col] = h;
}

// ============ layer-2 last-position: split-K part + fused red/gate/proj ====
__global__ void last_ssm_part_kernel(const float* __restrict__ hfin, const float* __restrict__ Ct,
                                     const float* __restrict__ wo, float* __restrict__ part) {
    __shared__ float hC[4][128];
    const int c = blockIdx.x, tid = threadIdx.x;
    const int p0 = c * 128;
#pragma unroll
    for (int e = 0; e < 2; ++e) {
        int i = e * 256 + tid;
        int b = i >> 7, p = i & 127;
        hC[b][p] = hfin[b * 4096 + p0 + p] *
                   Ct[((size_t)b * LL + (LL - 1)) * NN + (p & 15)];
    }
    __syncthreads();
    float a0 = 0.f, a1 = 0.f, a2 = 0.f, a3 = 0.f;
    for (int p = 0; p < 128; ++p) {
        float wv = wo[(size_t)(p0 + p) * DD + tid];
        a0 = fmaf(hC[0][p], wv, a0);
        a1 = fmaf(hC[1][p], wv, a1);
        a2 = fmaf(hC[2][p], wv, a2);
        a3 = fmaf(hC[3][p], wv, a3);
    }
    part[(0 * 32 + c) * DD + tid] = a0;
    part[(1 * 32 + c) * DD + tid] = a1;
    part[(2 * 32 + c) * DD + tid] = a2;
    part[(3 * 32 + c) * DD + tid] = a3;
}

__global__ void last_redproj_kernel(const float* __restrict__ part, const float* __restrict__ bo,
                                    const __hip_bfloat16* __restrict__ xn, const float* __restrict__ gw,
                                    const float* __restrict__ gb, const float* __restrict__ pw,
                                    const float* __restrict__ pb, const float* __restrict__ resid,
                                    float* __restrict__ xtlast) {
    __shared__ float xrow[256];
    __shared__ float xsg[256];
    const int b = blockIdx.x, d = threadIdx.x;
    float ol = bo[d];
#pragma unroll
    for (int c = 0; c < 32; ++c) ol += part[(b * 32 + c) * DD + d];
    const size_t rbase = ((size_t)b * LL + (LL - 1)) * DD;
    xrow[d] = __bfloat162float(xn[rbase + d]);
    __syncthreads();
    float acc = gb[d];
    for (int k = 0; k < 256; ++k) acc = fmaf(xrow[k], gw[(size_t)k * DD + d], acc);
    xsg[d] = ol * sigmoidf_(acc);
    __syncthreads();
    float acc2 = pb[d];
    for (int k = 0; k < 256; ++k) acc2 = fmaf(xsg[k], pw[(size_t)k * DD + d], acc2);
    xtlast[b * DD + d] = acc2 + resid[rbase + d];
}

// ============ packed radix-2 FFT: 2 real seqs per block =====================
__global__ __launch_bounds__(256)
void fft2_kernel(const float* __restrict__ ht, const float* __restrict__ tab,
                 float* __restrict__ Xre, float* __restrict__ Xim) {
    __shared__ float re[2080];
    __shared__ float im[2080];
    __shared__ float c2[2048];
    __shared__ float s2[2048];
    const int tid = threadIdx.x;
    const int pair = blockIdx.x;
    const int b = pair >> 7, d0 = pair & 127;
    for (int p = tid; p < 2048; p += 256) {
        if (p >= 1) {
            int lh = 31 - __clz((unsigned)p);
            int j = p - (1 << lh);
            int t = j << (10 - lh);
            c2[p] = tab[t]; s2[p] = tab[2048 + t];
        }
    }
    const float* ha = ht + ((size_t)b * 256 + d0) * LL;
    const float* hb = ha + (size_t)128 * LL;
    for (int i = tid; i < 2048; i += 256) {
        int r = (int)(__brev((unsigned)i) >> 21);
        re[IX(r)] = ha[i];
        im[IX(r)] = hb[i];
    }
    __syncthreads();
#pragma unroll
    for (int s = 1; s <= 11; ++s) {
        const int half = 1 << (s - 1);
#pragma unroll
        for (int e = 0; e < 4; ++e) {
            int q = e * 256 + tid;
            int j = q & (half - 1);
            int i0 = ((q >> (s - 1)) << s) + j;
            int i1 = i0 + half;
            float wr = c2[half + j], wi = -s2[half + j];
            float xr = re[IX(i1)], xi = im[IX(i1)];
            float tr = xr * wr - xi * wi;
            float ti = xr * wi + xi * wr;
            float ur = re[IX(i0)], ui = im[IX(i0)];
            re[IX(i0)] = ur + tr; im[IX(i0)] = ui + ti;
            re[IX(i1)] = ur - tr; im[IX(i1)] = ui - ti;
        }
        __syncthreads();
    }
    const int seqa = b * 256 + d0;
    float* xra = Xre + (size_t)seqa * FSTR;
    float* xia = Xim + (size_t)seqa * FSTR;
    float* xrb = xra + (size_t)128 * FSTR;
    float* xib = xia + (size_t)128 * FSTR;
    for (int f = tid; f < FCNT; f += 256) {
        int nf = (2048 - f) & 2047;
        float zrf = re[IX(f)], zif = im[IX(f)];
        float zrn = re[IX(nf)], zin = im[IX(nf)];
        xra[f] = 0.5f * (zrf + zrn);
        xia[f] = 0.5f * (zif - zin);
        xrb[f] = 0.5f * (zif + zin);
        xib[f] = 0.5f * (zrn - zrf);
    }
}

// ============ mag partials / topk / xslast / head ===========================
__global__ void mag_part_kernel(const float* __restrict__ Xre, const float* __restrict__ Xim,
                                float* __restrict__ part) {
    const int fb = blockIdx.x, sb = blockIdx.y;
    const int tid = threadIdx.x;
    const int f = fb * 256 + tid;
    float s = 0.f;
    if (f < FCNT) {
        for (int q = 0; q < 64; ++q) {
            size_t base = (size_t)(sb * 64 + q) * FSTR + f;
            float re = Xre[base], im = Xim[base];
            s += sqrtf(re * re + im * im);
        }
    }
    part[sb * 1280 + fb * 256 + tid] = s;
}

__global__ void topk_kernel(const float* __restrict__ part, int* __restrict__ sel) {
    __shared__ float vals[1280];
    __shared__ float wv[4];
    __shared__ int wi[4];
    const int tid = threadIdx.x;
    const int lane = tid & 63, wid = tid >> 6;
    for (int i = tid; i < 1280; i += 256) {
        float v = -1e30f;
        if (i < FCNT) {
            v = 0.f;
#pragma unroll
            for (int sb = 0; sb < 16; ++sb) v += part[sb * 1280 + i];
        }
        vals[i] = v;
    }
    __syncthreads();
    for (int k = 0; k < 32; ++k) {
        float bv = -1e30f; int bi = 0x7fffffff;
        for (int i = tid; i < FCNT; i += 256) {
            float v = vals[i];
            if (v > bv) { bv = v; bi = i; }
        }
#pragma unroll
        for (int off = 32; off > 0; off >>= 1) {
            float ov = __shfl_down(bv, off);
            int   oi = __shfl_down(bi, off);
            if (ov > bv || (ov == bv && oi < bi)) { bv = ov; bi = oi; }
        }
        if (lane == 0) { wv[wid] = bv; wi[wid] = bi; }
        __syncthreads();
        if (tid == 0) {
            float fv = wv[0]; int fi = wi[0];
#pragma unroll
            for (int q = 1; q < 4; ++q)
                if (wv[q] > fv || (wv[q] == fv && wi[q] < fi)) { fv = wv[q]; fi = wi[q]; }
            sel[k] = fi;
            vals[fi] = -1e30f;
        }
        __syncthreads();
    }
}

__global__ void xslast_kernel(const float* __restrict__ Xre, const float* __restrict__ Xim,
                              const int* __restrict__ sel, const float* __restrict__ fr,
                              const float* __restrict__ fi, const float* __restrict__ tab,
                              float* __restrict__ xsl) {
    const int b = blockIdx.x, d = threadIdx.x;
    const size_t sbase = (size_t)(b * 256 + d) * FSTR;
    float acc = 0.f;
    for (int j = 0; j < 32; ++j) {
        int f = sel[j];
        float xr = Xre[sbase + f];
        float xi = Xim[sbase + f];
        float frv = fr[d * KK + j], fiv = fi[d * KK + j];
        float xor_ = xr * frv - xi * fiv;
        float xoi  = xr * fiv + xi * frv;
        int kk2 = (f * (LL - 1)) & (LL - 1);
        float c = tab[kk2], s = tab[2048 + kk2];
        float w = (f == 0 || f == 1024) ? 1.f : 2.f;
        acc = fmaf(w, xor_ * c - xoi * s, acc);
    }
    xsl[b * DD + d] = acc * (1.f / LL);
}

__global__ void head_kernel(const float* __restrict__ xtlast, const float* __restrict__ xslast,
                            const float* __restrict__ alpha, const float* __restrict__ beta,
                            const float* __restrict__ gout, const float* __restrict__ bout,
                            const float* __restrict__ hw1, const float* __restrict__ hb1,
                            const float* __restrict__ hw2, const float* __restrict__ hb2,
                            float* __restrict__ out) {
    __shared__ float red[256];
    __shared__ float z[256];
    __shared__ float hid[128];
    const int b = blockIdx.x, tid = threadIdx.x;
    float zv = alpha[tid] * xtlast[b * 256 + tid] + beta[tid] * xslast[b * 256 + tid];
    red[tid] = zv; __syncthreads();
    for (int s = 128; s > 0; s >>= 1) { if (tid < s) red[tid] += red[tid + s]; __syncthreads(); }
    float m = red[0] * (1.f / DD);
    __syncthreads();
    float c = zv - m;
    red[tid] = c * c; __syncthreads();
    for (int s = 128; s > 0; s >>= 1) { if (tid < s) red[tid] += red[tid + s]; __syncthreads(); }
    float var = red[0] * (1.f / DD);
    z[tid] = c * rsqrtf(var + 1e-5f) * gout[tid] + bout[tid];
    __syncthreads();
    if (tid < 128) {
        float a = hb1[tid];
        for (int k = 0; k < 256; ++k) a = fmaf(z[k], hw1[(size_t)k * 128 + tid], a);
        hid[tid] = a * sigmoidf_(a);
    }
    __syncthreads();
    if (tid < 2) {
        float a = hb2[tid];
        for (int k = 0; k < 128; ++k) a = fmaf(hid[k], hw2[(size_t)k * 2 + tid], a);
        out[b * 2 + tid] = a;
    }
}

extern "C" void kernel_launch(void* const* d_in, const int* in_sizes, int n_in,
                              void* d_out, int out_size, void* d_ws, size_t ws_size,
                              hipStream_t stream) {
    const float* x      = (const float*)d_in[0];
    const float* w_in   = (const float*)d_in[1];
    const float* b_in   = (const float*)d_in[2];
    const float* ln_g   = (const float*)d_in[3];
    const float* ln_b   = (const float*)d_in[4];
    const float* conv_w = (const float*)d_in[5];
    const float* conv_b = (const float*)d_in[6];
    const float* loglam = (const float*)d_in[7];
    const float* wd     = (const float*)d_in[8];
    const float* bd     = (const float*)d_in[9];
    const float* wb     = (const float*)d_in[10];
    const float* wc     = (const float*)d_in[11];
    const float* wo     = (const float*)d_in[12];
    const float* bo     = (const float*)d_in[13];
    const float* gw     = (const float*)d_in[14];
    const float* gb     = (const float*)d_in[15];
    const float* pw     = (const float*)d_in[16];
    const float* pb     = (const float*)d_in[17];
    const float* fr     = (const float*)d_in[18];
    const float* fi     = (const float*)d_in[19];
    const float* alpha  = (const float*)d_in[20];
    const float* beta   = (const float*)d_in[21];
    const float* gout   = (const float*)d_in[22];
    const float* bout   = (const float*)d_in[23];
    const float* hw1    = (const float*)d_in[24];
    const float* hb1    = (const float*)d_in[25];
    const float* hw2    = (const float*)d_in[26];
    const float* hb2    = (const float*)d_in[27];

    float* ws = (float*)d_ws;
    size_t o = 0;
    auto alloc = [&](size_t n) { float* p = ws + o; o += (n + 15) & ~(size_t)15; return p; };

    const size_t BLnDD = (size_t)BLn * DD;
    float* h      = alloc(BLnDD);
    float* xt1    = alloc(BLnDD);   // xt1+xpad contiguous: split-K partials P0,P1
    float* xpad   = alloc(BLnDD);
    float* ht     = alloc(BLnDD);
    float* delta  = alloc(BLnDD);
    float* Btm    = alloc((size_t)BLn * NN);
    float* Ctm    = alloc((size_t)BLn * NN);
    float* tab    = alloc(4096);
    float* ysf    = alloc(BLnDD * NN / 2);          // ys bf16; later Xre/Xim
    float* sA     = alloc((size_t)BB * 16 * 4096);
    float* sB     = alloc((size_t)BB * 16 * 4096);
    float* hst    = alloc((size_t)BB * 16 * 4096);
    float* xnbf_f = alloc(BLnDD / 2);
    float* xcbf_f = alloc(BLnDD / 2);
    float* xsgf   = alloc(BLnDD / 2);
    float* cat0_f = alloc((size_t)320 * 256 / 2);
    float* cat1_f = alloc((size_t)320 * 256 / 2);
    float* gwt_f  = alloc((size_t)DD * DD / 2);
    float* pwt_f  = alloc((size_t)DD * DD / 2);
    float* wot_f  = alloc((size_t)DD * NN * DD / 2);
    float* wint_f = alloc((size_t)DD * 64 / 2);
    float* magp   = alloc(16 * 1280);
    int*   sel    = (int*)alloc(32);
    float* hfin   = alloc((size_t)BB * DD * NN);
    float* lpart  = alloc((size_t)BB * 32 * DD);
    float* xtlast = alloc(BB * DD);
    float* xslast = alloc(BB * DD);

    __hip_bfloat16* ys    = (__hip_bfloat16*)ysf;
    float*          Xre   = ysf;
    float*          Xim   = ysf + (size_t)1024 * FSTR;
    __hip_bfloat16* xn_bf = (__hip_bfloat16*)xnbf_f;
    __hip_bfloat16* xc_bf = (__hip_bfloat16*)xcbf_f;
    __hip_bfloat16* xsg_bf= (__hip_bfloat16*)xsgf;
    __hip_bfloat16* cat0  = (__hip_bfloat16*)cat0_f;
    __hip_bfloat16* cat1  = (__hip_bfloat16*)cat1_f;
    __hip_bfloat16* gwt   = (__hip_bfloat16*)gwt_f;
    __hip_bfloat16* pwt   = (__hip_bfloat16*)pwt_f;
    __hip_bfloat16* wot   = (__hip_bfloat16*)wot_f;
    __hip_bfloat16* wint  = (__hip_bfloat16*)wint_f;
    float*          Pbuf  = xt1;

    const dim3 blk(256);

    prep_kernel<<<1368, blk, 0, stream>>>(wd, gw, pw, wo, wb, wc, w_in, tab,
                                          cat0, cat1, gwt, pwt, wot, wint);
    gemm_in_kernel<<<dim3(4, 128), blk, 0, stream>>>(x, wint, b_in, h, ht);

    const dim3 qgrid(5, BLn / 64);
    const dim3 ggrid(4, BLn / 64);
    const dim3 sgrid(16, 16, BB);

    // ---- layer 0 (full sequence) ----
    lnconv_kernel<<<BLn / 32, blk, 0, stream>>>(h, ln_g, ln_b, conv_w, conv_b, xn_bf, xc_bf);
    gemm_core<0><<<qgrid, blk, 0, stream>>>((const short*)xc_bf, (const short*)cat0,
                                            bd, nullptr, nullptr, delta, Btm, Ctm, nullptr);
    ssm_chunk_kernel<0><<<sgrid, blk, 0, stream>>>(delta, Btm, nullptr, loglam,
                                                   nullptr, sA, sB, nullptr);
    ssm_comb_kernel<<<BB * 4096 / 256, blk, 0, stream>>>(sA, sB, hst, nullptr);
    ssm_chunk_kernel<1><<<sgrid, blk, 0, stream>>>(delta, Btm, Ctm, loglam,
                                                   hst, nullptr, nullptr, ys);
    gemm_sk_kernel<<<512, blk, 0, stream>>>(ys, wot, Pbuf);
    gemm_core<1><<<ggrid, blk, 0, stream>>>((const short*)xn_bf, (const short*)gwt,
                                            gb, Pbuf, bo, nullptr, nullptr, nullptr, xsg_bf);
    gemm_core<2><<<ggrid, blk, 0, stream>>>((const short*)xsg_bf, (const short*)pwt,
                                            pb, h, nullptr, xt1, nullptr, nullptr, nullptr);

    // ---- layer 1 (only final state needed downstream) ----
    lnconv_kernel<<<BLn / 32, blk, 0, stream>>>(xt1, ln_g + DD, ln_b + DD,
                                                conv_w + DD * 3, conv_b + DD, xn_bf, xc_bf);
    gemm_core<0><<<qgrid, blk, 0, stream>>>((const short*)xc_bf, (const short*)cat1,
                                            bd + DD, nullptr, nullptr, delta, Btm, Ctm, nullptr);
    ssm_chunk_kernel<0><<<sgrid, blk, 0, stream>>>(delta, Btm, nullptr, loglam + DD * NN,
                                                   nullptr, sA, sB, nullptr);
    ssm_comb_kernel<<<BB * 4096 / 256, blk, 0, stream>>>(sA, sB, hst, hfin);
    last_ssm_part_kernel<<<32, blk, 0, stream>>>(hfin, Ctm, wo + (size_t)DD * NN * DD, lpart);
    last_redproj_kernel<<<BB, blk, 0, stream>>>(lpart, bo + DD, xn_bf,
                                                gw + (size_t)DD * DD, gb + DD,
                                                pw + (size_t)DD * DD, pb + DD, xt1, xtlast);

    // ---- spectral path ----
    fft2_kernel<<<512, blk, 0, stream>>>(ht, tab, Xre, Xim);
    mag_part_kernel<<<dim3(5, 16), blk, 0, stream>>>(Xre, Xim, magp);
    topk_kernel<<<1, blk, 0, stream>>>(magp, sel);
    xslast_kernel<<<BB, blk, 0, stream>>>(Xre, Xim, sel, fr, fi, tab, xslast);

    head_kernel<<<BB, blk, 0, stream>>>(xtlast, xslast, alpha, beta, gout, bout,
                                        hw1, hb1, hw2, hb2, (float*)d_out);
}